// Round 3
// baseline (246476.587 us; speedup 1.0000x reference)
//
#include <hip/hip_runtime.h>
#include <cstdint>
#include <cstddef>

// ---------------- constants ----------------
#define NB    64      // batch
#define TIN   512
#define TOUT  500
#define NMEL  80
#define ENC   512
#define ATTD  128
#define ARNN  1024
#define DRNN  1024
#define PREN  256
#define NFILT 32
#define KSZ   31
#define CPAD  15
#define NBLK  256     // persistent grid == CU count

#define MEL_OFF  0
#define GATE_OFF 2560000
#define ALGN_OFF 2592000

// ws float-layout sizes
#define X_SZ      8192000   // prenet output [500][64][256]
#define PM_SZ     4194304   // processed memory [64][512][128]
#define GATES_SZ  1048576   // 4 k-split partials [4][64][4096] (shared att/dec)
#define XATT_SZ   98304     // [64][1536] = [ctx(512)|ah(1024)]
#define XDEC_SZ   163840    // [64][2560] = [ah(1024)|ctx(512)|dh(1024)]
#define AC_SZ     65536
#define DC_SZ     65536
#define AW_SZ     32768
#define AWC_SZ    32768
#define PQ_SZ     8192
#define EN_SZ     32768
#define LOC_SZ    1048576   // conv output [64][512][32]
#define MASK_N    8208384   // 501*64*256

__device__ __forceinline__ float sigf(float x) { return 1.f / (1.f + expf(-x)); }
__device__ __forceinline__ uint32_t rotl32(uint32_t v, int r) { return (v << r) | (v >> (32 - r)); }

// JAX threefry2x32 (exact: 5 groups of 4 rounds + key injections)
__device__ void tf_block(uint32_t k1, uint32_t k2, uint32_t& x0, uint32_t& x1) {
    uint32_t ks0 = k1, ks1 = k2, ks2 = k1 ^ k2 ^ 0x1BD11BDAu;
    x0 += ks0; x1 += ks1;
#define TFR(r) { x0 += x1; x1 = rotl32(x1, r); x1 ^= x0; }
    TFR(13) TFR(15) TFR(26) TFR(6)   x0 += ks1; x1 += ks2 + 1u;
    TFR(17) TFR(29) TFR(16) TFR(24)  x0 += ks2; x1 += ks0 + 2u;
    TFR(13) TFR(15) TFR(26) TFR(6)   x0 += ks0; x1 += ks1 + 3u;
    TFR(17) TFR(29) TFR(16) TFR(24)  x0 += ks1; x1 += ks2 + 4u;
    TFR(13) TFR(15) TFR(26) TFR(6)   x0 += ks2; x1 += ks0 + 5u;
#undef TFR
}

// Dropout keep masks, JAX >= 0.4.30 partitionable threefry semantics (verified round 2).
__global__ __launch_bounds__(256) void mask_kernel(unsigned char* m1, unsigned char* m2) {
    int i = blockIdx.x * 256 + threadIdx.x;
    if (i >= MASK_N) return;
    uint32_t a0 = 0u, a1 = 0u; tf_block(0u, 42u, a0, a1);   // dk1
    uint32_t b0 = 0u, b1 = 1u; tf_block(0u, 42u, b0, b1);   // dk2
    uint32_t x0, x1;
    x0 = 0u; x1 = (uint32_t)i; tf_block(a0, a1, x0, x1);
    m1[i] = ((x0 ^ x1) >> 31) == 0u;
    x0 = 0u; x1 = (uint32_t)i; tf_block(b0, b1, x0, x1);
    m2[i] = ((x0 ^ x1) >> 31) == 0u;
}

__global__ __launch_bounds__(256) void prenet1_kernel(
    const float* __restrict__ dec_in, const float* __restrict__ w1,
    const unsigned char* __restrict__ m1, float* __restrict__ x)
{
    int r = blockIdx.x;            // 0..31999
    int t = r >> 6, b = r & 63;
    int tid = threadIdx.x;
    __shared__ float ds[NMEL];
    if (tid < NMEL) ds[tid] = (t == 0) ? 0.f : dec_in[(size_t)b * 40000 + tid * 500 + (t - 1)];
    __syncthreads();
    float acc = 0.f;
    const float* w = w1 + tid * NMEL;
#pragma unroll
    for (int k = 0; k < NMEL; ++k) acc += ds[k] * w[k];
    acc = fmaxf(acc, 0.f);
    int flat = r * 256 + tid;
    x[flat] = m1[flat] ? acc * 2.f : 0.f;
}

__global__ __launch_bounds__(256) void prenet2_kernel(
    const float* __restrict__ w2, const unsigned char* __restrict__ m2, float* x)
{
    int r = blockIdx.x;
    int tid = threadIdx.x;
    __shared__ float xs[PREN];
    xs[tid] = x[r * 256 + tid];
    __syncthreads();
    float acc = 0.f;
    const float* w = w2 + tid * PREN;
#pragma unroll 8
    for (int k = 0; k < PREN; ++k) acc += xs[k] * w[k];
    acc = fmaxf(acc, 0.f);
    int flat = r * 256 + tid;
    x[flat] = m2[flat] ? acc * 2.f : 0.f;
}

__global__ __launch_bounds__(128) void pm_kernel(
    const float* __restrict__ memory, const float* __restrict__ wm, float* __restrict__ pm)
{
    int b = blockIdx.x, t = blockIdx.y;
    int tid = threadIdx.x;
    __shared__ float ms[ENC];
    for (int i = tid; i < ENC; i += 128) ms[i] = memory[(size_t)b * (TIN * ENC) + (size_t)t * ENC + i];
    __syncthreads();
    float acc = 0.f;
    const float* w = wm + tid * ENC;
#pragma unroll 8
    for (int k = 0; k < ENC; ++k) acc += ms[k] * w[k];
    pm[(size_t)b * (TIN * ATTD) + t * ATTD + tid] = acc;
}

// ---------------- persistent decoder ----------------
struct SmemConv { float awin[160]; float awcin[160]; float lcs[NFILT * 62]; };
struct SmemGemm { float Xs[32][68]; float Ws[32][68]; };
struct SmemPh2  { float hs[ARNN]; float red[256]; };
struct SmemPh3  { float locs[128 * 33]; float ldm[ATTD * NFILT]; float pqs[ATTD]; float vs[ATTD]; float ered[256]; };
struct SmemPh4  { float es[TIN]; float red[256]; };
struct SmemPh6  { float s[1536]; float red[256]; };
union Smem {
    SmemConv conv; SmemGemm gemm; SmemPh2 p2; SmemPh3 p3; SmemPh4 p4; SmemPh6 p6;
};

// software grid barrier: monotone counter, epoch target. All blocks co-resident
// (grid == 256 == #CUs, 36KB LDS -> every CU hosts >=1 block immediately).
__device__ __forceinline__ void gbar(unsigned int* ctr, unsigned int& epoch) {
    epoch += 1;
    __syncthreads();
    if (threadIdx.x == 0) {
        __threadfence();                       // release our global writes (device scope)
        atomicAdd(ctr, 1u);                    // device-scope by default
        const unsigned int target = epoch * (unsigned int)NBLK;
        while (__hip_atomic_load(ctr, __ATOMIC_RELAXED, __HIP_MEMORY_SCOPE_AGENT) < target)
            __builtin_amdgcn_s_sleep(1);
        __threadfence();                       // acquire: invalidate caches before reads
    }
    __syncthreads();
}

// K-split GEMM phase: out[ks][64][4096] partial = X[m,kbeg..kbeg+Kq) . W[n,...]
__device__ void gemm_phase(
    const float* __restrict__ X1, int ldx1, int kx1,
    const float* __restrict__ X2, int ldx2,
    const float* __restrict__ W1, int ldw1, int kw1,
    const float* __restrict__ W2, int ldw2,
    float* __restrict__ outp, int Kq, int blk, SmemGemm& s)
{
    const int tid = threadIdx.x;
    const int n0 = (blk & 63) * 64;
    const int ks = blk >> 6;
    const int kbeg = ks * Kq;
    const int tn = tid & 15, tm = tid >> 4;
    float acc[4][4];
#pragma unroll
    for (int i = 0; i < 4; ++i)
#pragma unroll
        for (int j = 0; j < 4; ++j) acc[i][j] = 0.f;

#pragma unroll 1
    for (int k0 = kbeg; k0 < kbeg + Kq; k0 += 32) {
#pragma unroll
        for (int i = 0; i < 8; ++i) {
            int flat = i * 256 + tid;
            int m = flat >> 5, c = flat & 31;
            int k = k0 + c;
            s.Xs[c][m] = (k < kx1) ? X1[m * ldx1 + k] : X2[m * ldx2 + (k - kx1)];
        }
#pragma unroll
        for (int i = 0; i < 8; ++i) {
            int flat = i * 256 + tid;
            int r = flat >> 5, c = flat & 31;
            int k = k0 + c;
            int n = n0 + r;
            s.Ws[c][r] = (k < kw1) ? W1[n * ldw1 + k] : W2[n * ldw2 + (k - kw1)];
        }
        __syncthreads();
#pragma unroll
        for (int kk = 0; kk < 32; ++kk) {
            float4 xv = *(const float4*)&s.Xs[kk][tm * 4];
            float4 wv = *(const float4*)&s.Ws[kk][tn * 4];
            float xr[4] = { xv.x, xv.y, xv.z, xv.w };
            float wr[4] = { wv.x, wv.y, wv.z, wv.w };
#pragma unroll
            for (int i = 0; i < 4; ++i)
#pragma unroll
                for (int j = 0; j < 4; ++j) acc[i][j] += xr[i] * wr[j];
        }
        __syncthreads();
    }
    float* o = outp + (size_t)ks * 64 * 4096;
#pragma unroll
    for (int i = 0; i < 4; ++i)
#pragma unroll
        for (int j = 0; j < 4; ++j)
            o[(tm * 4 + i) * 4096 + (n0 + tn * 4 + j)] = acc[i][j];
}

__global__ __launch_bounds__(256, 1) void decoder_persistent(
    const float* __restrict__ memory, const int* __restrict__ mlen,
    const float* __restrict__ x, const float* __restrict__ pm,
    const float* __restrict__ wq, const float* __restrict__ loc_conv,
    const float* __restrict__ loc_dense, const float* __restrict__ vvec,
    const float* __restrict__ att_wih, const float* __restrict__ att_whh,
    const float* __restrict__ att_bih, const float* __restrict__ att_bhh,
    const float* __restrict__ dec_wih, const float* __restrict__ dec_whh,
    const float* __restrict__ dec_bih, const float* __restrict__ dec_bhh,
    const float* __restrict__ proj_w, const float* __restrict__ proj_b,
    const float* __restrict__ gate_w, const float* __restrict__ gate_b,
    float* __restrict__ gates, float* __restrict__ xcat_att, float* __restrict__ xcat_dec,
    float* __restrict__ ac, float* __restrict__ dc,
    float* __restrict__ aw, float* __restrict__ awc,
    float* __restrict__ pqb, float* __restrict__ energ, float* __restrict__ locws,
    float* __restrict__ out, unsigned int* __restrict__ barctr)
{
    const int blk = blockIdx.x;
    const int tid = threadIdx.x;
    __shared__ __align__(16) Smem sm;
    unsigned int epoch = 0;

#pragma unroll 1
    for (int t = 0; t < TOUT; ++t) {
        // ===== Ph1: location conv (depends on prev step's aw/awc) + GEMM1 =====
        {
            const int b = blk >> 2, t0 = (blk & 3) * 128;
            for (int i = tid; i < 158; i += 256) {
                int tt = t0 + i - CPAD;
                bool ok = (tt >= 0 && tt < TIN);
                sm.conv.awin[i]  = ok ? aw[b * TIN + tt]  : 0.f;
                sm.conv.awcin[i] = ok ? awc[b * TIN + tt] : 0.f;
            }
            for (int i = tid; i < NFILT * 62; i += 256) sm.conv.lcs[i] = loc_conv[i];
            __syncthreads();
            for (int idx = tid; idx < 128 * 32; idx += 256) {
                int tl = idx >> 5, fch = idx & 31;
                const float* w0 = sm.conv.lcs + fch * 62;
                float s = 0.f;
#pragma unroll
                for (int k = 0; k < KSZ; ++k)
                    s += sm.conv.awin[tl + k] * w0[k] + sm.conv.awcin[tl + k] * w0[31 + k];
                locws[((size_t)b * TIN + t0 + tl) * NFILT + fch] = s;
            }
            __syncthreads();
            // attention gates GEMM: X = [x_t(256)|ctx(512)|ah(1024)], W = [wih(768)|whh(1024)]
            gemm_phase(x + (size_t)t * (NB * PREN), PREN, PREN, xcat_att, 1536,
                       att_wih, 768, 768, att_whh, 1024, gates, 448, blk, sm.gemm);
        }
        gbar(barctr, epoch);

        // ===== Ph2: attention-LSTM pointwise + pq (64 blocks, one per b) =====
        if (blk < NB) {
            const int b = blk;
#pragma unroll
            for (int q = 0; q < 4; ++q) {
                int j = q * 256 + tid;
                float gi = att_bih[j] + att_bhh[j];
                float gf = att_bih[1024 + j] + att_bhh[1024 + j];
                float gg = att_bih[2048 + j] + att_bhh[2048 + j];
                float go = att_bih[3072 + j] + att_bhh[3072 + j];
#pragma unroll
                for (int s = 0; s < 4; ++s) {
                    const float* g = gates + (size_t)s * 262144 + b * 4096;
                    gi += g[j]; gf += g[1024 + j]; gg += g[2048 + j]; go += g[3072 + j];
                }
                float c = sigf(gf) * ac[b * 1024 + j] + sigf(gi) * tanhf(gg);
                float h = sigf(go) * tanhf(c);
                ac[b * 1024 + j] = c;
                xcat_att[b * 1536 + 512 + j] = h;
                xcat_dec[b * 2560 + j] = h;
                sm.p2.hs[j] = h;
            }
            __syncthreads();
            const int a = tid >> 1, half = tid & 1;
            const float* wr = wq + a * 1024 + half * 512;
            const float* hh = sm.p2.hs + half * 512;
            float s = 0.f;
#pragma unroll 4
            for (int k = 0; k < 512; k += 4) {
                float4 wv = *(const float4*)&wr[k];
                float4 hv = *(const float4*)&hh[k];
                s += hv.x * wv.x + hv.y * wv.y + hv.z * wv.z + hv.w * wv.w;
            }
            sm.p2.red[tid] = s;
            __syncthreads();
            if (half == 0) pqb[b * ATTD + a] = sm.p2.red[tid] + sm.p2.red[tid + 1];
        }
        gbar(barctr, epoch);

        // ===== Ph3: energies (256 blocks = 64 b x 4 t-chunks) =====
        {
            const int b = blk >> 2, t0 = (blk & 3) * 128;
            SmemPh3& s3 = sm.p3;
            for (int i = tid; i < 128 * 32; i += 256) {
                int tl = i >> 5, fch = i & 31;
                s3.locs[tl * 33 + fch] = locws[((size_t)b * TIN + t0 + tl) * NFILT + fch];
            }
            for (int i = tid; i < ATTD * NFILT; i += 256) s3.ldm[i] = loc_dense[i];
            if (tid < ATTD) { s3.pqs[tid] = pqb[b * ATTD + tid]; s3.vs[tid] = vvec[tid]; }
            __syncthreads();
            const int tl = tid >> 1, half = tid & 1;
            float e = 0.f;
            const float* pmrow = pm + (size_t)b * (TIN * ATTD) + (size_t)(t0 + tl) * ATTD + half * 64;
            const float* lt = s3.locs + tl * 33;
            for (int a = 0; a < 64; ++a) {
                const float* lrow = s3.ldm + (half * 64 + a) * 32;
                float sv = s3.pqs[half * 64 + a] + pmrow[a];
#pragma unroll
                for (int fch = 0; fch < NFILT; ++fch) sv += lt[fch] * lrow[fch];
                e += s3.vs[half * 64 + a] * tanhf(sv);
            }
            s3.ered[tid] = e;
            __syncthreads();
            if (half == 0) energ[b * TIN + t0 + tl] = s3.ered[tid] + s3.ered[tid + 1];
        }
        gbar(barctr, epoch);

        // ===== Ph4: softmax + aw/awc/align + ctx (256 blocks = 64 b x 4 d-chunks) =====
        {
            const int b = blk >> 2, dq = blk & 3;
            const int len = mlen[b];
            SmemPh4& s4 = sm.p4;
            float e1 = (tid < len) ? energ[b * TIN + tid] : -INFINITY;
            float e2 = (tid + 256 < len) ? energ[b * TIN + tid + 256] : -INFINITY;
            s4.red[tid] = fmaxf(e1, e2);
            __syncthreads();
            for (int s = 128; s > 0; s >>= 1) {
                if (tid < s) s4.red[tid] = fmaxf(s4.red[tid], s4.red[tid + s]);
                __syncthreads();
            }
            const float mx = s4.red[0];
            __syncthreads();
            float p1 = expf(e1 - mx);
            float p2 = expf(e2 - mx);
            s4.red[tid] = p1 + p2;
            __syncthreads();
            for (int s = 128; s > 0; s >>= 1) {
                if (tid < s) s4.red[tid] += s4.red[tid + s];
                __syncthreads();
            }
            const float inv = 1.f / s4.red[0];
            p1 *= inv; p2 *= inv;
            s4.es[tid] = p1; s4.es[tid + 256] = p2;
            __syncthreads();
            if (tid < 128) {
                int tt = dq * 128 + tid;
                float p = s4.es[tt];
                aw[b * TIN + tt] = p;
                awc[b * TIN + tt] += p;
                out[ALGN_OFF + (size_t)b * (TOUT * TIN) + (size_t)t * TIN + tt] = p;
            }
            // ctx chunk: d in [dq*128, dq*128+128)
            const int d = dq * 128 + (tid & 127), th = tid >> 7;
            float accv = 0.f;
            const float* mb = memory + (size_t)b * (TIN * ENC);
            for (int tt = th * 256; tt < th * 256 + 256; ++tt)
                accv += s4.es[tt] * mb[(size_t)tt * ENC + d];
            __syncthreads();
            s4.red[tid] = accv;
            __syncthreads();
            if (tid < 128) {
                float cv = s4.red[tid] + s4.red[tid + 128];
                int dd = dq * 128 + tid;
                xcat_att[b * 1536 + dd] = cv;
                xcat_dec[b * 2560 + 1024 + dd] = cv;
            }
        }
        gbar(barctr, epoch);

        // ===== Ph5: decoder gates GEMM =====
        gemm_phase(xcat_dec, 2560, 2560, xcat_dec, 2560,
                   dec_wih, 1536, 1536, dec_whh, 1024, gates, 640, blk, sm.gemm);
        gbar(barctr, epoch);

        // ===== Ph6: decoder-LSTM pointwise + projection (64 blocks) =====
        if (blk < NB) {
            const int b = blk;
            SmemPh6& s6 = sm.p6;
#pragma unroll
            for (int q = 0; q < 4; ++q) {
                int j = q * 256 + tid;
                float gi = dec_bih[j] + dec_bhh[j];
                float gf = dec_bih[1024 + j] + dec_bhh[1024 + j];
                float gg = dec_bih[2048 + j] + dec_bhh[2048 + j];
                float go = dec_bih[3072 + j] + dec_bhh[3072 + j];
#pragma unroll
                for (int s = 0; s < 4; ++s) {
                    const float* g = gates + (size_t)s * 262144 + b * 4096;
                    gi += g[j]; gf += g[1024 + j]; gg += g[2048 + j]; go += g[3072 + j];
                }
                float c = sigf(gf) * dc[b * 1024 + j] + sigf(gi) * tanhf(gg);
                float h = sigf(go) * tanhf(c);
                dc[b * 1024 + j] = c;
                xcat_dec[b * 2560 + 1536 + j] = h;
                s6.s[j] = h;
            }
            for (int i = tid; i < 512; i += 256) s6.s[1024 + i] = xcat_dec[b * 2560 + 1024 + i];
            __syncthreads();
            const int o = tid >> 1, half = tid & 1;
            float accv = 0.f;
            if (o <= 80) {
                const float* w = (o < 80) ? (proj_w + o * 1536) : gate_w;
                const float* sv = s6.s + half * 768;
                const float* wv = w + half * 768;
#pragma unroll 4
                for (int k = 0; k < 768; k += 4) {
                    float4 a4 = *(const float4*)&sv[k];
                    float4 b4 = *(const float4*)&wv[k];
                    accv += a4.x * b4.x + a4.y * b4.y + a4.z * b4.z + a4.w * b4.w;
                }
            }
            s6.red[tid] = accv;
            __syncthreads();
            if (half == 0 && o <= 80) {
                float r = s6.red[tid] + s6.red[tid + 1];
                if (o < 80)
                    out[MEL_OFF + (size_t)b * (TOUT * NMEL) + (size_t)t * NMEL + o] = r + proj_b[o];
                else
                    out[GATE_OFF + (size_t)b * TOUT + t] = r + gate_b[0];
            }
        }
        gbar(barctr, epoch);
    }
}

extern "C" void kernel_launch(void* const* d_in, const int* in_sizes, int n_in,
                              void* d_out, int out_size, void* d_ws, size_t ws_size,
                              hipStream_t stream) {
    const float* memory   = (const float*)d_in[0];
    const float* dec_in   = (const float*)d_in[1];
    const int*   mlen     = (const int*)d_in[2];
    const float* pw1      = (const float*)d_in[3];
    const float* pw2      = (const float*)d_in[4];
    const float* att_wih  = (const float*)d_in[5];
    const float* att_whh  = (const float*)d_in[6];
    const float* att_bih  = (const float*)d_in[7];
    const float* att_bhh  = (const float*)d_in[8];
    const float* wq       = (const float*)d_in[9];
    const float* wm       = (const float*)d_in[10];
    const float* v        = (const float*)d_in[11];
    const float* loc_conv = (const float*)d_in[12];
    const float* loc_dense= (const float*)d_in[13];
    const float* dec_wih  = (const float*)d_in[14];
    const float* dec_whh  = (const float*)d_in[15];
    const float* dec_bih  = (const float*)d_in[16];
    const float* dec_bhh  = (const float*)d_in[17];
    const float* proj_w   = (const float*)d_in[18];
    const float* proj_b   = (const float*)d_in[19];
    const float* gate_w   = (const float*)d_in[20];
    const float* gate_b   = (const float*)d_in[21];
    float* out = (float*)d_out;

    // ---- ws layout ----
    float* f        = (float*)d_ws;
    float* x        = f;
    float* pm       = x + X_SZ;
    float* gates    = pm + PM_SZ;
    float* xcat_att = gates + GATES_SZ;
    float* xcat_dec = xcat_att + XATT_SZ;
    float* ac       = xcat_dec + XDEC_SZ;
    float* dc       = ac + AC_SZ;
    float* aw       = dc + DC_SZ;
    float* awc      = aw + AW_SZ;
    float* pqb      = awc + AWC_SZ;
    float* energ    = pqb + PQ_SZ;
    float* locws    = energ + EN_SZ;
    unsigned int* barctr = (unsigned int*)(locws + LOC_SZ);
    unsigned char* m1 = (unsigned char*)(barctr + 16);
    unsigned char* m2 = m1 + MASK_N;
    size_t need = (size_t)(m2 + MASK_N - (unsigned char*)d_ws);
    if (ws_size < need) return;

    // zero recurrent state (xcat_att..awc contiguous) + barrier counter
    size_t state_floats = (size_t)XATT_SZ + XDEC_SZ + AC_SZ + DC_SZ + AW_SZ + AWC_SZ;
    hipMemsetAsync(xcat_att, 0, state_floats * sizeof(float), stream);
    hipMemsetAsync(barctr, 0, 16 * sizeof(unsigned int), stream);

    // one-time: dropout masks, prenet, processed memory
    mask_kernel<<<(MASK_N + 255) / 256, 256, 0, stream>>>(m1, m2);
    prenet1_kernel<<<TOUT * NB, 256, 0, stream>>>(dec_in, pw1, m1, x);
    prenet2_kernel<<<TOUT * NB, 256, 0, stream>>>(pw2, m2, x);
    pm_kernel<<<dim3(NB, TIN), 128, 0, stream>>>(memory, wm, pm);

    decoder_persistent<<<NBLK, 256, 0, stream>>>(
        memory, mlen, x, pm, wq, loc_conv, loc_dense, v,
        att_wih, att_whh, att_bih, att_bhh,
        dec_wih, dec_whh, dec_bih, dec_bhh,
        proj_w, proj_b, gate_w, gate_b,
        gates, xcat_att, xcat_dec, ac, dc, aw, awc,
        pqb, energ, locws, out, barctr);
}

// Round 4
// 189150.452 us; speedup vs baseline: 1.3031x; 1.3031x over previous
//
#include <hip/hip_runtime.h>
#include <cstdint>
#include <cstddef>

// ---------------- constants ----------------
#define NB    64      // batch
#define TIN   512
#define TOUT  500
#define NMEL  80
#define ENC   512
#define ATTD  128
#define ARNN  1024
#define DRNN  1024
#define PREN  256
#define NFILT 32
#define KSZ   31
#define CPAD  15

#define MEL_OFF  0
#define GATE_OFF 2560000
#define ALGN_OFF 2592000

// ws float-layout sizes
#define X_SZ      8192000   // prenet output [500][64][256]
#define PM_SZ     4194304   // processed memory [64][512][128]
#define G1_SZ     1048576   // gemm1 partials [4][64][4096]
#define G2_SZ     1048576   // gemm2 partials [4][64][4096]
#define XATT_SZ   98304     // [64][1536] = [ctx(512)|ah(1024)]
#define XDEC_SZ   163840    // [64][2560] = [ah(1024)|ctx(512)|dh(1024)]
#define AC_SZ     65536
#define DC_SZ     65536
#define AW_SZ     32768
#define AWC_SZ    32768
#define MASK_N    8208384   // 501*64*256

__device__ __forceinline__ float sigf(float x) { return 1.f / (1.f + expf(-x)); }
__device__ __forceinline__ uint32_t rotl32(uint32_t v, int r) { return (v << r) | (v >> (32 - r)); }

// JAX threefry2x32 (exact: 5 groups of 4 rounds + key injections)
__device__ void tf_block(uint32_t k1, uint32_t k2, uint32_t& x0, uint32_t& x1) {
    uint32_t ks0 = k1, ks1 = k2, ks2 = k1 ^ k2 ^ 0x1BD11BDAu;
    x0 += ks0; x1 += ks1;
#define TFR(r) { x0 += x1; x1 = rotl32(x1, r); x1 ^= x0; }
    TFR(13) TFR(15) TFR(26) TFR(6)   x0 += ks1; x1 += ks2 + 1u;
    TFR(17) TFR(29) TFR(16) TFR(24)  x0 += ks2; x1 += ks0 + 2u;
    TFR(13) TFR(15) TFR(26) TFR(6)   x0 += ks0; x1 += ks1 + 3u;
    TFR(17) TFR(29) TFR(16) TFR(24)  x0 += ks1; x1 += ks2 + 4u;
    TFR(13) TFR(15) TFR(26) TFR(6)   x0 += ks2; x1 += ks0 + 5u;
#undef TFR
}

// Dropout keep masks, JAX >= 0.4.30 partitionable threefry semantics (verified round 2).
__global__ __launch_bounds__(256) void mask_kernel(unsigned char* m1, unsigned char* m2) {
    int i = blockIdx.x * 256 + threadIdx.x;
    if (i >= MASK_N) return;
    uint32_t a0 = 0u, a1 = 0u; tf_block(0u, 42u, a0, a1);   // dk1
    uint32_t b0 = 0u, b1 = 1u; tf_block(0u, 42u, b0, b1);   // dk2
    uint32_t x0, x1;
    x0 = 0u; x1 = (uint32_t)i; tf_block(a0, a1, x0, x1);
    m1[i] = ((x0 ^ x1) >> 31) == 0u;
    x0 = 0u; x1 = (uint32_t)i; tf_block(b0, b1, x0, x1);
    m2[i] = ((x0 ^ x1) >> 31) == 0u;
}

__global__ __launch_bounds__(256) void prenet1_kernel(
    const float* __restrict__ dec_in, const float* __restrict__ w1,
    const unsigned char* __restrict__ m1, float* __restrict__ x)
{
    int r = blockIdx.x;            // 0..31999
    int t = r >> 6, b = r & 63;
    int tid = threadIdx.x;
    __shared__ float ds[NMEL];
    if (tid < NMEL) ds[tid] = (t == 0) ? 0.f : dec_in[(size_t)b * 40000 + tid * 500 + (t - 1)];
    __syncthreads();
    float acc = 0.f;
    const float* w = w1 + tid * NMEL;
#pragma unroll
    for (int k = 0; k < NMEL; ++k) acc += ds[k] * w[k];
    acc = fmaxf(acc, 0.f);
    int flat = r * 256 + tid;
    x[flat] = m1[flat] ? acc * 2.f : 0.f;
}

__global__ __launch_bounds__(256) void prenet2_kernel(
    const float* __restrict__ w2, const unsigned char* __restrict__ m2, float* x)
{
    int r = blockIdx.x;
    int tid = threadIdx.x;
    __shared__ float xs[PREN];
    xs[tid] = x[r * 256 + tid];
    __syncthreads();
    float acc = 0.f;
    const float* w = w2 + tid * PREN;
#pragma unroll 8
    for (int k = 0; k < PREN; ++k) acc += xs[k] * w[k];
    acc = fmaxf(acc, 0.f);
    int flat = r * 256 + tid;
    x[flat] = m2[flat] ? acc * 2.f : 0.f;
}

__global__ __launch_bounds__(128) void pm_kernel(
    const float* __restrict__ memory, const float* __restrict__ wm, float* __restrict__ pm)
{
    int b = blockIdx.x, t = blockIdx.y;
    int tid = threadIdx.x;
    __shared__ float ms[ENC];
    for (int i = tid; i < ENC; i += 128) ms[i] = memory[(size_t)b * (TIN * ENC) + (size_t)t * ENC + i];
    __syncthreads();
    float acc = 0.f;
    const float* w = wm + tid * ENC;
#pragma unroll 8
    for (int k = 0; k < ENC; ++k) acc += ms[k] * w[k];
    pm[(size_t)b * (TIN * ATTD) + t * ATTD + tid] = acc;
}

// ---------------- K-split GEMM device fn (256 threads) ----------------
struct SmemGemm { float Xs[32][68]; float Ws[32][68]; };

__device__ void gemm_phase(
    const float* __restrict__ X1, int ldx1, int kx1,
    const float* __restrict__ X2, int ldx2,
    const float* __restrict__ W1, int ldw1, int kw1,
    const float* __restrict__ W2, int ldw2,
    float* __restrict__ outp, int Kq, int blk, SmemGemm& s)
{
    const int tid = threadIdx.x;
    const int n0 = (blk & 63) * 64;
    const int ks = blk >> 6;
    const int kbeg = ks * Kq;
    const int tn = tid & 15, tm = tid >> 4;
    float acc[4][4];
#pragma unroll
    for (int i = 0; i < 4; ++i)
#pragma unroll
        for (int j = 0; j < 4; ++j) acc[i][j] = 0.f;

#pragma unroll 1
    for (int k0 = kbeg; k0 < kbeg + Kq; k0 += 32) {
#pragma unroll
        for (int i = 0; i < 8; ++i) {
            int flat = i * 256 + tid;
            int m = flat >> 5, c = flat & 31;
            int k = k0 + c;
            s.Xs[c][m] = (k < kx1) ? X1[m * ldx1 + k] : X2[m * ldx2 + (k - kx1)];
        }
#pragma unroll
        for (int i = 0; i < 8; ++i) {
            int flat = i * 256 + tid;
            int r = flat >> 5, c = flat & 31;
            int k = k0 + c;
            int n = n0 + r;
            s.Ws[c][r] = (k < kw1) ? W1[n * ldw1 + k] : W2[n * ldw2 + (k - kw1)];
        }
        __syncthreads();
#pragma unroll
        for (int kk = 0; kk < 32; ++kk) {
            float4 xv = *(const float4*)&s.Xs[kk][tm * 4];
            float4 wv = *(const float4*)&s.Ws[kk][tn * 4];
            float xr[4] = { xv.x, xv.y, xv.z, xv.w };
            float wr[4] = { wv.x, wv.y, wv.z, wv.w };
#pragma unroll
            for (int i = 0; i < 4; ++i)
#pragma unroll
                for (int j = 0; j < 4; ++j) acc[i][j] += xr[i] * wr[j];
        }
        __syncthreads();
    }
    float* o = outp + (size_t)ks * 64 * 4096;
#pragma unroll
    for (int i = 0; i < 4; ++i)
#pragma unroll
        for (int j = 0; j < 4; ++j)
            o[(tm * 4 + i) * 4096 + (n0 + tn * 4 + j)] = acc[i][j];
}

// ---------------- BCD: per-b fused att-LSTM + pq + conv + energies + softmax + ctx ----------------
__global__ __launch_bounds__(512, 1) void bcd_kernel(
    const float* __restrict__ g1, const float* __restrict__ att_bih, const float* __restrict__ att_bhh,
    float* __restrict__ ac, const float* __restrict__ wq,
    const float* __restrict__ loc_conv, const float* __restrict__ loc_dense,
    const float* __restrict__ vvec, const float* __restrict__ pm,
    const int* __restrict__ mlen, const float* __restrict__ memory,
    float* __restrict__ aw, float* __restrict__ awc,
    float* __restrict__ xcat_att, float* __restrict__ xcat_dec,
    float* __restrict__ out, int t_step)
{
    const int b = blockIdx.x, tid = threadIdx.x;
    __shared__ float hs[ARNN];
    __shared__ float red[512];
    __shared__ float pqs[ATTD];
    __shared__ float vs[ATTD];
    __shared__ float awin[544], awcin[544];
    __shared__ float lcs[NFILT * 62];
    __shared__ float ldm[ATTD * NFILT];
    __shared__ float es[TIN];

    // stage small constants + prev-step attention weights (with conv halo)
    for (int i = tid; i < 542; i += 512) {
        int t = i - CPAD;
        bool ok = (t >= 0 && t < TIN);
        awin[i]  = ok ? aw[b * TIN + t]  : 0.f;
        awcin[i] = ok ? awc[b * TIN + t] : 0.f;
    }
    for (int i = tid; i < NFILT * 62; i += 512) lcs[i] = loc_conv[i];
    for (int i = tid; i < ATTD * NFILT; i += 512) ldm[i] = loc_dense[i];
    if (tid < ATTD) vs[tid] = vvec[tid];

    // 1. attention LSTM pointwise (gates = sum of 4 K-split partials + biases)
#pragma unroll
    for (int q = 0; q < 2; ++q) {
        int j = q * 512 + tid;
        float gi = att_bih[j] + att_bhh[j];
        float gf = att_bih[1024 + j] + att_bhh[1024 + j];
        float gg = att_bih[2048 + j] + att_bhh[2048 + j];
        float go = att_bih[3072 + j] + att_bhh[3072 + j];
#pragma unroll
        for (int s = 0; s < 4; ++s) {
            const float* g = g1 + (size_t)s * 262144 + b * 4096;
            gi += g[j]; gf += g[1024 + j]; gg += g[2048 + j]; go += g[3072 + j];
        }
        float c = sigf(gf) * ac[b * 1024 + j] + sigf(gi) * tanhf(gg);
        float h = sigf(go) * tanhf(c);
        ac[b * 1024 + j] = c;
        xcat_att[b * 1536 + 512 + j] = h;
        xcat_dec[b * 2560 + j] = h;
        hs[j] = h;
    }
    __syncthreads();

    // 2. pq[a] = hs . wq[a]  (4 threads per a)
    {
        const int a = tid >> 2, part = tid & 3;
        const float* wr = wq + a * 1024 + part * 256;
        const float* hh = hs + part * 256;
        float s = 0.f;
#pragma unroll 4
        for (int k = 0; k < 256; k += 4) {
            float4 wv = *(const float4*)&wr[k];
            float4 hv = *(const float4*)&hh[k];
            s += hv.x * wv.x + hv.y * wv.y + hv.z * wv.z + hv.w * wv.w;
        }
        red[tid] = s;
    }
    __syncthreads();
    if (tid < ATTD) {
        pqs[tid] = red[tid * 4] + red[tid * 4 + 1] + red[tid * 4 + 2] + red[tid * 4 + 3];
    }
    __syncthreads();

    // 3. location conv: thread t computes all 32 filters (kept in regs)
    float lcv[NFILT];
#pragma unroll
    for (int f = 0; f < NFILT; ++f) {
        const float* w0 = lcs + f * 62;
        float s = 0.f;
#pragma unroll
        for (int k = 0; k < KSZ; ++k)
            s += awin[tid + k] * w0[k] + awcin[tid + k] * w0[31 + k];
        lcv[f] = s;
    }

    // 4. energies: e[t] = sum_a v[a] * tanh(pq[a] + pm[b,t,a] + loc[t].ld[a])
    float e;
    {
        const float* pmrow = pm + (size_t)b * (TIN * ATTD) + (size_t)tid * ATTD;
        float acc = 0.f;
#pragma unroll 1
        for (int a0 = 0; a0 < ATTD; a0 += 32) {
            float4 pv[8];
#pragma unroll
            for (int u = 0; u < 8; ++u) pv[u] = *(const float4*)&pmrow[a0 + u * 4];
#pragma unroll
            for (int aa = 0; aa < 32; ++aa) {
                int a = a0 + aa;
                float sv = pqs[a] + ((const float*)pv)[aa];
                const float* lrow = ldm + a * NFILT;
#pragma unroll
                for (int f = 0; f < NFILT; ++f) sv += lcv[f] * lrow[f];
                acc += vs[a] * tanhf(sv);
            }
        }
        e = acc;
    }

    // 5. masked softmax over t (len = memory_lengths[b])
    const int len = mlen[b];
    float val = (tid < len) ? e : -INFINITY;
    red[tid] = val;
    __syncthreads();
    for (int s = 256; s > 0; s >>= 1) {
        if (tid < s) red[tid] = fmaxf(red[tid], red[tid + s]);
        __syncthreads();
    }
    const float mx = red[0];
    __syncthreads();
    float p = expf(val - mx);
    red[tid] = p;
    __syncthreads();
    for (int s = 256; s > 0; s >>= 1) {
        if (tid < s) red[tid] += red[tid + s];
        __syncthreads();
    }
    p *= 1.f / red[0];
    es[tid] = p;
    aw[b * TIN + tid] = p;
    awc[b * TIN + tid] += p;
    out[ALGN_OFF + (size_t)b * (TOUT * TIN) + (size_t)t_step * TIN + tid] = p;
    __syncthreads();

    // 6. ctx[d] = sum_t p[t] * memory[b,t,d]  (one thread per d)
    {
        const float* mb = memory + (size_t)b * (TIN * ENC);
        float c = 0.f;
#pragma unroll 8
        for (int t = 0; t < TIN; ++t) c += es[t] * mb[(size_t)t * ENC + tid];
        xcat_att[b * 1536 + tid] = c;
        xcat_dec[b * 2560 + 1024 + tid] = c;
    }
}

// ---------------- E: decoder gates GEMM (grid 256) ----------------
__global__ __launch_bounds__(256) void gemm2_kernel(
    const float* __restrict__ xcat_dec,
    const float* __restrict__ dec_wih, const float* __restrict__ dec_whh,
    float* __restrict__ g2)
{
    __shared__ __align__(16) SmemGemm sm;
    gemm_phase(xcat_dec, 2560, 2560, xcat_dec, 2560,
               dec_wih, 1536, 1536, dec_whh, 1024, g2, 640, blockIdx.x, sm);
}

// ---------------- FA: F(t) = dec-pointwise+proj  ||  A(t+1) = gemm1 ----------------
struct SmemF { float s[1536]; float red[256]; };
union SmemFA { SmemGemm g; SmemF f; };

__global__ __launch_bounds__(256) void fa_kernel(
    const float* __restrict__ g2, const float* __restrict__ dec_bih, const float* __restrict__ dec_bhh,
    float* __restrict__ dc, float* __restrict__ xcat_dec,
    const float* __restrict__ proj_w, const float* __restrict__ proj_b,
    const float* __restrict__ gate_w, const float* __restrict__ gate_b,
    float* __restrict__ out,
    const float* __restrict__ x, const float* __restrict__ xcat_att,
    const float* __restrict__ att_wih, const float* __restrict__ att_whh,
    float* __restrict__ g1, int t_cur)
{
    __shared__ __align__(16) SmemFA sm;
    const int blk = blockIdx.x;
    const int tid = threadIdx.x;
    if (blk < 256) {
        // gemm1 for step t_cur+1: X = [x_t(256)|ctx(512)|ah(1024)]
        const int tn = t_cur + 1;
        if (tn >= TOUT) return;
        gemm_phase(x + (size_t)tn * (NB * PREN), PREN, PREN, xcat_att, 1536,
                   att_wih, 768, 768, att_whh, 1024, g1, 448, blk, sm.g);
    } else {
        // F for step t_cur: decoder-LSTM pointwise + mel/gate projection
        if (t_cur < 0) return;
        const int b = blk - 256;
        SmemF& s6 = sm.f;
#pragma unroll
        for (int q = 0; q < 4; ++q) {
            int j = q * 256 + tid;
            float gi = dec_bih[j] + dec_bhh[j];
            float gf = dec_bih[1024 + j] + dec_bhh[1024 + j];
            float gg = dec_bih[2048 + j] + dec_bhh[2048 + j];
            float go = dec_bih[3072 + j] + dec_bhh[3072 + j];
#pragma unroll
            for (int s = 0; s < 4; ++s) {
                const float* g = g2 + (size_t)s * 262144 + b * 4096;
                gi += g[j]; gf += g[1024 + j]; gg += g[2048 + j]; go += g[3072 + j];
            }
            float c = sigf(gf) * dc[b * 1024 + j] + sigf(gi) * tanhf(gg);
            float h = sigf(go) * tanhf(c);
            dc[b * 1024 + j] = c;
            xcat_dec[b * 2560 + 1536 + j] = h;
            s6.s[j] = h;
        }
        for (int i = tid; i < 512; i += 256) s6.s[1024 + i] = xcat_dec[b * 2560 + 1024 + i];
        __syncthreads();
        const int o = tid >> 1, half = tid & 1;
        float accv = 0.f;
        if (o <= 80) {
            const float* w = (o < 80) ? (proj_w + o * 1536) : gate_w;
            const float* sv = s6.s + half * 768;
            const float* wv = w + half * 768;
#pragma unroll 4
            for (int k = 0; k < 768; k += 4) {
                float4 a4 = *(const float4*)&sv[k];
                float4 b4 = *(const float4*)&wv[k];
                accv += a4.x * b4.x + a4.y * b4.y + a4.z * b4.z + a4.w * b4.w;
            }
        }
        s6.red[tid] = accv;
        __syncthreads();
        if (half == 0 && o <= 80) {
            float r = s6.red[tid] + s6.red[tid + 1];
            if (o < 80)
                out[MEL_OFF + (size_t)b * (TOUT * NMEL) + (size_t)t_cur * NMEL + o] = r + proj_b[o];
            else
                out[GATE_OFF + (size_t)b * TOUT + t_cur] = r + gate_b[0];
        }
    }
}

extern "C" void kernel_launch(void* const* d_in, const int* in_sizes, int n_in,
                              void* d_out, int out_size, void* d_ws, size_t ws_size,
                              hipStream_t stream) {
    const float* memory   = (const float*)d_in[0];
    const float* dec_in   = (const float*)d_in[1];
    const int*   mlen     = (const int*)d_in[2];
    const float* pw1      = (const float*)d_in[3];
    const float* pw2      = (const float*)d_in[4];
    const float* att_wih  = (const float*)d_in[5];
    const float* att_whh  = (const float*)d_in[6];
    const float* att_bih  = (const float*)d_in[7];
    const float* att_bhh  = (const float*)d_in[8];
    const float* wq       = (const float*)d_in[9];
    const float* wm       = (const float*)d_in[10];
    const float* v        = (const float*)d_in[11];
    const float* loc_conv = (const float*)d_in[12];
    const float* loc_dense= (const float*)d_in[13];
    const float* dec_wih  = (const float*)d_in[14];
    const float* dec_whh  = (const float*)d_in[15];
    const float* dec_bih  = (const float*)d_in[16];
    const float* dec_bhh  = (const float*)d_in[17];
    const float* proj_w   = (const float*)d_in[18];
    const float* proj_b   = (const float*)d_in[19];
    const float* gate_w   = (const float*)d_in[20];
    const float* gate_b   = (const float*)d_in[21];
    float* out = (float*)d_out;

    // ---- ws layout ----
    float* x        = (float*)d_ws;
    float* pm       = x + X_SZ;
    float* g1       = pm + PM_SZ;
    float* g2       = g1 + G1_SZ;
    float* xcat_att = g2 + G2_SZ;
    float* xcat_dec = xcat_att + XATT_SZ;
    float* ac       = xcat_dec + XDEC_SZ;
    float* dc       = ac + AC_SZ;
    float* aw       = dc + DC_SZ;
    float* awc      = aw + AW_SZ;
    unsigned char* m1 = (unsigned char*)(awc + AWC_SZ);
    unsigned char* m2 = m1 + MASK_N;
    size_t need = (size_t)(m2 + MASK_N - (unsigned char*)d_ws);
    if (ws_size < need) return;

    // zero recurrent state (xcat_att..awc contiguous)
    size_t state_floats = (size_t)XATT_SZ + XDEC_SZ + AC_SZ + DC_SZ + AW_SZ + AWC_SZ;
    hipMemsetAsync(xcat_att, 0, state_floats * sizeof(float), stream);

    // one-time: dropout masks, prenet, processed memory
    mask_kernel<<<(MASK_N + 255) / 256, 256, 0, stream>>>(m1, m2);
    prenet1_kernel<<<TOUT * NB, 256, 0, stream>>>(dec_in, pw1, m1, x);
    prenet2_kernel<<<TOUT * NB, 256, 0, stream>>>(pw2, m2, x);
    pm_kernel<<<dim3(NB, TIN), 128, 0, stream>>>(memory, wm, pm);

    // prologue: gemm1 for t=0 (F part no-ops via t_cur=-1)
    fa_kernel<<<320, 256, 0, stream>>>(g2, dec_bih, dec_bhh, dc, xcat_dec,
                                       proj_w, proj_b, gate_w, gate_b, out,
                                       x, xcat_att, att_wih, att_whh, g1, -1);

    for (int t = 0; t < TOUT; ++t) {
        bcd_kernel<<<NB, 512, 0, stream>>>(g1, att_bih, att_bhh, ac, wq,
                                           loc_conv, loc_dense, v, pm, mlen, memory,
                                           aw, awc, xcat_att, xcat_dec, out, t);
        gemm2_kernel<<<256, 256, 0, stream>>>(xcat_dec, dec_wih, dec_whh, g2);
        fa_kernel<<<320, 256, 0, stream>>>(g2, dec_bih, dec_bhh, dc, xcat_dec,
                                           proj_w, proj_b, gate_w, gate_b, out,
                                           x, xcat_att, att_wih, att_whh, g1, t);
    }
}

// Round 5
// 117148.926 us; speedup vs baseline: 2.1040x; 1.6146x over previous
//
#include <hip/hip_runtime.h>
#include <cstdint>
#include <cstddef>

// ---------------- constants ----------------
#define NB    64      // batch
#define TIN   512
#define TOUT  500
#define NMEL  80
#define ENC   512
#define ATTD  128
#define ARNN  1024
#define DRNN  1024
#define PREN  256
#define NFILT 32
#define KSZ   31
#define CPAD  15

#define MEL_OFF  0
#define GATE_OFF 2560000
#define ALGN_OFF 2592000

// ws float-layout sizes
#define X_SZ      8192000   // prenet output [500][64][256]
#define PM_SZ     4194304   // processed memory [64][512][128]
#define G1_SZ     1048576   // gemm1 partials [4][64][4096]
#define G2_SZ     1048576   // gemm2 partials [4][64][4096]
#define XATT_SZ   98304     // [64][1536] = [ctx(512)|ah(1024)]
#define XDEC_SZ   163840    // [64][2560] = [ah(1024)|ctx(512)|dh(1024)]
#define AC_SZ     65536
#define DC_SZ     65536
#define AW_SZ     32768
#define AWC_SZ    32768
#define PQ_SZ     8192
#define EN_SZ     32768
#define MASK_N    8208384   // 501*64*256

__device__ __forceinline__ float sigf(float x) { return 1.f / (1.f + expf(-x)); }
__device__ __forceinline__ uint32_t rotl32(uint32_t v, int r) { return (v << r) | (v >> (32 - r)); }

// JAX threefry2x32 (exact: 5 groups of 4 rounds + key injections)
__device__ void tf_block(uint32_t k1, uint32_t k2, uint32_t& x0, uint32_t& x1) {
    uint32_t ks0 = k1, ks1 = k2, ks2 = k1 ^ k2 ^ 0x1BD11BDAu;
    x0 += ks0; x1 += ks1;
#define TFR(r) { x0 += x1; x1 = rotl32(x1, r); x1 ^= x0; }
    TFR(13) TFR(15) TFR(26) TFR(6)   x0 += ks1; x1 += ks2 + 1u;
    TFR(17) TFR(29) TFR(16) TFR(24)  x0 += ks2; x1 += ks0 + 2u;
    TFR(13) TFR(15) TFR(26) TFR(6)   x0 += ks0; x1 += ks1 + 3u;
    TFR(17) TFR(29) TFR(16) TFR(24)  x0 += ks1; x1 += ks2 + 4u;
    TFR(13) TFR(15) TFR(26) TFR(6)   x0 += ks2; x1 += ks0 + 5u;
#undef TFR
}

// Dropout keep masks, JAX >= 0.4.30 partitionable threefry semantics (verified round 2).
__global__ __launch_bounds__(256) void mask_kernel(unsigned char* m1, unsigned char* m2) {
    int i = blockIdx.x * 256 + threadIdx.x;
    if (i >= MASK_N) return;
    uint32_t a0 = 0u, a1 = 0u; tf_block(0u, 42u, a0, a1);   // dk1
    uint32_t b0 = 0u, b1 = 1u; tf_block(0u, 42u, b0, b1);   // dk2
    uint32_t x0, x1;
    x0 = 0u; x1 = (uint32_t)i; tf_block(a0, a1, x0, x1);
    m1[i] = ((x0 ^ x1) >> 31) == 0u;
    x0 = 0u; x1 = (uint32_t)i; tf_block(b0, b1, x0, x1);
    m2[i] = ((x0 ^ x1) >> 31) == 0u;
}

__global__ __launch_bounds__(256) void prenet1_kernel(
    const float* __restrict__ dec_in, const float* __restrict__ w1,
    const unsigned char* __restrict__ m1, float* __restrict__ x)
{
    int r = blockIdx.x;            // 0..31999
    int t = r >> 6, b = r & 63;
    int tid = threadIdx.x;
    __shared__ float ds[NMEL];
    if (tid < NMEL) ds[tid] = (t == 0) ? 0.f : dec_in[(size_t)b * 40000 + tid * 500 + (t - 1)];
    __syncthreads();
    float acc = 0.f;
    const float* w = w1 + tid * NMEL;
#pragma unroll
    for (int k = 0; k < NMEL; ++k) acc += ds[k] * w[k];
    acc = fmaxf(acc, 0.f);
    int flat = r * 256 + tid;
    x[flat] = m1[flat] ? acc * 2.f : 0.f;
}

__global__ __launch_bounds__(256) void prenet2_kernel(
    const float* __restrict__ w2, const unsigned char* __restrict__ m2, float* x)
{
    int r = blockIdx.x;
    int tid = threadIdx.x;
    __shared__ float xs[PREN];
    xs[tid] = x[r * 256 + tid];
    __syncthreads();
    float acc = 0.f;
    const float* w = w2 + tid * PREN;
#pragma unroll 8
    for (int k = 0; k < PREN; ++k) acc += xs[k] * w[k];
    acc = fmaxf(acc, 0.f);
    int flat = r * 256 + tid;
    x[flat] = m2[flat] ? acc * 2.f : 0.f;
}

__global__ __launch_bounds__(128) void pm_kernel(
    const float* __restrict__ memory, const float* __restrict__ wm, float* __restrict__ pm)
{
    int b = blockIdx.x, t = blockIdx.y;
    int tid = threadIdx.x;
    __shared__ float ms[ENC];
    for (int i = tid; i < ENC; i += 128) ms[i] = memory[(size_t)b * (TIN * ENC) + (size_t)t * ENC + i];
    __syncthreads();
    float acc = 0.f;
    const float* w = wm + tid * ENC;
#pragma unroll 8
    for (int k = 0; k < ENC; ++k) acc += ms[k] * w[k];
    pm[(size_t)b * (TIN * ATTD) + t * ATTD + tid] = acc;
}

// ---------------- K-split GEMM device fn (256 threads, round-2 body) ----------------
struct SmemGemm { float Xs[32][68]; float Ws[32][68]; };

__device__ void gemm_phase(
    const float* __restrict__ X1, int ldx1, int kx1,
    const float* __restrict__ X2, int ldx2,
    const float* __restrict__ W1, int ldw1, int kw1,
    const float* __restrict__ W2, int ldw2,
    float* __restrict__ outp, int Kq, int blk, SmemGemm& s)
{
    const int tid = threadIdx.x;
    const int n0 = (blk & 63) * 64;
    const int ks = blk >> 6;
    const int kbeg = ks * Kq;
    const int tn = tid & 15, tm = tid >> 4;
    float acc[4][4];
#pragma unroll
    for (int i = 0; i < 4; ++i)
#pragma unroll
        for (int j = 0; j < 4; ++j) acc[i][j] = 0.f;

#pragma unroll 1
    for (int k0 = kbeg; k0 < kbeg + Kq; k0 += 32) {
#pragma unroll
        for (int i = 0; i < 8; ++i) {
            int flat = i * 256 + tid;
            int m = flat >> 5, c = flat & 31;
            int k = k0 + c;
            s.Xs[c][m] = (k < kx1) ? X1[m * ldx1 + k] : X2[m * ldx2 + (k - kx1)];
        }
#pragma unroll
        for (int i = 0; i < 8; ++i) {
            int flat = i * 256 + tid;
            int r = flat >> 5, c = flat & 31;
            int k = k0 + c;
            int n = n0 + r;
            s.Ws[c][r] = (k < kw1) ? W1[n * ldw1 + k] : W2[n * ldw2 + (k - kw1)];
        }
        __syncthreads();
#pragma unroll
        for (int kk = 0; kk < 32; ++kk) {
            float4 xv = *(const float4*)&s.Xs[kk][tm * 4];
            float4 wv = *(const float4*)&s.Ws[kk][tn * 4];
            float xr[4] = { xv.x, xv.y, xv.z, xv.w };
            float wr[4] = { wv.x, wv.y, wv.z, wv.w };
#pragma unroll
            for (int i = 0; i < 4; ++i)
#pragma unroll
                for (int j = 0; j < 4; ++j) acc[i][j] += xr[i] * wr[j];
        }
        __syncthreads();
    }
    float* o = outp + (size_t)ks * 64 * 4096;
#pragma unroll
    for (int i = 0; i < 4; ++i)
#pragma unroll
        for (int j = 0; j < 4; ++j)
            o[(tm * 4 + i) * 4096 + (n0 + tn * 4 + j)] = acc[i][j];
}

// ---------------- L4: gemm2(t) || gemm1(t+1) (512 blocks, 2/CU) ----------------
__global__ __launch_bounds__(256, 2) void pair_gemm(
    const float* __restrict__ xcat_dec,
    const float* __restrict__ dec_wih, const float* __restrict__ dec_whh,
    float* __restrict__ g2,
    const float* __restrict__ x, const float* __restrict__ xcat_att,
    const float* __restrict__ att_wih, const float* __restrict__ att_whh,
    float* __restrict__ g1, int t)
{
    __shared__ __align__(16) SmemGemm sm;
    const int blk = blockIdx.x;
    if (blk < 256) {
        if (t < 0) return;   // prologue: no gemm2
        // decoder gates: X = [ah(1024)|ctx(512)|dh(1024)], W = [wih(1536)|whh(1024)]
        gemm_phase(xcat_dec, 2560, 2560, xcat_dec, 2560,
                   dec_wih, 1536, 1536, dec_whh, 1024, g2, 640, blk, sm);
    } else {
        const int tn = t + 1;
        if (tn >= TOUT) return;
        // attention gates for step t+1: X = [x_t(256)|ctx(512)|ah(1024)], W = [wih(768)|whh(1024)]
        gemm_phase(x + (size_t)tn * (NB * PREN), PREN, PREN, xcat_att, 1536,
                   att_wih, 768, 768, att_whh, 1024, g1, 448, blk - 256, sm);
    }
}

// ---------------- L1: att_pointwise(t) || dec_pointwise+proj(t-1) (128 blocks) ----------------
__global__ __launch_bounds__(256) void pair_pw(
    const float* __restrict__ g1, const float* __restrict__ att_bih, const float* __restrict__ att_bhh,
    float* __restrict__ ac, float* __restrict__ xcat_att, float* __restrict__ xcat_dec,
    const float* __restrict__ wq, float* __restrict__ pq,
    const float* __restrict__ g2, const float* __restrict__ dec_bih, const float* __restrict__ dec_bhh,
    float* __restrict__ dc, const float* __restrict__ proj_w, const float* __restrict__ proj_b,
    const float* __restrict__ gate_w, const float* __restrict__ gate_b,
    float* __restrict__ out, int t)
{
    const int tid = threadIdx.x;
    __shared__ float sbuf[1536];
    __shared__ float red[256];

    if (blockIdx.x < 64) {
        // ===== attention-LSTM pointwise + pq, step t =====
        if (t >= TOUT) return;
        const int b = blockIdx.x;
#pragma unroll
        for (int q = 0; q < 4; ++q) {
            int j = q * 256 + tid;
            float gi = att_bih[j] + att_bhh[j];
            float gf = att_bih[1024 + j] + att_bhh[1024 + j];
            float gg = att_bih[2048 + j] + att_bhh[2048 + j];
            float go = att_bih[3072 + j] + att_bhh[3072 + j];
#pragma unroll
            for (int s = 0; s < 4; ++s) {
                const float* g = g1 + (size_t)s * 262144 + b * 4096;
                gi += g[j]; gf += g[1024 + j]; gg += g[2048 + j]; go += g[3072 + j];
            }
            float c = sigf(gf) * ac[b * 1024 + j] + sigf(gi) * tanhf(gg);
            float h = sigf(go) * tanhf(c);
            ac[b * 1024 + j] = c;
            xcat_att[b * 1536 + 512 + j] = h;
            xcat_dec[b * 2560 + j] = h;
            sbuf[j] = h;
        }
        __syncthreads();
        const int a = tid & 127, half = tid >> 7;
        float s = 0.f;
        const float* wr = wq + a * 1024 + half * 512;
        const float* hh = sbuf + half * 512;
#pragma unroll 4
        for (int k = 0; k < 512; k += 4) {
            float4 wv = *(const float4*)&wr[k];
            float4 hv = *(const float4*)&hh[k];
            s += hv.x * wv.x + hv.y * wv.y + hv.z * wv.z + hv.w * wv.w;
        }
        red[tid] = s;
        __syncthreads();
        if (half == 0) pq[b * 128 + a] = red[a] + red[a + 128];
    } else {
        // ===== decoder-LSTM pointwise + projection, step t-1 =====
        if (t < 1) return;
        const int b = blockIdx.x - 64;
        const int ts = t - 1;
#pragma unroll
        for (int q = 0; q < 4; ++q) {
            int j = q * 256 + tid;
            float gi = dec_bih[j] + dec_bhh[j];
            float gf = dec_bih[1024 + j] + dec_bhh[1024 + j];
            float gg = dec_bih[2048 + j] + dec_bhh[2048 + j];
            float go = dec_bih[3072 + j] + dec_bhh[3072 + j];
#pragma unroll
            for (int s = 0; s < 4; ++s) {
                const float* g = g2 + (size_t)s * 262144 + b * 4096;
                gi += g[j]; gf += g[1024 + j]; gg += g[2048 + j]; go += g[3072 + j];
            }
            float c = sigf(gf) * dc[b * 1024 + j] + sigf(gi) * tanhf(gg);
            float h = sigf(go) * tanhf(c);
            dc[b * 1024 + j] = c;
            xcat_dec[b * 2560 + 1536 + j] = h;
            sbuf[j] = h;
        }
        for (int i = tid; i < 512; i += 256) sbuf[1024 + i] = xcat_dec[b * 2560 + 1024 + i];
        __syncthreads();
        const int o = tid >> 1, half = tid & 1;
        float accv = 0.f;
        if (o <= 80) {
            const float* w = (o < 80) ? (proj_w + o * 1536) : gate_w;
            const float* sv = sbuf + half * 768;
            const float* wv = w + half * 768;
#pragma unroll 4
            for (int k = 0; k < 768; k += 4) {
                float4 a4 = *(const float4*)&sv[k];
                float4 b4 = *(const float4*)&wv[k];
                accv += a4.x * b4.x + a4.y * b4.y + a4.z * b4.z + a4.w * b4.w;
            }
        }
        red[tid] = accv;
        __syncthreads();
        if (half == 0 && o <= 80) {
            float r = red[tid] + red[tid + 1];
            if (o < 80)
                out[MEL_OFF + (size_t)b * (TOUT * NMEL) + (size_t)ts * NMEL + o] = r + proj_b[o];
            else
                out[GATE_OFF + (size_t)b * TOUT + ts] = r + gate_b[0];
        }
    }
}

// ---------------- L2: conv + loc_dense + energies (round-2 body, 256 blocks) ----------------
__global__ __launch_bounds__(256) void energies_kernel(
    const float* __restrict__ aw, const float* __restrict__ awc,
    const float* __restrict__ lc, const float* __restrict__ ld,
    const float* __restrict__ vvec, const float* __restrict__ pq,
    const float* __restrict__ pm, float* __restrict__ energ)
{
    const int b = blockIdx.x, tc = blockIdx.y;
    const int t0 = tc * 128;
    const int tid = threadIdx.x;
    __shared__ float awin[160], awcin[160];
    __shared__ float lcs[NFILT * 62];          // [f][2][31]
    __shared__ float locs[128 * 33];           // conv out [t][f], padded
    __shared__ float pqs[ATTD], vs[ATTD];
    __shared__ float ldm[ATTD * NFILT];        // loc_dense [a][f]
    __shared__ float ered[256];

    for (int i = tid; i < 158; i += 256) {
        int t = t0 + i - CPAD;
        bool ok = (t >= 0 && t < TIN);
        awin[i]  = ok ? aw[b * TIN + t]  : 0.f;
        awcin[i] = ok ? awc[b * TIN + t] : 0.f;
    }
    for (int i = tid; i < NFILT * 62; i += 256) lcs[i] = lc[i];
    for (int i = tid; i < ATTD * NFILT; i += 256) ldm[i] = ld[i];
    if (tid < ATTD) { pqs[tid] = pq[b * ATTD + tid]; vs[tid] = vvec[tid]; }
    __syncthreads();

    // conv: 128 t x 32 f outputs
    for (int idx = tid; idx < 128 * 32; idx += 256) {
        int tl = idx >> 5, f = idx & 31;
        const float* w0 = lcs + f * 62;
        float s = 0.f;
#pragma unroll
        for (int k = 0; k < KSZ; ++k)
            s += awin[tl + k] * w0[k] + awcin[tl + k] * w0[31 + k];
        locs[tl * 33 + f] = s;
    }
    __syncthreads();

    // energies: thread pair (tl, half) covers 64 a each
    const int tl = tid >> 1, half = tid & 1;
    float e = 0.f;
    const float* pmrow = pm + (size_t)b * (TIN * ATTD) + (size_t)(t0 + tl) * ATTD + half * 64;
    const float* lt = locs + tl * 33;
    for (int a = 0; a < 64; ++a) {
        const float* lrow = ldm + (half * 64 + a) * 32;
        float s = pqs[half * 64 + a] + pmrow[a];
#pragma unroll
        for (int f = 0; f < NFILT; ++f) s += lt[f] * lrow[f];
        e += vs[half * 64 + a] * tanhf(s);
    }
    ered[tid] = e;
    __syncthreads();
    if (half == 0) energ[b * TIN + t0 + tl] = ered[tid] + ered[tid + 1];
}

// ---------------- L3: masked softmax + aw/awc update + alignments + ctx (round-2 body) ----------------
__global__ __launch_bounds__(256) void softmax_ctx_kernel(
    const float* __restrict__ energ, const int* __restrict__ mlen,
    const float* __restrict__ memory,
    float* __restrict__ aw, float* __restrict__ awc,
    float* __restrict__ out_align, int t_step,
    float* __restrict__ xcat_att, float* __restrict__ xcat_dec)
{
    const int b = blockIdx.x, tid = threadIdx.x;
    const int len = mlen[b];
    __shared__ float es[TIN];
    __shared__ float red[256];
    __shared__ float ms[8][ENC];

    float e1 = (tid < len) ? energ[b * TIN + tid] : -INFINITY;
    float e2 = (tid + 256 < len) ? energ[b * TIN + tid + 256] : -INFINITY;
    red[tid] = fmaxf(e1, e2);
    __syncthreads();
    for (int s = 128; s > 0; s >>= 1) {
        if (tid < s) red[tid] = fmaxf(red[tid], red[tid + s]);
        __syncthreads();
    }
    const float mx = red[0];
    __syncthreads();
    float p1 = expf(e1 - mx);
    float p2 = expf(e2 - mx);
    red[tid] = p1 + p2;
    __syncthreads();
    for (int s = 128; s > 0; s >>= 1) {
        if (tid < s) red[tid] += red[tid + s];
        __syncthreads();
    }
    const float inv = 1.f / red[0];
    p1 *= inv; p2 *= inv;
    es[tid] = p1; es[tid + 256] = p2;

    aw[b * TIN + tid] = p1;          aw[b * TIN + tid + 256] = p2;
    awc[b * TIN + tid] += p1;        awc[b * TIN + tid + 256] += p2;
    size_t ao = (size_t)b * (TOUT * TIN) + (size_t)t_step * TIN;
    out_align[ao + tid] = p1;        out_align[ao + tid + 256] = p2;

    // ctx[d] = sum_t aw[t] * memory[b,t,d]
    float c1 = 0.f, c2 = 0.f;
    for (int tc = 0; tc < TIN; tc += 8) {
        __syncthreads();
#pragma unroll
        for (int i = 0; i < 16; ++i) {
            int flat = i * 256 + tid;
            int tt = flat >> 9, d = flat & 511;
            ms[tt][d] = memory[(size_t)b * (TIN * ENC) + (size_t)(tc + tt) * ENC + d];
        }
        __syncthreads();
#pragma unroll
        for (int j = 0; j < 8; ++j) {
            float a_ = es[tc + j];
            c1 += a_ * ms[j][tid];
            c2 += a_ * ms[j][tid + 256];
        }
    }
    xcat_att[b * 1536 + tid] = c1;
    xcat_att[b * 1536 + 256 + tid] = c2;
    xcat_dec[b * 2560 + 1024 + tid] = c1;
    xcat_dec[b * 2560 + 1024 + 256 + tid] = c2;
}

extern "C" void kernel_launch(void* const* d_in, const int* in_sizes, int n_in,
                              void* d_out, int out_size, void* d_ws, size_t ws_size,
                              hipStream_t stream) {
    const float* memory   = (const float*)d_in[0];
    const float* dec_in   = (const float*)d_in[1];
    const int*   mlen     = (const int*)d_in[2];
    const float* pw1      = (const float*)d_in[3];
    const float* pw2      = (const float*)d_in[4];
    const float* att_wih  = (const float*)d_in[5];
    const float* att_whh  = (const float*)d_in[6];
    const float* att_bih  = (const float*)d_in[7];
    const float* att_bhh  = (const float*)d_in[8];
    const float* wq       = (const float*)d_in[9];
    const float* wm       = (const float*)d_in[10];
    const float* v        = (const float*)d_in[11];
    const float* loc_conv = (const float*)d_in[12];
    const float* loc_dense= (const float*)d_in[13];
    const float* dec_wih  = (const float*)d_in[14];
    const float* dec_whh  = (const float*)d_in[15];
    const float* dec_bih  = (const float*)d_in[16];
    const float* dec_bhh  = (const float*)d_in[17];
    const float* proj_w   = (const float*)d_in[18];
    const float* proj_b   = (const float*)d_in[19];
    const float* gate_w   = (const float*)d_in[20];
    const float* gate_b   = (const float*)d_in[21];
    float* out = (float*)d_out;

    // ---- ws layout ----
    float* x        = (float*)d_ws;
    float* pm       = x + X_SZ;
    float* g1       = pm + PM_SZ;
    float* g2       = g1 + G1_SZ;
    float* xcat_att = g2 + G2_SZ;
    float* xcat_dec = xcat_att + XATT_SZ;
    float* ac       = xcat_dec + XDEC_SZ;
    float* dc       = ac + AC_SZ;
    float* aw       = dc + DC_SZ;
    float* awc      = aw + AW_SZ;
    float* pq       = awc + AWC_SZ;
    float* energ    = pq + PQ_SZ;
    unsigned char* m1 = (unsigned char*)(energ + EN_SZ);
    unsigned char* m2 = m1 + MASK_N;
    size_t need = (size_t)(m2 + MASK_N - (unsigned char*)d_ws);
    if (ws_size < need) return;

    // zero recurrent state (xcat_att..awc contiguous)
    size_t state_floats = (size_t)XATT_SZ + XDEC_SZ + AC_SZ + DC_SZ + AW_SZ + AWC_SZ;
    hipMemsetAsync(xcat_att, 0, state_floats * sizeof(float), stream);

    // one-time: dropout masks, prenet, processed memory
    mask_kernel<<<(MASK_N + 255) / 256, 256, 0, stream>>>(m1, m2);
    prenet1_kernel<<<TOUT * NB, 256, 0, stream>>>(dec_in, pw1, m1, x);
    prenet2_kernel<<<TOUT * NB, 256, 0, stream>>>(pw2, m2, x);
    pm_kernel<<<dim3(NB, TIN), 128, 0, stream>>>(memory, wm, pm);

    float* out_align = out + ALGN_OFF;

    // prologue: gemm1 for t=0 (gemm2 half no-ops via t=-1)
    pair_gemm<<<512, 256, 0, stream>>>(xcat_dec, dec_wih, dec_whh, g2,
                                       x, xcat_att, att_wih, att_whh, g1, -1);

    for (int t = 0; t < TOUT; ++t) {
        // L1: att_pointwise(t) || dec_pointwise+proj(t-1)
        pair_pw<<<128, 256, 0, stream>>>(g1, att_bih, att_bhh, ac, xcat_att, xcat_dec, wq, pq,
                                         g2, dec_bih, dec_bhh, dc, proj_w, proj_b,
                                         gate_w, gate_b, out, t);
        // L2: energies(t)
        energies_kernel<<<dim3(NB, 4), 256, 0, stream>>>(aw, awc, loc_conv, loc_dense, v, pq, pm, energ);
        // L3: softmax + ctx (t)
        softmax_ctx_kernel<<<NB, 256, 0, stream>>>(energ, mlen, memory, aw, awc, out_align, t,
                                                   xcat_att, xcat_dec);
        // L4: gemm2(t) || gemm1(t+1)
        pair_gemm<<<512, 256, 0, stream>>>(xcat_dec, dec_wih, dec_whh, g2,
                                           x, xcat_att, att_wih, att_whh, g1, t);
    }
    // epilogue: dec_pointwise+proj for t=499 (att half no-ops via t=TOUT)
    pair_pw<<<128, 256, 0, stream>>>(g1, att_bih, att_bhh, ac, xcat_att, xcat_dec, wq, pq,
                                     g2, dec_bih, dec_bhh, dc, proj_w, proj_b,
                                     gate_w, gate_b, out, TOUT);
}

// Round 6
// 94746.350 us; speedup vs baseline: 2.6014x; 1.2364x over previous
//
#include <hip/hip_runtime.h>
#include <cstdint>
#include <cstddef>

// ---------------- constants ----------------
#define NB    64      // batch
#define TIN   512
#define TOUT  500
#define NMEL  80
#define ENC   512
#define ATTD  128
#define ARNN  1024
#define DRNN  1024
#define PREN  256
#define NFILT 32
#define KSZ   31
#define CPAD  15

#define MEL_OFF  0
#define GATE_OFF 2560000
#define ALGN_OFF 2592000

// ws float-layout sizes
#define X_SZ      8192000   // prenet output [500][64][256]
#define PM_SZ     4194304   // processed memory [64][512][128]
#define G1_SZ     1048576   // gemm1 out (fp32 path: [4][64][4096] partials; mfma: [64][4096])
#define G2_SZ     1048576
#define XATT_SZ   98304     // fp32 [64][1536] = [ctx|ah]
#define XDEC_SZ   163840    // fp32 [64][2560] = [ah|ctx|dh]
#define AC_SZ     65536
#define DC_SZ     65536
#define AW_SZ     32768
#define AWC_SZ    32768
#define TAILH_SZ  49152     // bf16 [64][1536] hi  (in float-slots, 2 u16/slot)
#define TAILL_SZ  49152
#define XDH_SZ    81920     // bf16 [64][2560] hi
#define XDL_SZ    81920
#define PQ_SZ     8192
#define EN_SZ     32768
#define MASK_N    8208384   // 501*64*256

// bf16 weight u16 element counts
#define AWIH_N  3145728   // 4096*768
#define AWHH_N  4194304   // 4096*1024
#define DWIH_N  6291456   // 4096*1536
#define DWHH_N  4194304   // 4096*1024

typedef unsigned short u16;
typedef __attribute__((ext_vector_type(8))) short bf16x8;
typedef __attribute__((ext_vector_type(4))) float f32x4;

__device__ __forceinline__ float sigf(float x) { return 1.f / (1.f + expf(-x)); }
__device__ __forceinline__ uint32_t rotl32(uint32_t v, int r) { return (v << r) | (v >> (32 - r)); }

// Dekker-style split: hi = truncate-to-bf16(v), lo = rn-bf16(v - hi). hi+lo ~ 16-bit mantissa.
__device__ __forceinline__ void split1(float v, u16& h, u16& l) {
    uint32_t u = __float_as_uint(v);
    h = (u16)(u >> 16);
    float r = v - __uint_as_float(u & 0xFFFF0000u);
    uint32_t ru = __float_as_uint(r);
    ru += 0x7FFFu + ((ru >> 16) & 1u);
    l = (u16)(ru >> 16);
}

__device__ __forceinline__ void split8(float4 f0, float4 f1, bf16x8& h, bf16x8& l) {
    float v[8] = { f0.x, f0.y, f0.z, f0.w, f1.x, f1.y, f1.z, f1.w };
#pragma unroll
    for (int i = 0; i < 8; ++i) {
        uint32_t u = __float_as_uint(v[i]);
        h[i] = (short)(u >> 16);
        float r = v[i] - __uint_as_float(u & 0xFFFF0000u);
        uint32_t ru = __float_as_uint(r);
        ru += 0x7FFFu + ((ru >> 16) & 1u);
        l[i] = (short)(ru >> 16);
    }
}

#define MFMA16(a, b, c) __builtin_amdgcn_mfma_f32_16x16x32_bf16(a, b, c, 0, 0, 0)

// JAX threefry2x32
__device__ void tf_block(uint32_t k1, uint32_t k2, uint32_t& x0, uint32_t& x1) {
    uint32_t ks0 = k1, ks1 = k2, ks2 = k1 ^ k2 ^ 0x1BD11BDAu;
    x0 += ks0; x1 += ks1;
#define TFR(r) { x0 += x1; x1 = rotl32(x1, r); x1 ^= x0; }
    TFR(13) TFR(15) TFR(26) TFR(6)   x0 += ks1; x1 += ks2 + 1u;
    TFR(17) TFR(29) TFR(16) TFR(24)  x0 += ks2; x1 += ks0 + 2u;
    TFR(13) TFR(15) TFR(26) TFR(6)   x0 += ks0; x1 += ks1 + 3u;
    TFR(17) TFR(29) TFR(16) TFR(24)  x0 += ks1; x1 += ks2 + 4u;
    TFR(13) TFR(15) TFR(26) TFR(6)   x0 += ks2; x1 += ks0 + 5u;
#undef TFR
}

__global__ __launch_bounds__(256) void mask_kernel(unsigned char* m1, unsigned char* m2) {
    int i = blockIdx.x * 256 + threadIdx.x;
    if (i >= MASK_N) return;
    uint32_t a0 = 0u, a1 = 0u; tf_block(0u, 42u, a0, a1);
    uint32_t b0 = 0u, b1 = 1u; tf_block(0u, 42u, b0, b1);
    uint32_t x0, x1;
    x0 = 0u; x1 = (uint32_t)i; tf_block(a0, a1, x0, x1);
    m1[i] = ((x0 ^ x1) >> 31) == 0u;
    x0 = 0u; x1 = (uint32_t)i; tf_block(b0, b1, x0, x1);
    m2[i] = ((x0 ^ x1) >> 31) == 0u;
}

__global__ __launch_bounds__(256) void prenet1_kernel(
    const float* __restrict__ dec_in, const float* __restrict__ w1,
    const unsigned char* __restrict__ m1, float* __restrict__ x)
{
    int r = blockIdx.x;
    int t = r >> 6, b = r & 63;
    int tid = threadIdx.x;
    __shared__ float ds[NMEL];
    if (tid < NMEL) ds[tid] = (t == 0) ? 0.f : dec_in[(size_t)b * 40000 + tid * 500 + (t - 1)];
    __syncthreads();
    float acc = 0.f;
    const float* w = w1 + tid * NMEL;
#pragma unroll
    for (int k = 0; k < NMEL; ++k) acc += ds[k] * w[k];
    acc = fmaxf(acc, 0.f);
    int flat = r * 256 + tid;
    x[flat] = m1[flat] ? acc * 2.f : 0.f;
}

__global__ __launch_bounds__(256) void prenet2_kernel(
    const float* __restrict__ w2, const unsigned char* __restrict__ m2, float* x)
{
    int r = blockIdx.x;
    int tid = threadIdx.x;
    __shared__ float xs[PREN];
    xs[tid] = x[r * 256 + tid];
    __syncthreads();
    float acc = 0.f;
    const float* w = w2 + tid * PREN;
#pragma unroll 8
    for (int k = 0; k < PREN; ++k) acc += xs[k] * w[k];
    acc = fmaxf(acc, 0.f);
    int flat = r * 256 + tid;
    x[flat] = m2[flat] ? acc * 2.f : 0.f;
}

__global__ __launch_bounds__(128) void pm_kernel(
    const float* __restrict__ memory, const float* __restrict__ wm, float* __restrict__ pm)
{
    int b = blockIdx.x, t = blockIdx.y;
    int tid = threadIdx.x;
    __shared__ float ms[ENC];
    for (int i = tid; i < ENC; i += 128) ms[i] = memory[(size_t)b * (TIN * ENC) + (size_t)t * ENC + i];
    __syncthreads();
    float acc = 0.f;
    const float* w = wm + tid * ENC;
#pragma unroll 8
    for (int k = 0; k < ENC; ++k) acc += ms[k] * w[k];
    pm[(size_t)b * (TIN * ATTD) + t * ATTD + tid] = acc;
}

// one-time weight split fp32 -> bf16 hi/lo
__global__ __launch_bounds__(256) void wsplit_kernel(
    const float* __restrict__ src, u16* __restrict__ hi, u16* __restrict__ lo, int n)
{
    int i = blockIdx.x * 256 + threadIdx.x;
    if (i >= n) return;
    u16 h, l;
    split1(src[i], h, l);
    hi[i] = h; lo[i] = l;
}

// ---------------- fp32 fallback K-split GEMM (round-5 body, proven) ----------------
struct SmemGemm { float Xs[32][68]; float Ws[32][68]; };

__device__ void gemm_phase(
    const float* __restrict__ X1, int ldx1, int kx1,
    const float* __restrict__ X2, int ldx2,
    const float* __restrict__ W1, int ldw1, int kw1,
    const float* __restrict__ W2, int ldw2,
    float* __restrict__ outp, int Kq, int blk, SmemGemm& s)
{
    const int tid = threadIdx.x;
    const int n0 = (blk & 63) * 64;
    const int ks = blk >> 6;
    const int kbeg = ks * Kq;
    const int tn = tid & 15, tm = tid >> 4;
    float acc[4][4];
#pragma unroll
    for (int i = 0; i < 4; ++i)
#pragma unroll
        for (int j = 0; j < 4; ++j) acc[i][j] = 0.f;

#pragma unroll 1
    for (int k0 = kbeg; k0 < kbeg + Kq; k0 += 32) {
#pragma unroll
        for (int i = 0; i < 8; ++i) {
            int flat = i * 256 + tid;
            int m = flat >> 5, c = flat & 31;
            int k = k0 + c;
            s.Xs[c][m] = (k < kx1) ? X1[m * ldx1 + k] : X2[m * ldx2 + (k - kx1)];
        }
#pragma unroll
        for (int i = 0; i < 8; ++i) {
            int flat = i * 256 + tid;
            int r = flat >> 5, c = flat & 31;
            int k = k0 + c;
            int n = n0 + r;
            s.Ws[c][r] = (k < kw1) ? W1[n * ldw1 + k] : W2[n * ldw2 + (k - kw1)];
        }
        __syncthreads();
#pragma unroll
        for (int kk = 0; kk < 32; ++kk) {
            float4 xv = *(const float4*)&s.Xs[kk][tm * 4];
            float4 wv = *(const float4*)&s.Ws[kk][tn * 4];
            float xr[4] = { xv.x, xv.y, xv.z, xv.w };
            float wr[4] = { wv.x, wv.y, wv.z, wv.w };
#pragma unroll
            for (int i = 0; i < 4; ++i)
#pragma unroll
                for (int j = 0; j < 4; ++j) acc[i][j] += xr[i] * wr[j];
        }
        __syncthreads();
    }
    float* o = outp + (size_t)ks * 64 * 4096;
#pragma unroll
    for (int i = 0; i < 4; ++i)
#pragma unroll
        for (int j = 0; j < 4; ++j)
            o[(tm * 4 + i) * 4096 + (n0 + tn * 4 + j)] = acc[i][j];
}

__global__ __launch_bounds__(256, 2) void pair_gemm(
    const float* __restrict__ xcat_dec,
    const float* __restrict__ dec_wih, const float* __restrict__ dec_whh,
    float* __restrict__ g2,
    const float* __restrict__ x, const float* __restrict__ xcat_att,
    const float* __restrict__ att_wih, const float* __restrict__ att_whh,
    float* __restrict__ g1, int t)
{
    __shared__ __align__(16) SmemGemm sm;
    const int blk = blockIdx.x;
    if (blk < 256) {
        if (t < 0) return;
        gemm_phase(xcat_dec, 2560, 2560, xcat_dec, 2560,
                   dec_wih, 1536, 1536, dec_whh, 1024, g2, 640, blk, sm);
    } else {
        const int tn = t + 1;
        if (tn >= TOUT) return;
        gemm_phase(x + (size_t)tn * (NB * PREN), PREN, PREN, xcat_att, 1536,
                   att_wih, 768, 768, att_whh, 1024, g1, 448, blk - 256, sm);
    }
}

// ---------------- MFMA pair gemm: gemm2(t) [blk 0-127] || gemm1(t+1) [blk 128-255] ----------------
// Per block: 4 waves, wave w owns m-rows 16w..16w+15; block covers 32 n-cols.
// Per k0 (32 k): A hi/lo frag (16B ds-free direct loads), 2 n-tiles x (Bhi,Blo), 6 MFMA.
__global__ __launch_bounds__(256) void mfma_pair_gemm(
    const u16* __restrict__ xdech, const u16* __restrict__ xdecl,
    const u16* __restrict__ dwih_h, const u16* __restrict__ dwih_l,
    const u16* __restrict__ dwhh_h, const u16* __restrict__ dwhh_l,
    float* __restrict__ g2,
    const float* __restrict__ x,
    const u16* __restrict__ tailh, const u16* __restrict__ taill,
    const u16* __restrict__ awih_h, const u16* __restrict__ awih_l,
    const u16* __restrict__ awhh_h, const u16* __restrict__ awhh_l,
    float* __restrict__ g1, int t)
{
    const int blk = blockIdx.x;
    const int tid = threadIdx.x;
    const int wave = tid >> 6, lane = tid & 63;
    const int lr = lane & 15, kg = lane >> 4;
    const int mrow = wave * 16 + lr;
    f32x4 acc0 = {0.f, 0.f, 0.f, 0.f}, acc1 = {0.f, 0.f, 0.f, 0.f};

    if (blk < 128) {
        if (t < 0) return;
        const int n0 = blk * 32;
        const int nA = n0 + lr, nB = n0 + 16 + lr;
        const u16* Ah = xdech + mrow * 2560;
        const u16* Al = xdecl + mrow * 2560;
#pragma unroll 2
        for (int k0 = 0; k0 < 2560; k0 += 32) {
            const int k = k0 + kg * 8;
            bf16x8 ah = *(const bf16x8*)(Ah + k);
            bf16x8 al = *(const bf16x8*)(Al + k);
            const u16 *bh0, *bl0, *bh1, *bl1;
            if (k < 1536) {
                bh0 = dwih_h + nA * 1536 + k;  bl0 = dwih_l + nA * 1536 + k;
                bh1 = dwih_h + nB * 1536 + k;  bl1 = dwih_l + nB * 1536 + k;
            } else {
                const int kk = k - 1536;
                bh0 = dwhh_h + nA * 1024 + kk; bl0 = dwhh_l + nA * 1024 + kk;
                bh1 = dwhh_h + nB * 1024 + kk; bl1 = dwhh_l + nB * 1024 + kk;
            }
            bf16x8 b0h = *(const bf16x8*)bh0, b0l = *(const bf16x8*)bl0;
            bf16x8 b1h = *(const bf16x8*)bh1, b1l = *(const bf16x8*)bl1;
            acc0 = MFMA16(ah, b0h, acc0); acc0 = MFMA16(ah, b0l, acc0); acc0 = MFMA16(al, b0h, acc0);
            acc1 = MFMA16(ah, b1h, acc1); acc1 = MFMA16(ah, b1l, acc1); acc1 = MFMA16(al, b1h, acc1);
        }
        const int mbase = wave * 16 + kg * 4;
#pragma unroll
        for (int r = 0; r < 4; ++r) {
            g2[(mbase + r) * 4096 + n0 + lr]      = acc0[r];
            g2[(mbase + r) * 4096 + n0 + 16 + lr] = acc1[r];
        }
    } else {
        const int tn = t + 1;
        if (tn >= TOUT) return;
        const int n0 = (blk - 128) * 32;
        const int nA = n0 + lr, nB = n0 + 16 + lr;
        const u16* Ah = tailh + mrow * 1536;
        const u16* Al = taill + mrow * 1536;
        const float* xr = x + ((size_t)tn * 64 + mrow) * 256;
#pragma unroll 1
        for (int k0 = 0; k0 < 1792; k0 += 32) {
            const int k = k0 + kg * 8;
            bf16x8 ah, al;
            if (k < 256) {
                float4 f0 = *(const float4*)(xr + k);
                float4 f1 = *(const float4*)(xr + k + 4);
                split8(f0, f1, ah, al);
            } else {
                ah = *(const bf16x8*)(Ah + (k - 256));
                al = *(const bf16x8*)(Al + (k - 256));
            }
            const u16 *bh0, *bl0, *bh1, *bl1;
            if (k < 768) {
                bh0 = awih_h + nA * 768 + k;  bl0 = awih_l + nA * 768 + k;
                bh1 = awih_h + nB * 768 + k;  bl1 = awih_l + nB * 768 + k;
            } else {
                const int kk = k - 768;
                bh0 = awhh_h + nA * 1024 + kk; bl0 = awhh_l + nA * 1024 + kk;
                bh1 = awhh_h + nB * 1024 + kk; bl1 = awhh_l + nB * 1024 + kk;
            }
            bf16x8 b0h = *(const bf16x8*)bh0, b0l = *(const bf16x8*)bl0;
            bf16x8 b1h = *(const bf16x8*)bh1, b1l = *(const bf16x8*)bl1;
            acc0 = MFMA16(ah, b0h, acc0); acc0 = MFMA16(ah, b0l, acc0); acc0 = MFMA16(al, b0h, acc0);
            acc1 = MFMA16(ah, b1h, acc1); acc1 = MFMA16(ah, b1l, acc1); acc1 = MFMA16(al, b1h, acc1);
        }
        const int mbase = wave * 16 + kg * 4;
#pragma unroll
        for (int r = 0; r < 4; ++r) {
            g1[(mbase + r) * 4096 + n0 + lr]      = acc0[r];
            g1[(mbase + r) * 4096 + n0 + 16 + lr] = acc1[r];
        }
    }
}

// ---------------- L1: att_pointwise(t) || dec_pointwise+proj(t-1) ----------------
__global__ __launch_bounds__(256) void pair_pw(
    const float* __restrict__ g1, const float* __restrict__ att_bih, const float* __restrict__ att_bhh,
    float* __restrict__ ac, float* __restrict__ xcat_att, float* __restrict__ xcat_dec,
    const float* __restrict__ wq, float* __restrict__ pq,
    const float* __restrict__ g2, const float* __restrict__ dec_bih, const float* __restrict__ dec_bhh,
    float* __restrict__ dc, const float* __restrict__ proj_w, const float* __restrict__ proj_b,
    const float* __restrict__ gate_w, const float* __restrict__ gate_b,
    float* __restrict__ out,
    u16* __restrict__ tailh, u16* __restrict__ taill,
    u16* __restrict__ xdech, u16* __restrict__ xdecl,
    int nsplit, int t)
{
    const int tid = threadIdx.x;
    __shared__ float sbuf[1536];
    __shared__ float red[256];

    if (blockIdx.x < 64) {
        if (t >= TOUT) return;
        const int b = blockIdx.x;
#pragma unroll
        for (int q = 0; q < 4; ++q) {
            int j = q * 256 + tid;
            float gi = att_bih[j] + att_bhh[j];
            float gf = att_bih[1024 + j] + att_bhh[1024 + j];
            float gg = att_bih[2048 + j] + att_bhh[2048 + j];
            float go = att_bih[3072 + j] + att_bhh[3072 + j];
            for (int s = 0; s < nsplit; ++s) {
                const float* g = g1 + (size_t)s * 262144 + b * 4096;
                gi += g[j]; gf += g[1024 + j]; gg += g[2048 + j]; go += g[3072 + j];
            }
            float c = sigf(gf) * ac[b * 1024 + j] + sigf(gi) * tanhf(gg);
            float h = sigf(go) * tanhf(c);
            ac[b * 1024 + j] = c;
            xcat_att[b * 1536 + 512 + j] = h;
            xcat_dec[b * 2560 + j] = h;
            u16 hh, hl; split1(h, hh, hl);
            tailh[b * 1536 + 512 + j] = hh;  taill[b * 1536 + 512 + j] = hl;
            xdech[b * 2560 + j] = hh;        xdecl[b * 2560 + j] = hl;
            sbuf[j] = h;
        }
        __syncthreads();
        const int a = tid & 127, half = tid >> 7;
        float s = 0.f;
        const float* wr = wq + a * 1024 + half * 512;
        const float* hh = sbuf + half * 512;
#pragma unroll 4
        for (int k = 0; k < 512; k += 4) {
            float4 wv = *(const float4*)&wr[k];
            float4 hv = *(const float4*)&hh[k];
            s += hv.x * wv.x + hv.y * wv.y + hv.z * wv.z + hv.w * wv.w;
        }
        red[tid] = s;
        __syncthreads();
        if (half == 0) pq[b * 128 + a] = red[a] + red[a + 128];
    } else {
        if (t < 1) return;
        const int b = blockIdx.x - 64;
        const int ts = t - 1;
#pragma unroll
        for (int q = 0; q < 4; ++q) {
            int j = q * 256 + tid;
            float gi = dec_bih[j] + dec_bhh[j];
            float gf = dec_bih[1024 + j] + dec_bhh[1024 + j];
            float gg = dec_bih[2048 + j] + dec_bhh[2048 + j];
            float go = dec_bih[3072 + j] + dec_bhh[3072 + j];
            for (int s = 0; s < nsplit; ++s) {
                const float* g = g2 + (size_t)s * 262144 + b * 4096;
                gi += g[j]; gf += g[1024 + j]; gg += g[2048 + j]; go += g[3072 + j];
            }
            float c = sigf(gf) * dc[b * 1024 + j] + sigf(gi) * tanhf(gg);
            float h = sigf(go) * tanhf(c);
            dc[b * 1024 + j] = c;
            xcat_dec[b * 2560 + 1536 + j] = h;
            u16 hh, hl; split1(h, hh, hl);
            xdech[b * 2560 + 1536 + j] = hh;  xdecl[b * 2560 + 1536 + j] = hl;
            sbuf[j] = h;
        }
        for (int i = tid; i < 512; i += 256) sbuf[1024 + i] = xcat_dec[b * 2560 + 1024 + i];
        __syncthreads();
        const int o = tid >> 1, half = tid & 1;
        float accv = 0.f;
        if (o <= 80) {
            const float* w = (o < 80) ? (proj_w + o * 1536) : gate_w;
            const float* sv = sbuf + half * 768;
            const float* wv = w + half * 768;
#pragma unroll 4
            for (int k = 0; k < 768; k += 4) {
                float4 a4 = *(const float4*)&sv[k];
                float4 b4 = *(const float4*)&wv[k];
                accv += a4.x * b4.x + a4.y * b4.y + a4.z * b4.z + a4.w * b4.w;
            }
        }
        red[tid] = accv;
        __syncthreads();
        if (half == 0 && o <= 80) {
            float r = red[tid] + red[tid + 1];
            if (o < 80)
                out[MEL_OFF + (size_t)b * (TOUT * NMEL) + (size_t)ts * NMEL + o] = r + proj_b[o];
            else
                out[GATE_OFF + (size_t)b * TOUT + ts] = r + gate_b[0];
        }
    }
}

// ---------------- L2: conv + loc_dense + energies ----------------
__global__ __launch_bounds__(256) void energies_kernel(
    const float* __restrict__ aw, const float* __restrict__ awc,
    const float* __restrict__ lc, const float* __restrict__ ld,
    const float* __restrict__ vvec, const float* __restrict__ pq,
    const float* __restrict__ pm, float* __restrict__ energ)
{
    const int b = blockIdx.x, tc = blockIdx.y;
    const int t0 = tc * 128;
    const int tid = threadIdx.x;
    __shared__ float awin[160], awcin[160];
    __shared__ float lcs[NFILT * 62];
    __shared__ float locs[128 * 33];
    __shared__ float pqs[ATTD], vs[ATTD];
    __shared__ float ldm[ATTD * NFILT];
    __shared__ float ered[256];

    for (int i = tid; i < 158; i += 256) {
        int t = t0 + i - CPAD;
        bool ok = (t >= 0 && t < TIN);
        awin[i]  = ok ? aw[b * TIN + t]  : 0.f;
        awcin[i] = ok ? awc[b * TIN + t] : 0.f;
    }
    for (int i = tid; i < NFILT * 62; i += 256) lcs[i] = lc[i];
    for (int i = tid; i < ATTD * NFILT; i += 256) ldm[i] = ld[i];
    if (tid < ATTD) { pqs[tid] = pq[b * ATTD + tid]; vs[tid] = vvec[tid]; }
    __syncthreads();

    for (int idx = tid; idx < 128 * 32; idx += 256) {
        int tl = idx >> 5, f = idx & 31;
        const float* w0 = lcs + f * 62;
        float s = 0.f;
#pragma unroll
        for (int k = 0; k < KSZ; ++k)
            s += awin[tl + k] * w0[k] + awcin[tl + k] * w0[31 + k];
        locs[tl * 33 + f] = s;
    }
    __syncthreads();

    const int tl = tid >> 1, half = tid & 1;
    float e = 0.f;
    const float* pmrow = pm + (size_t)b * (TIN * ATTD) + (size_t)(t0 + tl) * ATTD + half * 64;
    const float* lt = locs + tl * 33;
    for (int a = 0; a < 64; ++a) {
        const float* lrow = ldm + (half * 64 + a) * 32;
        float s = pqs[half * 64 + a] + pmrow[a];
#pragma unroll
        for (int f = 0; f < NFILT; ++f) s += lt[f] * lrow[f];
        e += vs[half * 64 + a] * tanhf(s);
    }
    ered[tid] = e;
    __syncthreads();
    if (half == 0) energ[b * TIN + t0 + tl] = ered[tid] + ered[tid + 1];
}

// ---------------- L3: masked softmax + aw/awc + alignments + ctx ----------------
__global__ __launch_bounds__(256) void softmax_ctx_kernel(
    const float* __restrict__ energ, const int* __restrict__ mlen,
    const float* __restrict__ memory,
    float* __restrict__ aw, float* __restrict__ awc,
    float* __restrict__ out_align, int t_step,
    float* __restrict__ xcat_att, float* __restrict__ xcat_dec,
    u16* __restrict__ tailh, u16* __restrict__ taill,
    u16* __restrict__ xdech, u16* __restrict__ xdecl)
{
    const int b = blockIdx.x, tid = threadIdx.x;
    const int len = mlen[b];
    __shared__ float es[TIN];
    __shared__ float red[256];
    __shared__ float ms[8][ENC];

    float e1 = (tid < len) ? energ[b * TIN + tid] : -INFINITY;
    float e2 = (tid + 256 < len) ? energ[b * TIN + tid + 256] : -INFINITY;
    red[tid] = fmaxf(e1, e2);
    __syncthreads();
    for (int s = 128; s > 0; s >>= 1) {
        if (tid < s) red[tid] = fmaxf(red[tid], red[tid + s]);
        __syncthreads();
    }
    const float mx = red[0];
    __syncthreads();
    float p1 = expf(e1 - mx);
    float p2 = expf(e2 - mx);
    red[tid] = p1 + p2;
    __syncthreads();
    for (int s = 128; s > 0; s >>= 1) {
        if (tid < s) red[tid] += red[tid + s];
        __syncthreads();
    }
    const float inv = 1.f / red[0];
    p1 *= inv; p2 *= inv;
    es[tid] = p1; es[tid + 256] = p2;

    aw[b * TIN + tid] = p1;          aw[b * TIN + tid + 256] = p2;
    awc[b * TIN + tid] += p1;        awc[b * TIN + tid + 256] += p2;
    size_t ao = (size_t)b * (TOUT * TIN) + (size_t)t_step * TIN;
    out_align[ao + tid] = p1;        out_align[ao + tid + 256] = p2;

    float c1 = 0.f, c2 = 0.f;
    for (int tc = 0; tc < TIN; tc += 8) {
        __syncthreads();
#pragma unroll
        for (int i = 0; i < 16; ++i) {
            int flat = i * 256 + tid;
            int tt = flat >> 9, d = flat & 511;
            ms[tt][d] = memory[(size_t)b * (TIN * ENC) + (size_t)(tc + tt) * ENC + d];
        }
        __syncthreads();
#pragma unroll
        for (int j = 0; j < 8; ++j) {
            float a_ = es[tc + j];
            c1 += a_ * ms[j][tid];
            c2 += a_ * ms[j][tid + 256];
        }
    }
    xcat_att[b * 1536 + tid] = c1;
    xcat_att[b * 1536 + 256 + tid] = c2;
    xcat_dec[b * 2560 + 1024 + tid] = c1;
    xcat_dec[b * 2560 + 1024 + 256 + tid] = c2;
    u16 h1, l1, h2, l2;
    split1(c1, h1, l1); split1(c2, h2, l2);
    tailh[b * 1536 + tid] = h1;        taill[b * 1536 + tid] = l1;
    tailh[b * 1536 + 256 + tid] = h2;  taill[b * 1536 + 256 + tid] = l2;
    xdech[b * 2560 + 1024 + tid] = h1;        xdecl[b * 2560 + 1024 + tid] = l1;
    xdech[b * 2560 + 1024 + 256 + tid] = h2;  xdecl[b * 2560 + 1024 + 256 + tid] = l2;
}

extern "C" void kernel_launch(void* const* d_in, const int* in_sizes, int n_in,
                              void* d_out, int out_size, void* d_ws, size_t ws_size,
                              hipStream_t stream) {
    const float* memory   = (const float*)d_in[0];
    const float* dec_in   = (const float*)d_in[1];
    const int*   mlen     = (const int*)d_in[2];
    const float* pw1      = (const float*)d_in[3];
    const float* pw2      = (const float*)d_in[4];
    const float* att_wih  = (const float*)d_in[5];
    const float* att_whh  = (const float*)d_in[6];
    const float* att_bih  = (const float*)d_in[7];
    const float* att_bhh  = (const float*)d_in[8];
    const float* wq       = (const float*)d_in[9];
    const float* wm       = (const float*)d_in[10];
    const float* v        = (const float*)d_in[11];
    const float* loc_conv = (const float*)d_in[12];
    const float* loc_dense= (const float*)d_in[13];
    const float* dec_wih  = (const float*)d_in[14];
    const float* dec_whh  = (const float*)d_in[15];
    const float* dec_bih  = (const float*)d_in[16];
    const float* dec_bhh  = (const float*)d_in[17];
    const float* proj_w   = (const float*)d_in[18];
    const float* proj_b   = (const float*)d_in[19];
    const float* gate_w   = (const float*)d_in[20];
    const float* gate_b   = (const float*)d_in[21];
    float* out = (float*)d_out;

    // ---- ws layout ----
    float* x        = (float*)d_ws;
    float* pm       = x + X_SZ;
    float* g1       = pm + PM_SZ;
    float* g2       = g1 + G1_SZ;
    float* xcat_att = g2 + G2_SZ;          // zero-block start
    float* xcat_dec = xcat_att + XATT_SZ;
    float* ac       = xcat_dec + XDEC_SZ;
    float* dc       = ac + AC_SZ;
    float* aw       = dc + DC_SZ;
    float* awc      = aw + AW_SZ;
    float* tailh_f  = awc + AWC_SZ;
    float* taill_f  = tailh_f + TAILH_SZ;
    float* xdech_f  = taill_f + TAILL_SZ;
    float* xdecl_f  = xdech_f + XDH_SZ;    // zero-block end
    float* pq       = xdecl_f + XDL_SZ;
    float* energ    = pq + PQ_SZ;
    unsigned char* m1 = (unsigned char*)(energ + EN_SZ);
    unsigned char* m2 = m1 + MASK_N;
    u16* wb = (u16*)(m2 + MASK_N);
    u16* awih_h = wb;               u16* awih_l = awih_h + AWIH_N;
    u16* awhh_h = awih_l + AWIH_N;  u16* awhh_l = awhh_h + AWHH_N;
    u16* dwih_h = awhh_l + AWHH_N;  u16* dwih_l = dwih_h + DWIH_N;
    u16* dwhh_h = dwih_l + DWIH_N;  u16* dwhh_l = dwhh_h + DWHH_N;

    u16* tailh = (u16*)tailh_f;  u16* taill = (u16*)taill_f;
    u16* xdech = (u16*)xdech_f;  u16* xdecl = (u16*)xdecl_f;

    size_t need_base = (size_t)(m2 + MASK_N - (unsigned char*)d_ws);
    size_t need_full = (size_t)((unsigned char*)(dwhh_l + DWHH_N) - (unsigned char*)d_ws);
    if (ws_size < need_base) return;
    const bool use_mfma = (ws_size >= need_full);
    const int nsplit = use_mfma ? 1 : 4;

    // zero recurrent state (xcat_att .. xdecl contiguous)
    size_t state_floats = (size_t)XATT_SZ + XDEC_SZ + AC_SZ + DC_SZ + AW_SZ + AWC_SZ
                        + TAILH_SZ + TAILL_SZ + XDH_SZ + XDL_SZ;
    hipMemsetAsync(xcat_att, 0, state_floats * sizeof(float), stream);

    // one-time: dropout masks, prenet, processed memory, weight split
    mask_kernel<<<(MASK_N + 255) / 256, 256, 0, stream>>>(m1, m2);
    prenet1_kernel<<<TOUT * NB, 256, 0, stream>>>(dec_in, pw1, m1, x);
    prenet2_kernel<<<TOUT * NB, 256, 0, stream>>>(pw2, m2, x);
    pm_kernel<<<dim3(NB, TIN), 128, 0, stream>>>(memory, wm, pm);
    if (use_mfma) {
        wsplit_kernel<<<(AWIH_N + 255) / 256, 256, 0, stream>>>(att_wih, awih_h, awih_l, AWIH_N);
        wsplit_kernel<<<(AWHH_N + 255) / 256, 256, 0, stream>>>(att_whh, awhh_h, awhh_l, AWHH_N);
        wsplit_kernel<<<(DWIH_N + 255) / 256, 256, 0, stream>>>(dec_wih, dwih_h, dwih_l, DWIH_N);
        wsplit_kernel<<<(DWHH_N + 255) / 256, 256, 0, stream>>>(dec_whh, dwhh_h, dwhh_l, DWHH_N);
    }

    float* out_align = out + ALGN_OFF;

    // prologue: gemm1 for t=0
    if (use_mfma)
        mfma_pair_gemm<<<256, 256, 0, stream>>>(xdech, xdecl, dwih_h, dwih_l, dwhh_h, dwhh_l, g2,
                                                x, tailh, taill, awih_h, awih_l, awhh_h, awhh_l, g1, -1);
    else
        pair_gemm<<<512, 256, 0, stream>>>(xcat_dec, dec_wih, dec_whh, g2,
                                           x, xcat_att, att_wih, att_whh, g1, -1);

    for (int t = 0; t < TOUT; ++t) {
        pair_pw<<<128, 256, 0, stream>>>(g1, att_bih, att_bhh, ac, xcat_att, xcat_dec, wq, pq,
                                         g2, dec_bih, dec_bhh, dc, proj_w, proj_b,
                                         gate_w, gate_b, out, tailh, taill, xdech, xdecl,
                                         nsplit, t);
        energies_kernel<<<dim3(NB, 4), 256, 0, stream>>>(aw, awc, loc_conv, loc_dense, v, pq, pm, energ);
        softmax_ctx_kernel<<<NB, 256, 0, stream>>>(energ, mlen, memory, aw, awc, out_align, t,
                                                   xcat_att, xcat_dec, tailh, taill, xdech, xdecl);
        if (use_mfma)
            mfma_pair_gemm<<<256, 256, 0, stream>>>(xdech, xdecl, dwih_h, dwih_l, dwhh_h, dwhh_l, g2,
                                                    x, tailh, taill, awih_h, awih_l, awhh_h, awhh_l, g1, t);
        else
            pair_gemm<<<512, 256, 0, stream>>>(xcat_dec, dec_wih, dec_whh, g2,
                                               x, xcat_att, att_wih, att_whh, g1, t);
    }
    // epilogue: dec_pointwise+proj for t=499
    pair_pw<<<128, 256, 0, stream>>>(g1, att_bih, att_bhh, ac, xcat_att, xcat_dec, wq, pq,
                                     g2, dec_bih, dec_bhh, dc, proj_w, proj_b,
                                     gate_w, gate_b, out, tailh, taill, xdech, xdecl,
                                     nsplit, TOUT);
}

// Round 7
// 66191.821 us; speedup vs baseline: 3.7237x; 1.4314x over previous
//
#include <hip/hip_runtime.h>
#include <cstdint>
#include <cstddef>

// ---------------- constants ----------------
#define NB    64      // batch
#define TIN   512
#define TOUT  500
#define NMEL  80
#define ENC   512
#define ATTD  128
#define ARNN  1024
#define DRNN  1024
#define PREN  256
#define NFILT 32
#define KSZ   31
#define CPAD  15

#define MEL_OFF  0
#define GATE_OFF 2560000
#define ALGN_OFF 2592000

// ws float-layout sizes
#define X_SZ      8192000   // prenet output [500][64][256]
#define PM_SZ     4194304   // processed memory [64][512][128]
#define G1_SZ     1048576   // gemm1 out (fp32 path: [4][64][4096] partials; mfma: [64][4096])
#define G2_SZ     1048576
#define XATT_SZ   98304     // fp32 [64][1536] = [ctx|ah]
#define XDEC_SZ   163840    // fp32 [64][2560] = [ah|ctx|dh]
#define AC_SZ     65536
#define DC_SZ     65536
#define AW_SZ     32768
#define AWC_SZ    32768
#define TAILH_SZ  49152     // bf16 [64][1536] hi (float-slots)
#define TAILL_SZ  49152
#define XDH_SZ    81920     // bf16 [64][2560] hi
#define XDL_SZ    81920
#define PQ_SZ     8192
#define EN_SZ     32768
#define MASK_N    8208384   // 501*64*256

// packed bf16 weight u16 element counts: [256 ntile][K/32 kchunk][2 hl][512]
#define K1TOT   1792      // gemm1: att_wih(768) ++ att_whh(1024)
#define K2TOT   2560      // gemm2: dec_wih(1536) ++ dec_whh(1024)
#define NCH1    56        // K1TOT/32
#define NCH2    80        // K2TOT/32
#define PK1_N   14680064  // 4096*1792*2
#define PK2_N   20971520  // 4096*2560*2

typedef unsigned short u16;
typedef __attribute__((ext_vector_type(8))) short bf16x8;
typedef __attribute__((ext_vector_type(4))) float f32x4;

__device__ __forceinline__ float sigf(float x) { return 1.f / (1.f + expf(-x)); }
__device__ __forceinline__ uint32_t rotl32(uint32_t v, int r) { return (v << r) | (v >> (32 - r)); }

// Dekker-style split: hi = truncate-to-bf16(v), lo = rn-bf16(v - hi).
__device__ __forceinline__ void split1(float v, u16& h, u16& l) {
    uint32_t u = __float_as_uint(v);
    h = (u16)(u >> 16);
    float r = v - __uint_as_float(u & 0xFFFF0000u);
    uint32_t ru = __float_as_uint(r);
    ru += 0x7FFFu + ((ru >> 16) & 1u);
    l = (u16)(ru >> 16);
}

__device__ __forceinline__ void split8(float4 f0, float4 f1, bf16x8& h, bf16x8& l) {
    float v[8] = { f0.x, f0.y, f0.z, f0.w, f1.x, f1.y, f1.z, f1.w };
#pragma unroll
    for (int i = 0; i < 8; ++i) {
        uint32_t u = __float_as_uint(v[i]);
        h[i] = (short)(u >> 16);
        float r = v[i] - __uint_as_float(u & 0xFFFF0000u);
        uint32_t ru = __float_as_uint(r);
        ru += 0x7FFFu + ((ru >> 16) & 1u);
        l[i] = (short)(ru >> 16);
    }
}

#define MFMA16(a, b, c) __builtin_amdgcn_mfma_f32_16x16x32_bf16(a, b, c, 0, 0, 0)

// JAX threefry2x32
__device__ void tf_block(uint32_t k1, uint32_t k2, uint32_t& x0, uint32_t& x1) {
    uint32_t ks0 = k1, ks1 = k2, ks2 = k1 ^ k2 ^ 0x1BD11BDAu;
    x0 += ks0; x1 += ks1;
#define TFR(r) { x0 += x1; x1 = rotl32(x1, r); x1 ^= x0; }
    TFR(13) TFR(15) TFR(26) TFR(6)   x0 += ks1; x1 += ks2 + 1u;
    TFR(17) TFR(29) TFR(16) TFR(24)  x0 += ks2; x1 += ks0 + 2u;
    TFR(13) TFR(15) TFR(26) TFR(6)   x0 += ks0; x1 += ks1 + 3u;
    TFR(17) TFR(29) TFR(16) TFR(24)  x0 += ks1; x1 += ks2 + 4u;
    TFR(13) TFR(15) TFR(26) TFR(6)   x0 += ks2; x1 += ks0 + 5u;
#undef TFR
}

__global__ __launch_bounds__(256) void mask_kernel(unsigned char* m1, unsigned char* m2) {
    int i = blockIdx.x * 256 + threadIdx.x;
    if (i >= MASK_N) return;
    uint32_t a0 = 0u, a1 = 0u; tf_block(0u, 42u, a0, a1);
    uint32_t b0 = 0u, b1 = 1u; tf_block(0u, 42u, b0, b1);
    uint32_t x0, x1;
    x0 = 0u; x1 = (uint32_t)i; tf_block(a0, a1, x0, x1);
    m1[i] = ((x0 ^ x1) >> 31) == 0u;
    x0 = 0u; x1 = (uint32_t)i; tf_block(b0, b1, x0, x1);
    m2[i] = ((x0 ^ x1) >> 31) == 0u;
}

__global__ __launch_bounds__(256) void prenet1_kernel(
    const float* __restrict__ dec_in, const float* __restrict__ w1,
    const unsigned char* __restrict__ m1, float* __restrict__ x)
{
    int r = blockIdx.x;
    int t = r >> 6, b = r & 63;
    int tid = threadIdx.x;
    __shared__ float ds[NMEL];
    if (tid < NMEL) ds[tid] = (t == 0) ? 0.f : dec_in[(size_t)b * 40000 + tid * 500 + (t - 1)];
    __syncthreads();
    float acc = 0.f;
    const float* w = w1 + tid * NMEL;
#pragma unroll
    for (int k = 0; k < NMEL; ++k) acc += ds[k] * w[k];
    acc = fmaxf(acc, 0.f);
    int flat = r * 256 + tid;
    x[flat] = m1[flat] ? acc * 2.f : 0.f;
}

__global__ __launch_bounds__(256) void prenet2_kernel(
    const float* __restrict__ w2, const unsigned char* __restrict__ m2, float* x)
{
    int r = blockIdx.x;
    int tid = threadIdx.x;
    __shared__ float xs[PREN];
    xs[tid] = x[r * 256 + tid];
    __syncthreads();
    float acc = 0.f;
    const float* w = w2 + tid * PREN;
#pragma unroll 8
    for (int k = 0; k < PREN; ++k) acc += xs[k] * w[k];
    acc = fmaxf(acc, 0.f);
    int flat = r * 256 + tid;
    x[flat] = m2[flat] ? acc * 2.f : 0.f;
}

__global__ __launch_bounds__(128) void pm_kernel(
    const float* __restrict__ memory, const float* __restrict__ wm, float* __restrict__ pm)
{
    int b = blockIdx.x, t = blockIdx.y;
    int tid = threadIdx.x;
    __shared__ float ms[ENC];
    for (int i = tid; i < ENC; i += 128) ms[i] = memory[(size_t)b * (TIN * ENC) + (size_t)t * ENC + i];
    __syncthreads();
    float acc = 0.f;
    const float* w = wm + tid * ENC;
#pragma unroll 8
    for (int k = 0; k < ENC; ++k) acc += ms[k] * w[k];
    pm[(size_t)b * (TIN * ATTD) + t * ATTD + tid] = acc;
}

// one-time weight split+pack: virtual W = [4096][K1+K2] = concat(w1, w2) row-wise,
// packed so one wave's 16x32 fragment (hi then lo) is two contiguous 1KB lines:
// dst[((tile*(K/32)+kc)*2 + hl)*512 + lane*8 + elem], lane=(n&15)+((k&31)>>3)*16
__global__ __launch_bounds__(256) void wpack_kernel(
    const float* __restrict__ w1, int K1, const float* __restrict__ w2, int K2,
    u16* __restrict__ dst)
{
    const int K = K1 + K2;
    int idx = blockIdx.x * 256 + threadIdx.x;
    if (idx >= 4096 * K) return;
    int n = idx / K, k = idx % K;
    float v = (k < K1) ? w1[n * K1 + k] : w2[n * K2 + (k - K1)];
    u16 h, l;
    split1(v, h, l);
    int tile = n >> 4, kc = k >> 5;
    int lane = (n & 15) + (((k & 31) >> 3) << 4);
    size_t off = ((size_t)(tile * (K >> 5) + kc) * 2) * 512 + lane * 8 + (k & 7);
    dst[off] = h;
    dst[off + 512] = l;
}

// ---------------- fp32 fallback K-split GEMM (proven round-5 body) ----------------
struct SmemGemm { float Xs[32][68]; float Ws[32][68]; };

__device__ void gemm_phase(
    const float* __restrict__ X1, int ldx1, int kx1,
    const float* __restrict__ X2, int ldx2,
    const float* __restrict__ W1, int ldw1, int kw1,
    const float* __restrict__ W2, int ldw2,
    float* __restrict__ outp, int Kq, int blk, SmemGemm& s)
{
    const int tid = threadIdx.x;
    const int n0 = (blk & 63) * 64;
    const int ks = blk >> 6;
    const int kbeg = ks * Kq;
    const int tn = tid & 15, tm = tid >> 4;
    float acc[4][4];
#pragma unroll
    for (int i = 0; i < 4; ++i)
#pragma unroll
        for (int j = 0; j < 4; ++j) acc[i][j] = 0.f;

#pragma unroll 1
    for (int k0 = kbeg; k0 < kbeg + Kq; k0 += 32) {
#pragma unroll
        for (int i = 0; i < 8; ++i) {
            int flat = i * 256 + tid;
            int m = flat >> 5, c = flat & 31;
            int k = k0 + c;
            s.Xs[c][m] = (k < kx1) ? X1[m * ldx1 + k] : X2[m * ldx2 + (k - kx1)];
        }
#pragma unroll
        for (int i = 0; i < 8; ++i) {
            int flat = i * 256 + tid;
            int r = flat >> 5, c = flat & 31;
            int k = k0 + c;
            int n = n0 + r;
            s.Ws[c][r] = (k < kw1) ? W1[n * ldw1 + k] : W2[n * ldw2 + (k - kw1)];
        }
        __syncthreads();
#pragma unroll
        for (int kk = 0; kk < 32; ++kk) {
            float4 xv = *(const float4*)&s.Xs[kk][tm * 4];
            float4 wv = *(const float4*)&s.Ws[kk][tn * 4];
            float xr[4] = { xv.x, xv.y, xv.z, xv.w };
            float wr[4] = { wv.x, wv.y, wv.z, wv.w };
#pragma unroll
            for (int i = 0; i < 4; ++i)
#pragma unroll
                for (int j = 0; j < 4; ++j) acc[i][j] += xr[i] * wr[j];
        }
        __syncthreads();
    }
    float* o = outp + (size_t)ks * 64 * 4096;
#pragma unroll
    for (int i = 0; i < 4; ++i)
#pragma unroll
        for (int j = 0; j < 4; ++j)
            o[(tm * 4 + i) * 4096 + (n0 + tn * 4 + j)] = acc[i][j];
}

__global__ __launch_bounds__(256, 2) void pair_gemm(
    const float* __restrict__ xcat_dec,
    const float* __restrict__ dec_wih, const float* __restrict__ dec_whh,
    float* __restrict__ g2,
    const float* __restrict__ x, const float* __restrict__ xcat_att,
    const float* __restrict__ att_wih, const float* __restrict__ att_whh,
    float* __restrict__ g1, int t)
{
    __shared__ __align__(16) SmemGemm sm;
    const int blk = blockIdx.x;
    if (blk < 256) {
        if (t < 0) return;
        gemm_phase(xcat_dec, 2560, 2560, xcat_dec, 2560,
                   dec_wih, 1536, 1536, dec_whh, 1024, g2, 640, blk, sm);
    } else {
        const int tn = t + 1;
        if (tn >= TOUT) return;
        gemm_phase(x + (size_t)tn * (NB * PREN), PREN, PREN, xcat_att, 1536,
                   att_wih, 768, 768, att_whh, 1024, g1, 448, blk - 256, sm);
    }
}

// ---------------- MFMA pair gemm with packed-coalesced B ----------------
// blk 0-127: gemm2(t); blk 128-255: gemm1(t+1). 4 waves/block; wave owns m-rows 16w..16w+15;
// block covers 32 n (2 tiles). Per k0: B fragments are contiguous 1KB lines (lane*8 u16).
__global__ __launch_bounds__(256) void mfma_pair_gemm(
    const u16* __restrict__ xdech, const u16* __restrict__ xdecl,
    const u16* __restrict__ pk2, float* __restrict__ g2,
    const float* __restrict__ x,
    const u16* __restrict__ tailh, const u16* __restrict__ taill,
    const u16* __restrict__ pk1, float* __restrict__ g1, int t)
{
    const int blk = blockIdx.x;
    const int tid = threadIdx.x;
    const int wave = tid >> 6, lane = tid & 63;
    const int lr = lane & 15, kg = lane >> 4;
    const int mrow = wave * 16 + lr;
    f32x4 acc0 = {0.f, 0.f, 0.f, 0.f}, acc1 = {0.f, 0.f, 0.f, 0.f};

    if (blk < 128) {
        if (t < 0) return;
        const u16* Ah = xdech + mrow * 2560;
        const u16* Al = xdecl + mrow * 2560;
        const u16* bp = pk2 + ((size_t)(2 * blk) * NCH2) * 1024 + lane * 8;
#pragma unroll 2
        for (int k0 = 0; k0 < K2TOT; k0 += 32) {
            const int k = k0 + kg * 8;
            bf16x8 ah = *(const bf16x8*)(Ah + k);
            bf16x8 al = *(const bf16x8*)(Al + k);
            const u16* c0 = bp + (size_t)(k0 >> 5) * 1024;
            bf16x8 b0h = *(const bf16x8*)c0;
            bf16x8 b0l = *(const bf16x8*)(c0 + 512);
            bf16x8 b1h = *(const bf16x8*)(c0 + (size_t)NCH2 * 1024);
            bf16x8 b1l = *(const bf16x8*)(c0 + (size_t)NCH2 * 1024 + 512);
            acc0 = MFMA16(ah, b0h, acc0); acc0 = MFMA16(ah, b0l, acc0); acc0 = MFMA16(al, b0h, acc0);
            acc1 = MFMA16(ah, b1h, acc1); acc1 = MFMA16(ah, b1l, acc1); acc1 = MFMA16(al, b1h, acc1);
        }
        const int n0 = blk * 32;
        const int mbase = wave * 16 + kg * 4;
#pragma unroll
        for (int r = 0; r < 4; ++r) {
            g2[(mbase + r) * 4096 + n0 + lr]      = acc0[r];
            g2[(mbase + r) * 4096 + n0 + 16 + lr] = acc1[r];
        }
    } else {
        const int tn = t + 1;
        if (tn >= TOUT) return;
        const int bb = blk - 128;
        const u16* Ah = tailh + mrow * 1536;
        const u16* Al = taill + mrow * 1536;
        const float* xr = x + ((size_t)tn * 64 + mrow) * 256;
        const u16* bp = pk1 + ((size_t)(2 * bb) * NCH1) * 1024 + lane * 8;
#pragma unroll 1
        for (int k0 = 0; k0 < K1TOT; k0 += 32) {
            const int k = k0 + kg * 8;
            bf16x8 ah, al;
            if (k < 256) {
                float4 f0 = *(const float4*)(xr + k);
                float4 f1 = *(const float4*)(xr + k + 4);
                split8(f0, f1, ah, al);
            } else {
                ah = *(const bf16x8*)(Ah + (k - 256));
                al = *(const bf16x8*)(Al + (k - 256));
            }
            const u16* c0 = bp + (size_t)(k0 >> 5) * 1024;
            bf16x8 b0h = *(const bf16x8*)c0;
            bf16x8 b0l = *(const bf16x8*)(c0 + 512);
            bf16x8 b1h = *(const bf16x8*)(c0 + (size_t)NCH1 * 1024);
            bf16x8 b1l = *(const bf16x8*)(c0 + (size_t)NCH1 * 1024 + 512);
            acc0 = MFMA16(ah, b0h, acc0); acc0 = MFMA16(ah, b0l, acc0); acc0 = MFMA16(al, b0h, acc0);
            acc1 = MFMA16(ah, b1h, acc1); acc1 = MFMA16(ah, b1l, acc1); acc1 = MFMA16(al, b1h, acc1);
        }
        const int n0 = bb * 32;
        const int mbase = wave * 16 + kg * 4;
#pragma unroll
        for (int r = 0; r < 4; ++r) {
            g1[(mbase + r) * 4096 + n0 + lr]      = acc0[r];
            g1[(mbase + r) * 4096 + n0 + 16 + lr] = acc1[r];
        }
    }
}

// ---------------- L1: att_pointwise(t) || dec_pointwise+proj(t-1) ----------------
__global__ __launch_bounds__(256) void pair_pw(
    const float* __restrict__ g1, const float* __restrict__ att_bih, const float* __restrict__ att_bhh,
    float* __restrict__ ac, float* __restrict__ xcat_att, float* __restrict__ xcat_dec,
    const float* __restrict__ wq, float* __restrict__ pq,
    const float* __restrict__ g2, const float* __restrict__ dec_bih, const float* __restrict__ dec_bhh,
    float* __restrict__ dc, const float* __restrict__ proj_w, const float* __restrict__ proj_b,
    const float* __restrict__ gate_w, const float* __restrict__ gate_b,
    float* __restrict__ out,
    u16* __restrict__ tailh, u16* __restrict__ taill,
    u16* __restrict__ xdech, u16* __restrict__ xdecl,
    int nsplit, int t)
{
    const int tid = threadIdx.x;
    __shared__ float sbuf[1536];
    __shared__ float red[256];

    if (blockIdx.x < 64) {
        if (t >= TOUT) return;
        const int b = blockIdx.x;
#pragma unroll
        for (int q = 0; q < 4; ++q) {
            int j = q * 256 + tid;
            float gi = att_bih[j] + att_bhh[j];
            float gf = att_bih[1024 + j] + att_bhh[1024 + j];
            float gg = att_bih[2048 + j] + att_bhh[2048 + j];
            float go = att_bih[3072 + j] + att_bhh[3072 + j];
            for (int s = 0; s < nsplit; ++s) {
                const float* g = g1 + (size_t)s * 262144 + b * 4096;
                gi += g[j]; gf += g[1024 + j]; gg += g[2048 + j]; go += g[3072 + j];
            }
            float c = sigf(gf) * ac[b * 1024 + j] + sigf(gi) * tanhf(gg);
            float h = sigf(go) * tanhf(c);
            ac[b * 1024 + j] = c;
            xcat_att[b * 1536 + 512 + j] = h;
            xcat_dec[b * 2560 + j] = h;
            u16 hh, hl; split1(h, hh, hl);
            tailh[b * 1536 + 512 + j] = hh;  taill[b * 1536 + 512 + j] = hl;
            xdech[b * 2560 + j] = hh;        xdecl[b * 2560 + j] = hl;
            sbuf[j] = h;
        }
        __syncthreads();
        const int a = tid & 127, half = tid >> 7;
        float s = 0.f;
        const float* wr = wq + a * 1024 + half * 512;
        const float* hh = sbuf + half * 512;
#pragma unroll 4
        for (int k = 0; k < 512; k += 4) {
            float4 wv = *(const float4*)&wr[k];
            float4 hv = *(const float4*)&hh[k];
            s += hv.x * wv.x + hv.y * wv.y + hv.z * wv.z + hv.w * wv.w;
        }
        red[tid] = s;
        __syncthreads();
        if (half == 0) pq[b * 128 + a] = red[a] + red[a + 128];
    } else {
        if (t < 1) return;
        const int b = blockIdx.x - 64;
        const int ts = t - 1;
#pragma unroll
        for (int q = 0; q < 4; ++q) {
            int j = q * 256 + tid;
            float gi = dec_bih[j] + dec_bhh[j];
            float gf = dec_bih[1024 + j] + dec_bhh[1024 + j];
            float gg = dec_bih[2048 + j] + dec_bhh[2048 + j];
            float go = dec_bih[3072 + j] + dec_bhh[3072 + j];
            for (int s = 0; s < nsplit; ++s) {
                const float* g = g2 + (size_t)s * 262144 + b * 4096;
                gi += g[j]; gf += g[1024 + j]; gg += g[2048 + j]; go += g[3072 + j];
            }
            float c = sigf(gf) * dc[b * 1024 + j] + sigf(gi) * tanhf(gg);
            float h = sigf(go) * tanhf(c);
            dc[b * 1024 + j] = c;
            xcat_dec[b * 2560 + 1536 + j] = h;
            u16 hh, hl; split1(h, hh, hl);
            xdech[b * 2560 + 1536 + j] = hh;  xdecl[b * 2560 + 1536 + j] = hl;
            sbuf[j] = h;
        }
        for (int i = tid; i < 512; i += 256) sbuf[1024 + i] = xcat_dec[b * 2560 + 1024 + i];
        __syncthreads();
        const int o = tid >> 1, half = tid & 1;
        float accv = 0.f;
        if (o <= 80) {
            const float* w = (o < 80) ? (proj_w + o * 1536) : gate_w;
            const float* sv = sbuf + half * 768;
            const float* wv = w + half * 768;
#pragma unroll 4
            for (int k = 0; k < 768; k += 4) {
                float4 a4 = *(const float4*)&sv[k];
                float4 b4 = *(const float4*)&wv[k];
                accv += a4.x * b4.x + a4.y * b4.y + a4.z * b4.z + a4.w * b4.w;
            }
        }
        red[tid] = accv;
        __syncthreads();
        if (half == 0 && o <= 80) {
            float r = red[tid] + red[tid + 1];
            if (o < 80)
                out[MEL_OFF + (size_t)b * (TOUT * NMEL) + (size_t)ts * NMEL + o] = r + proj_b[o];
            else
                out[GATE_OFF + (size_t)b * TOUT + ts] = r + gate_b[0];
        }
    }
}

// ---------------- L2: conv + loc_dense + energies ----------------
__global__ __launch_bounds__(256) void energies_kernel(
    const float* __restrict__ aw, const float* __restrict__ awc,
    const float* __restrict__ lc, const float* __restrict__ ld,
    const float* __restrict__ vvec, const float* __restrict__ pq,
    const float* __restrict__ pm, float* __restrict__ energ)
{
    const int b = blockIdx.x, tc = blockIdx.y;
    const int t0 = tc * 128;
    const int tid = threadIdx.x;
    __shared__ float awin[160], awcin[160];
    __shared__ float lcs[NFILT * 62];
    __shared__ float locs[128 * 33];
    __shared__ float pqs[ATTD], vs[ATTD];
    __shared__ float ldm[ATTD * NFILT];
    __shared__ float ered[256];

    for (int i = tid; i < 158; i += 256) {
        int t = t0 + i - CPAD;
        bool ok = (t >= 0 && t < TIN);
        awin[i]  = ok ? aw[b * TIN + t]  : 0.f;
        awcin[i] = ok ? awc[b * TIN + t] : 0.f;
    }
    for (int i = tid; i < NFILT * 62; i += 256) lcs[i] = lc[i];
    for (int i = tid; i < ATTD * NFILT; i += 256) ldm[i] = ld[i];
    if (tid < ATTD) { pqs[tid] = pq[b * ATTD + tid]; vs[tid] = vvec[tid]; }
    __syncthreads();

    for (int idx = tid; idx < 128 * 32; idx += 256) {
        int tl = idx >> 5, f = idx & 31;
        const float* w0 = lcs + f * 62;
        float s = 0.f;
#pragma unroll
        for (int k = 0; k < KSZ; ++k)
            s += awin[tl + k] * w0[k] + awcin[tl + k] * w0[31 + k];
        locs[tl * 33 + f] = s;
    }
    __syncthreads();

    const int tl = tid >> 1, half = tid & 1;
    float e = 0.f;
    const float* pmrow = pm + (size_t)b * (TIN * ATTD) + (size_t)(t0 + tl) * ATTD + half * 64;
    const float* lt = locs + tl * 33;
    for (int a = 0; a < 64; ++a) {
        const float* lrow = ldm + (half * 64 + a) * 32;
        float s = pqs[half * 64 + a] + pmrow[a];
#pragma unroll
        for (int f = 0; f < NFILT; ++f) s += lt[f] * lrow[f];
        e += vs[half * 64 + a] * tanhf(s);
    }
    ered[tid] = e;
    __syncthreads();
    if (half == 0) energ[b * TIN + t0 + tl] = ered[tid] + ered[tid + 1];
}

// ---------------- L3: distributed softmax + aw/awc + align + ctx (256 blocks = 64b x 4dq) ----------------
__global__ __launch_bounds__(256) void softmax_ctx_kernel(
    const float* __restrict__ energ, const int* __restrict__ mlen,
    const float* __restrict__ memory,
    float* __restrict__ aw, float* __restrict__ awc,
    float* __restrict__ out_align, int t_step,
    float* __restrict__ xcat_att, float* __restrict__ xcat_dec,
    u16* __restrict__ tailh, u16* __restrict__ taill,
    u16* __restrict__ xdech, u16* __restrict__ xdecl)
{
    const int b = blockIdx.x >> 2, dq = blockIdx.x & 3;
    const int tid = threadIdx.x;
    const int len = mlen[b];
    __shared__ float es[TIN];
    __shared__ float red[256];

    // redundant 512-wide softmax (cheap; avoids cross-block dependency)
    float e1 = (tid < len) ? energ[b * TIN + tid] : -INFINITY;
    float e2 = (tid + 256 < len) ? energ[b * TIN + tid + 256] : -INFINITY;
    red[tid] = fmaxf(e1, e2);
    __syncthreads();
    for (int s = 128; s > 0; s >>= 1) {
        if (tid < s) red[tid] = fmaxf(red[tid], red[tid + s]);
        __syncthreads();
    }
    const float mx = red[0];
    __syncthreads();
    float p1 = expf(e1 - mx);
    float p2 = expf(e2 - mx);
    red[tid] = p1 + p2;
    __syncthreads();
    for (int s = 128; s > 0; s >>= 1) {
        if (tid < s) red[tid] += red[tid + s];
        __syncthreads();
    }
    const float inv = 1.f / red[0];
    p1 *= inv; p2 *= inv;
    es[tid] = p1; es[tid + 256] = p2;
    __syncthreads();

    // disjoint 128-slice of aw/awc/alignments
    if (tid < 128) {
        int tt = dq * 128 + tid;
        float p = es[tt];
        aw[b * TIN + tt] = p;
        awc[b * TIN + tt] += p;
        out_align[(size_t)b * (TOUT * TIN) + (size_t)t_step * TIN + tt] = p;
    }

    // ctx 128-d slice: 2 threads per d, 256 t each
    const int d = dq * 128 + (tid & 127), th = tid >> 7;
    const float* mb = memory + (size_t)b * (TIN * ENC);
    float accv = 0.f;
#pragma unroll 4
    for (int tt = th * 256; tt < th * 256 + 256; ++tt)
        accv += es[tt] * mb[(size_t)tt * ENC + d];
    __syncthreads();
    red[tid] = accv;
    __syncthreads();
    if (tid < 128) {
        float cv = red[tid] + red[tid + 128];
        int dd = dq * 128 + tid;
        xcat_att[b * 1536 + dd] = cv;
        xcat_dec[b * 2560 + 1024 + dd] = cv;
        u16 h, l; split1(cv, h, l);
        tailh[b * 1536 + dd] = h;        taill[b * 1536 + dd] = l;
        xdech[b * 2560 + 1024 + dd] = h; xdecl[b * 2560 + 1024 + dd] = l;
    }
}

extern "C" void kernel_launch(void* const* d_in, const int* in_sizes, int n_in,
                              void* d_out, int out_size, void* d_ws, size_t ws_size,
                              hipStream_t stream) {
    const float* memory   = (const float*)d_in[0];
    const float* dec_in   = (const float*)d_in[1];
    const int*   mlen     = (const int*)d_in[2];
    const float* pw1      = (const float*)d_in[3];
    const float* pw2      = (const float*)d_in[4];
    const float* att_wih  = (const float*)d_in[5];
    const float* att_whh  = (const float*)d_in[6];
    const float* att_bih  = (const float*)d_in[7];
    const float* att_bhh  = (const float*)d_in[8];
    const float* wq       = (const float*)d_in[9];
    const float* wm       = (const float*)d_in[10];
    const float* v        = (const float*)d_in[11];
    const float* loc_conv = (const float*)d_in[12];
    const float* loc_dense= (const float*)d_in[13];
    const float* dec_wih  = (const float*)d_in[14];
    const float* dec_whh  = (const float*)d_in[15];
    const float* dec_bih  = (const float*)d_in[16];
    const float* dec_bhh  = (const float*)d_in[17];
    const float* proj_w   = (const float*)d_in[18];
    const float* proj_b   = (const float*)d_in[19];
    const float* gate_w   = (const float*)d_in[20];
    const float* gate_b   = (const float*)d_in[21];
    float* out = (float*)d_out;

    // ---- ws layout ----
    float* x        = (float*)d_ws;
    float* pm       = x + X_SZ;
    float* g1       = pm + PM_SZ;
    float* g2       = g1 + G1_SZ;
    float* xcat_att = g2 + G2_SZ;          // zero-block start
    float* xcat_dec = xcat_att + XATT_SZ;
    float* ac       = xcat_dec + XDEC_SZ;
    float* dc       = ac + AC_SZ;
    float* aw       = dc + DC_SZ;
    float* awc      = aw + AW_SZ;
    float* tailh_f  = awc + AWC_SZ;
    float* taill_f  = tailh_f + TAILH_SZ;
    float* xdech_f  = taill_f + TAILL_SZ;
    float* xdecl_f  = xdech_f + XDH_SZ;    // zero-block end
    float* pq       = xdecl_f + XDL_SZ;
    float* energ    = pq + PQ_SZ;
    unsigned char* m1 = (unsigned char*)(energ + EN_SZ);
    unsigned char* m2 = m1 + MASK_N;
    u16* pk1 = (u16*)(m2 + MASK_N);
    u16* pk2 = pk1 + PK1_N;

    u16* tailh = (u16*)tailh_f;  u16* taill = (u16*)taill_f;
    u16* xdech = (u16*)xdech_f;  u16* xdecl = (u16*)xdecl_f;

    size_t need_base = (size_t)(m2 + MASK_N - (unsigned char*)d_ws);
    size_t need_full = (size_t)((unsigned char*)(pk2 + PK2_N) - (unsigned char*)d_ws);
    if (ws_size < need_base) return;
    const bool use_mfma = (ws_size >= need_full);
    const int nsplit = use_mfma ? 1 : 4;

    // zero recurrent state (xcat_att .. xdecl contiguous)
    size_t state_floats = (size_t)XATT_SZ + XDEC_SZ + AC_SZ + DC_SZ + AW_SZ + AWC_SZ
                        + TAILH_SZ + TAILL_SZ + XDH_SZ + XDL_SZ;
    hipMemsetAsync(xcat_att, 0, state_floats * sizeof(float), stream);

    // one-time: dropout masks, prenet, processed memory, weight pack
    mask_kernel<<<(MASK_N + 255) / 256, 256, 0, stream>>>(m1, m2);
    prenet1_kernel<<<TOUT * NB, 256, 0, stream>>>(dec_in, pw1, m1, x);
    prenet2_kernel<<<TOUT * NB, 256, 0, stream>>>(pw2, m2, x);
    pm_kernel<<<dim3(NB, TIN), 128, 0, stream>>>(memory, wm, pm);
    if (use_mfma) {
        wpack_kernel<<<(4096 * K1TOT + 255) / 256, 256, 0, stream>>>(att_wih, 768, att_whh, 1024, pk1);
        wpack_kernel<<<(4096 * K2TOT + 255) / 256, 256, 0, stream>>>(dec_wih, 1536, dec_whh, 1024, pk2);
    }

    float* out_align = out + ALGN_OFF;

    // prologue: gemm1 for t=0
    if (use_mfma)
        mfma_pair_gemm<<<256, 256, 0, stream>>>(xdech, xdecl, pk2, g2, x, tailh, taill, pk1, g1, -1);
    else
        pair_gemm<<<512, 256, 0, stream>>>(xcat_dec, dec_wih, dec_whh, g2,
                                           x, xcat_att, att_wih, att_whh, g1, -1);

    for (int t = 0; t < TOUT; ++t) {
        pair_pw<<<128, 256, 0, stream>>>(g1, att_bih, att_bhh, ac, xcat_att, xcat_dec, wq, pq,
                                         g2, dec_bih, dec_bhh, dc, proj_w, proj_b,
                                         gate_w, gate_b, out, tailh, taill, xdech, xdecl,
                                         nsplit, t);
        energies_kernel<<<dim3(NB, 4), 256, 0, stream>>>(aw, awc, loc_conv, loc_dense, v, pq, pm, energ);
        softmax_ctx_kernel<<<256, 256, 0, stream>>>(energ, mlen, memory, aw, awc, out_align, t,
                                                    xcat_att, xcat_dec, tailh, taill, xdech, xdecl);
        if (use_mfma)
            mfma_pair_gemm<<<256, 256, 0, stream>>>(xdech, xdecl, pk2, g2, x, tailh, taill, pk1, g1, t);
        else
            pair_gemm<<<512, 256, 0, stream>>>(xcat_dec, dec_wih, dec_whh, g2,
                                               x, xcat_att, att_wih, att_whh, g1, t);
    }
    // epilogue: dec_pointwise+proj for t=499
    pair_pw<<<128, 256, 0, stream>>>(g1, att_bih, att_bhh, ac, xcat_att, xcat_dec, wq, pq,
                                     g2, dec_bih, dec_bhh, dc, proj_w, proj_b,
                                     gate_w, gate_b, out, tailh, taill, xdech, xdecl,
                                     nsplit, TOUT);
}

// Round 8
// 65260.138 us; speedup vs baseline: 3.7768x; 1.0143x over previous
//
#include <hip/hip_runtime.h>
#include <cstdint>
#include <cstddef>

// ---------------- constants ----------------
#define NB    64      // batch
#define TIN   512
#define TOUT  500
#define NMEL  80
#define ENC   512
#define ATTD  128
#define ARNN  1024
#define DRNN  1024
#define PREN  256
#define NFILT 32
#define KSZ   31
#define CPAD  15

#define MEL_OFF  0
#define GATE_OFF 2560000
#define ALGN_OFF 2592000

// ws float-layout sizes
#define X_SZ      8192000   // prenet output [500][64][256]
#define PM_SZ     4194304   // processed memory [64][512][128]
#define G1_SZ     1048576   // gate partials (fp32 path: 4; mfma path: 2 of [64][4096])
#define G2_SZ     1048576
#define XATT_SZ   98304     // fp32 [64][1536] = [ctx|ah]
#define XDEC_SZ   163840    // fp32 [64][2560] = [ah|ctx|dh]
#define AC_SZ     65536
#define DC_SZ     65536
#define AW_SZ     32768
#define AWC_SZ    32768
#define TAILH_SZ  49152     // bf16 [64][1536] hi (float-slots)
#define TAILL_SZ  49152
#define XDH_SZ    81920     // bf16 [64][2560] hi
#define XDL_SZ    81920
#define PQ_SZ     8192
#define EN_SZ     32768
#define MASK_N    8208384   // 501*64*256

// packed bf16 weight u16 element counts: [256 ntile][K/32 kchunk][2 hl][512]
#define K1TOT   1792      // gemm1: att_wih(768) ++ att_whh(1024)
#define K2TOT   2560      // gemm2: dec_wih(1536) ++ dec_whh(1024)
#define NCH1    56        // K1TOT/32
#define NCH2    80        // K2TOT/32
#define PK1_N   14680064  // 4096*1792*2
#define PK2_N   20971520  // 4096*2560*2

typedef unsigned short u16;
typedef __attribute__((ext_vector_type(8))) short bf16x8;
typedef __attribute__((ext_vector_type(4))) float f32x4;

__device__ __forceinline__ float sigf(float x) { return 1.f / (1.f + expf(-x)); }
__device__ __forceinline__ uint32_t rotl32(uint32_t v, int r) { return (v << r) | (v >> (32 - r)); }

// Dekker-style split: hi = truncate-to-bf16(v), lo = rn-bf16(v - hi).
__device__ __forceinline__ void split1(float v, u16& h, u16& l) {
    uint32_t u = __float_as_uint(v);
    h = (u16)(u >> 16);
    float r = v - __uint_as_float(u & 0xFFFF0000u);
    uint32_t ru = __float_as_uint(r);
    ru += 0x7FFFu + ((ru >> 16) & 1u);
    l = (u16)(ru >> 16);
}

__device__ __forceinline__ void split8(float4 f0, float4 f1, bf16x8& h, bf16x8& l) {
    float v[8] = { f0.x, f0.y, f0.z, f0.w, f1.x, f1.y, f1.z, f1.w };
#pragma unroll
    for (int i = 0; i < 8; ++i) {
        uint32_t u = __float_as_uint(v[i]);
        h[i] = (short)(u >> 16);
        float r = v[i] - __uint_as_float(u & 0xFFFF0000u);
        uint32_t ru = __float_as_uint(r);
        ru += 0x7FFFu + ((ru >> 16) & 1u);
        l[i] = (short)(ru >> 16);
    }
}

#define MFMA16(a, b, c) __builtin_amdgcn_mfma_f32_16x16x32_bf16(a, b, c, 0, 0, 0)

// JAX threefry2x32
__device__ void tf_block(uint32_t k1, uint32_t k2, uint32_t& x0, uint32_t& x1) {
    uint32_t ks0 = k1, ks1 = k2, ks2 = k1 ^ k2 ^ 0x1BD11BDAu;
    x0 += ks0; x1 += ks1;
#define TFR(r) { x0 += x1; x1 = rotl32(x1, r); x1 ^= x0; }
    TFR(13) TFR(15) TFR(26) TFR(6)   x0 += ks1; x1 += ks2 + 1u;
    TFR(17) TFR(29) TFR(16) TFR(24)  x0 += ks2; x1 += ks0 + 2u;
    TFR(13) TFR(15) TFR(26) TFR(6)   x0 += ks0; x1 += ks1 + 3u;
    TFR(17) TFR(29) TFR(16) TFR(24)  x0 += ks1; x1 += ks2 + 4u;
    TFR(13) TFR(15) TFR(26) TFR(6)   x0 += ks2; x1 += ks0 + 5u;
#undef TFR
}

__global__ __launch_bounds__(256) void mask_kernel(unsigned char* m1, unsigned char* m2) {
    int i = blockIdx.x * 256 + threadIdx.x;
    if (i >= MASK_N) return;
    uint32_t a0 = 0u, a1 = 0u; tf_block(0u, 42u, a0, a1);
    uint32_t b0 = 0u, b1 = 1u; tf_block(0u, 42u, b0, b1);
    uint32_t x0, x1;
    x0 = 0u; x1 = (uint32_t)i; tf_block(a0, a1, x0, x1);
    m1[i] = ((x0 ^ x1) >> 31) == 0u;
    x0 = 0u; x1 = (uint32_t)i; tf_block(b0, b1, x0, x1);
    m2[i] = ((x0 ^ x1) >> 31) == 0u;
}

__global__ __launch_bounds__(256) void prenet1_kernel(
    const float* __restrict__ dec_in, const float* __restrict__ w1,
    const unsigned char* __restrict__ m1, float* __restrict__ x)
{
    int r = blockIdx.x;
    int t = r >> 6, b = r & 63;
    int tid = threadIdx.x;
    __shared__ float ds[NMEL];
    if (tid < NMEL) ds[tid] = (t == 0) ? 0.f : dec_in[(size_t)b * 40000 + tid * 500 + (t - 1)];
    __syncthreads();
    float acc = 0.f;
    const float* w = w1 + tid * NMEL;
#pragma unroll
    for (int k = 0; k < NMEL; ++k) acc += ds[k] * w[k];
    acc = fmaxf(acc, 0.f);
    int flat = r * 256 + tid;
    x[flat] = m1[flat] ? acc * 2.f : 0.f;
}

__global__ __launch_bounds__(256) void prenet2_kernel(
    const float* __restrict__ w2, const unsigned char* __restrict__ m2, float* x)
{
    int r = blockIdx.x;
    int tid = threadIdx.x;
    __shared__ float xs[PREN];
    xs[tid] = x[r * 256 + tid];
    __syncthreads();
    float acc = 0.f;
    const float* w = w2 + tid * PREN;
#pragma unroll 8
    for (int k = 0; k < PREN; ++k) acc += xs[k] * w[k];
    acc = fmaxf(acc, 0.f);
    int flat = r * 256 + tid;
    x[flat] = m2[flat] ? acc * 2.f : 0.f;
}

__global__ __launch_bounds__(128) void pm_kernel(
    const float* __restrict__ memory, const float* __restrict__ wm, float* __restrict__ pm)
{
    int b = blockIdx.x, t = blockIdx.y;
    int tid = threadIdx.x;
    __shared__ float ms[ENC];
    for (int i = tid; i < ENC; i += 128) ms[i] = memory[(size_t)b * (TIN * ENC) + (size_t)t * ENC + i];
    __syncthreads();
    float acc = 0.f;
    const float* w = wm + tid * ENC;
#pragma unroll 8
    for (int k = 0; k < ENC; ++k) acc += ms[k] * w[k];
    pm[(size_t)b * (TIN * ATTD) + t * ATTD + tid] = acc;
}

// one-time weight split+pack: virtual W = [4096][K1+K2] = concat(w1, w2) row-wise,
// packed so one wave's 16x32 fragment (hi then lo) is two contiguous 1KB lines.
__global__ __launch_bounds__(256) void wpack_kernel(
    const float* __restrict__ w1, int K1, const float* __restrict__ w2, int K2,
    u16* __restrict__ dst)
{
    const int K = K1 + K2;
    int idx = blockIdx.x * 256 + threadIdx.x;
    if (idx >= 4096 * K) return;
    int n = idx / K, k = idx % K;
    float v = (k < K1) ? w1[n * K1 + k] : w2[n * K2 + (k - K1)];
    u16 h, l;
    split1(v, h, l);
    int tile = n >> 4, kc = k >> 5;
    int lane = (n & 15) + (((k & 31) >> 3) << 4);
    size_t off = ((size_t)(tile * (K >> 5) + kc) * 2) * 512 + lane * 8 + (k & 7);
    dst[off] = h;
    dst[off + 512] = l;
}

// ---------------- fp32 fallback K-split GEMM (proven round-5 body) ----------------
struct SmemGemm { float Xs[32][68]; float Ws[32][68]; };

__device__ void gemm_phase(
    const float* __restrict__ X1, int ldx1, int kx1,
    const float* __restrict__ X2, int ldx2,
    const float* __restrict__ W1, int ldw1, int kw1,
    const float* __restrict__ W2, int ldw2,
    float* __restrict__ outp, int Kq, int blk, SmemGemm& s)
{
    const int tid = threadIdx.x;
    const int n0 = (blk & 63) * 64;
    const int ks = blk >> 6;
    const int kbeg = ks * Kq;
    const int tn = tid & 15, tm = tid >> 4;
    float acc[4][4];
#pragma unroll
    for (int i = 0; i < 4; ++i)
#pragma unroll
        for (int j = 0; j < 4; ++j) acc[i][j] = 0.f;

#pragma unroll 1
    for (int k0 = kbeg; k0 < kbeg + Kq; k0 += 32) {
#pragma unroll
        for (int i = 0; i < 8; ++i) {
            int flat = i * 256 + tid;
            int m = flat >> 5, c = flat & 31;
            int k = k0 + c;
            s.Xs[c][m] = (k < kx1) ? X1[m * ldx1 + k] : X2[m * ldx2 + (k - kx1)];
        }
#pragma unroll
        for (int i = 0; i < 8; ++i) {
            int flat = i * 256 + tid;
            int r = flat >> 5, c = flat & 31;
            int k = k0 + c;
            int n = n0 + r;
            s.Ws[c][r] = (k < kw1) ? W1[n * ldw1 + k] : W2[n * ldw2 + (k - kw1)];
        }
        __syncthreads();
#pragma unroll
        for (int kk = 0; kk < 32; ++kk) {
            float4 xv = *(const float4*)&s.Xs[kk][tm * 4];
            float4 wv = *(const float4*)&s.Ws[kk][tn * 4];
            float xr[4] = { xv.x, xv.y, xv.z, xv.w };
            float wr[4] = { wv.x, wv.y, wv.z, wv.w };
#pragma unroll
            for (int i = 0; i < 4; ++i)
#pragma unroll
                for (int j = 0; j < 4; ++j) acc[i][j] += xr[i] * wr[j];
        }
        __syncthreads();
    }
    float* o = outp + (size_t)ks * 64 * 4096;
#pragma unroll
    for (int i = 0; i < 4; ++i)
#pragma unroll
        for (int j = 0; j < 4; ++j)
            o[(tm * 4 + i) * 4096 + (n0 + tn * 4 + j)] = acc[i][j];
}

__global__ __launch_bounds__(256, 2) void pair_gemm(
    const float* __restrict__ xcat_dec,
    const float* __restrict__ dec_wih, const float* __restrict__ dec_whh,
    float* __restrict__ g2,
    const float* __restrict__ x, const float* __restrict__ xcat_att,
    const float* __restrict__ att_wih, const float* __restrict__ att_whh,
    float* __restrict__ g1, int t)
{
    __shared__ __align__(16) SmemGemm sm;
    const int blk = blockIdx.x;
    if (blk < 256) {
        if (t < 0) return;
        gemm_phase(xcat_dec, 2560, 2560, xcat_dec, 2560,
                   dec_wih, 1536, 1536, dec_whh, 1024, g2, 640, blk, sm);
    } else {
        const int tn = t + 1;
        if (tn >= TOUT) return;
        gemm_phase(x + (size_t)tn * (NB * PREN), PREN, PREN, xcat_att, 1536,
                   att_wih, 768, 768, att_whh, 1024, g1, 448, blk - 256, sm);
    }
}

// ---------------- MFMA pair gemm: 1 n-tile/block, K-split 2, grid 1024 (4 blk/CU) ----------------
// blk 0-511: gemm2(t), tile=blk>>1, ks=blk&1. blk 512-1023: gemm1(t+1).
// 4 waves/block own m-rows 16w..16w+15. B fragments contiguous 1KB lines.
__global__ __launch_bounds__(256) void mfma_pair_gemm(
    const u16* __restrict__ xdech, const u16* __restrict__ xdecl,
    const u16* __restrict__ pk2, float* __restrict__ g2,
    const float* __restrict__ x,
    const u16* __restrict__ tailh, const u16* __restrict__ taill,
    const u16* __restrict__ pk1, float* __restrict__ g1, int t)
{
    const int blk = blockIdx.x;
    const int tid = threadIdx.x;
    const int wave = tid >> 6, lane = tid & 63;
    const int lr = lane & 15, kg = lane >> 4;
    const int mrow = wave * 16 + lr;
    f32x4 acc = {0.f, 0.f, 0.f, 0.f};

    if (blk < 512) {
        if (t < 0) return;
        const int tile = blk >> 1, ks = blk & 1;
        const int c_beg = ks * (NCH2 / 2), c_end = c_beg + NCH2 / 2;
        const u16* Ah = xdech + mrow * 2560;
        const u16* Al = xdecl + mrow * 2560;
        const u16* bp = pk2 + (size_t)tile * NCH2 * 1024 + lane * 8;
#pragma unroll 4
        for (int kc = c_beg; kc < c_end; ++kc) {
            const int k = kc * 32 + kg * 8;
            bf16x8 ah = *(const bf16x8*)(Ah + k);
            bf16x8 al = *(const bf16x8*)(Al + k);
            const u16* c0 = bp + (size_t)kc * 1024;
            bf16x8 bh = *(const bf16x8*)c0;
            bf16x8 bl = *(const bf16x8*)(c0 + 512);
            acc = MFMA16(ah, bh, acc); acc = MFMA16(ah, bl, acc); acc = MFMA16(al, bh, acc);
        }
        const int n0 = tile * 16;
        const int mbase = wave * 16 + kg * 4;
        float* o = g2 + (size_t)ks * 262144;
#pragma unroll
        for (int r = 0; r < 4; ++r)
            o[(mbase + r) * 4096 + n0 + lr] = acc[r];
    } else {
        const int tn = t + 1;
        if (tn >= TOUT) return;
        const int bb = blk - 512;
        const int tile = bb >> 1, ks = bb & 1;
        const int c_beg = ks * (NCH1 / 2), c_end = c_beg + NCH1 / 2;
        const u16* Ah = tailh + mrow * 1536;
        const u16* Al = taill + mrow * 1536;
        const float* xr = x + ((size_t)tn * 64 + mrow) * 256;
        const u16* bp = pk1 + (size_t)tile * NCH1 * 1024 + lane * 8;
#pragma unroll 4
        for (int kc = c_beg; kc < c_end; ++kc) {
            const int k = kc * 32 + kg * 8;
            bf16x8 ah, al;
            if (k < 256) {
                float4 f0 = *(const float4*)(xr + k);
                float4 f1 = *(const float4*)(xr + k + 4);
                split8(f0, f1, ah, al);
            } else {
                ah = *(const bf16x8*)(Ah + (k - 256));
                al = *(const bf16x8*)(Al + (k - 256));
            }
            const u16* c0 = bp + (size_t)kc * 1024;
            bf16x8 bh = *(const bf16x8*)c0;
            bf16x8 bl = *(const bf16x8*)(c0 + 512);
            acc = MFMA16(ah, bh, acc); acc = MFMA16(ah, bl, acc); acc = MFMA16(al, bh, acc);
        }
        const int n0 = tile * 16;
        const int mbase = wave * 16 + kg * 4;
        float* o = g1 + (size_t)ks * 262144;
#pragma unroll
        for (int r = 0; r < 4; ++r)
            o[(mbase + r) * 4096 + n0 + lr] = acc[r];
    }
}

// ---------------- L1: att_pointwise(t) || dec_pointwise+proj(t-1) ----------------
__global__ __launch_bounds__(256) void pair_pw(
    const float* __restrict__ g1, const float* __restrict__ att_bih, const float* __restrict__ att_bhh,
    float* __restrict__ ac, float* __restrict__ xcat_att, float* __restrict__ xcat_dec,
    const float* __restrict__ wq, float* __restrict__ pq,
    const float* __restrict__ g2, const float* __restrict__ dec_bih, const float* __restrict__ dec_bhh,
    float* __restrict__ dc, const float* __restrict__ proj_w, const float* __restrict__ proj_b,
    const float* __restrict__ gate_w, const float* __restrict__ gate_b,
    float* __restrict__ out,
    u16* __restrict__ tailh, u16* __restrict__ taill,
    u16* __restrict__ xdech, u16* __restrict__ xdecl,
    int nsplit, int t)
{
    const int tid = threadIdx.x;
    __shared__ float sbuf[1536];
    __shared__ float red[256];

    if (blockIdx.x < 64) {
        if (t >= TOUT) return;
        const int b = blockIdx.x;
#pragma unroll
        for (int q = 0; q < 4; ++q) {
            int j = q * 256 + tid;
            float gi = att_bih[j] + att_bhh[j];
            float gf = att_bih[1024 + j] + att_bhh[1024 + j];
            float gg = att_bih[2048 + j] + att_bhh[2048 + j];
            float go = att_bih[3072 + j] + att_bhh[3072 + j];
            for (int s = 0; s < nsplit; ++s) {
                const float* g = g1 + (size_t)s * 262144 + b * 4096;
                gi += g[j]; gf += g[1024 + j]; gg += g[2048 + j]; go += g[3072 + j];
            }
            float c = sigf(gf) * ac[b * 1024 + j] + sigf(gi) * tanhf(gg);
            float h = sigf(go) * tanhf(c);
            ac[b * 1024 + j] = c;
            xcat_att[b * 1536 + 512 + j] = h;
            xcat_dec[b * 2560 + j] = h;
            u16 hh, hl; split1(h, hh, hl);
            tailh[b * 1536 + 512 + j] = hh;  taill[b * 1536 + 512 + j] = hl;
            xdech[b * 2560 + j] = hh;        xdecl[b * 2560 + j] = hl;
            sbuf[j] = h;
        }
        __syncthreads();
        const int a = tid & 127, half = tid >> 7;
        float s = 0.f;
        const float* wr = wq + a * 1024 + half * 512;
        const float* hh = sbuf + half * 512;
#pragma unroll 4
        for (int k = 0; k < 512; k += 4) {
            float4 wv = *(const float4*)&wr[k];
            float4 hv = *(const float4*)&hh[k];
            s += hv.x * wv.x + hv.y * wv.y + hv.z * wv.z + hv.w * wv.w;
        }
        red[tid] = s;
        __syncthreads();
        if (half == 0) pq[b * 128 + a] = red[a] + red[a + 128];
    } else {
        if (t < 1) return;
        const int b = blockIdx.x - 64;
        const int ts = t - 1;
#pragma unroll
        for (int q = 0; q < 4; ++q) {
            int j = q * 256 + tid;
            float gi = dec_bih[j] + dec_bhh[j];
            float gf = dec_bih[1024 + j] + dec_bhh[1024 + j];
            float gg = dec_bih[2048 + j] + dec_bhh[2048 + j];
            float go = dec_bih[3072 + j] + dec_bhh[3072 + j];
            for (int s = 0; s < nsplit; ++s) {
                const float* g = g2 + (size_t)s * 262144 + b * 4096;
                gi += g[j]; gf += g[1024 + j]; gg += g[2048 + j]; go += g[3072 + j];
            }
            float c = sigf(gf) * dc[b * 1024 + j] + sigf(gi) * tanhf(gg);
            float h = sigf(go) * tanhf(c);
            dc[b * 1024 + j] = c;
            xcat_dec[b * 2560 + 1536 + j] = h;
            u16 hh, hl; split1(h, hh, hl);
            xdech[b * 2560 + 1536 + j] = hh;  xdecl[b * 2560 + 1536 + j] = hl;
            sbuf[j] = h;
        }
        for (int i = tid; i < 512; i += 256) sbuf[1024 + i] = xcat_dec[b * 2560 + 1024 + i];
        __syncthreads();
        const int o = tid >> 1, half = tid & 1;
        float accv = 0.f;
        if (o <= 80) {
            const float* w = (o < 80) ? (proj_w + o * 1536) : gate_w;
            const float* sv = sbuf + half * 768;
            const float* wv = w + half * 768;
#pragma unroll 4
            for (int k = 0; k < 768; k += 4) {
                float4 a4 = *(const float4*)&sv[k];
                float4 b4 = *(const float4*)&wv[k];
                accv += a4.x * b4.x + a4.y * b4.y + a4.z * b4.z + a4.w * b4.w;
            }
        }
        red[tid] = accv;
        __syncthreads();
        if (half == 0 && o <= 80) {
            float r = red[tid] + red[tid + 1];
            if (o < 80)
                out[MEL_OFF + (size_t)b * (TOUT * NMEL) + (size_t)ts * NMEL + o] = r + proj_b[o];
            else
                out[GATE_OFF + (size_t)b * TOUT + ts] = r + gate_b[0];
        }
    }
}

// ---------------- L2: conv + loc_dense + energies ----------------
__global__ __launch_bounds__(256) void energies_kernel(
    const float* __restrict__ aw, const float* __restrict__ awc,
    const float* __restrict__ lc, const float* __restrict__ ld,
    const float* __restrict__ vvec, const float* __restrict__ pq,
    const float* __restrict__ pm, float* __restrict__ energ)
{
    const int b = blockIdx.x, tc = blockIdx.y;
    const int t0 = tc * 128;
    const int tid = threadIdx.x;
    __shared__ float awin[160], awcin[160];
    __shared__ float lcs[NFILT * 62];
    __shared__ float locs[128 * 33];
    __shared__ float pqs[ATTD], vs[ATTD];
    __shared__ float ldm[ATTD * NFILT];
    __shared__ float ered[256];

    for (int i = tid; i < 158; i += 256) {
        int t = t0 + i - CPAD;
        bool ok = (t >= 0 && t < TIN);
        awin[i]  = ok ? aw[b * TIN + t]  : 0.f;
        awcin[i] = ok ? awc[b * TIN + t] : 0.f;
    }
    for (int i = tid; i < NFILT * 62; i += 256) lcs[i] = lc[i];
    for (int i = tid; i < ATTD * NFILT; i += 256) ldm[i] = ld[i];
    if (tid < ATTD) { pqs[tid] = pq[b * ATTD + tid]; vs[tid] = vvec[tid]; }
    __syncthreads();

    for (int idx = tid; idx < 128 * 32; idx += 256) {
        int tl = idx >> 5, f = idx & 31;
        const float* w0 = lcs + f * 62;
        float s = 0.f;
#pragma unroll
        for (int k = 0; k < KSZ; ++k)
            s += awin[tl + k] * w0[k] + awcin[tl + k] * w0[31 + k];
        locs[tl * 33 + f] = s;
    }
    __syncthreads();

    const int tl = tid >> 1, half = tid & 1;
    float e = 0.f;
    const float* pmrow = pm + (size_t)b * (TIN * ATTD) + (size_t)(t0 + tl) * ATTD + half * 64;
    const float* lt = locs + tl * 33;
    for (int a = 0; a < 64; ++a) {
        const float* lrow = ldm + (half * 64 + a) * 32;
        float s = pqs[half * 64 + a] + pmrow[a];
#pragma unroll
        for (int f = 0; f < NFILT; ++f) s += lt[f] * lrow[f];
        e += vs[half * 64 + a] * tanhf(s);
    }
    ered[tid] = e;
    __syncthreads();
    if (half == 0) energ[b * TIN + t0 + tl] = ered[tid] + ered[tid + 1];
}

// ---------------- L3: distributed softmax + aw/awc + align + ctx (256 blocks = 64b x 4dq) ----------------
__global__ __launch_bounds__(256) void softmax_ctx_kernel(
    const float* __restrict__ energ, const int* __restrict__ mlen,
    const float* __restrict__ memory,
    float* __restrict__ aw, float* __restrict__ awc,
    float* __restrict__ out_align, int t_step,
    float* __restrict__ xcat_att, float* __restrict__ xcat_dec,
    u16* __restrict__ tailh, u16* __restrict__ taill,
    u16* __restrict__ xdech, u16* __restrict__ xdecl)
{
    const int b = blockIdx.x >> 2, dq = blockIdx.x & 3;
    const int tid = threadIdx.x;
    const int len = mlen[b];
    __shared__ float es[TIN];
    __shared__ float red[256];

    float e1 = (tid < len) ? energ[b * TIN + tid] : -INFINITY;
    float e2 = (tid + 256 < len) ? energ[b * TIN + tid + 256] : -INFINITY;
    red[tid] = fmaxf(e1, e2);
    __syncthreads();
    for (int s = 128; s > 0; s >>= 1) {
        if (tid < s) red[tid] = fmaxf(red[tid], red[tid + s]);
        __syncthreads();
    }
    const float mx = red[0];
    __syncthreads();
    float p1 = expf(e1 - mx);
    float p2 = expf(e2 - mx);
    red[tid] = p1 + p2;
    __syncthreads();
    for (int s = 128; s > 0; s >>= 1) {
        if (tid < s) red[tid] += red[tid + s];
        __syncthreads();
    }
    const float inv = 1.f / red[0];
    p1 *= inv; p2 *= inv;
    es[tid] = p1; es[tid + 256] = p2;
    __syncthreads();

    if (tid < 128) {
        int tt = dq * 128 + tid;
        float p = es[tt];
        aw[b * TIN + tt] = p;
        awc[b * TIN + tt] += p;
        out_align[(size_t)b * (TOUT * TIN) + (size_t)t_step * TIN + tt] = p;
    }

    const int d = dq * 128 + (tid & 127), th = tid >> 7;
    const float* mb = memory + (size_t)b * (TIN * ENC);
    float accv = 0.f;
#pragma unroll 4
    for (int tt = th * 256; tt < th * 256 + 256; ++tt)
        accv += es[tt] * mb[(size_t)tt * ENC + d];
    __syncthreads();
    red[tid] = accv;
    __syncthreads();
    if (tid < 128) {
        float cv = red[tid] + red[tid + 128];
        int dd = dq * 128 + tid;
        xcat_att[b * 1536 + dd] = cv;
        xcat_dec[b * 2560 + 1024 + dd] = cv;
        u16 h, l; split1(cv, h, l);
        tailh[b * 1536 + dd] = h;        taill[b * 1536 + dd] = l;
        xdech[b * 2560 + 1024 + dd] = h; xdecl[b * 2560 + 1024 + dd] = l;
    }
}

extern "C" void kernel_launch(void* const* d_in, const int* in_sizes, int n_in,
                              void* d_out, int out_size, void* d_ws, size_t ws_size,
                              hipStream_t stream) {
    const float* memory   = (const float*)d_in[0];
    const float* dec_in   = (const float*)d_in[1];
    const int*   mlen     = (const int*)d_in[2];
    const float* pw1      = (const float*)d_in[3];
    const float* pw2      = (const float*)d_in[4];
    const float* att_wih  = (const float*)d_in[5];
    const float* att_whh  = (const float*)d_in[6];
    const float* att_bih  = (const float*)d_in[7];
    const float* att_bhh  = (const float*)d_in[8];
    const float* wq       = (const float*)d_in[9];
    const float* wm       = (const float*)d_in[10];
    const float* v        = (const float*)d_in[11];
    const float* loc_conv = (const float*)d_in[12];
    const float* loc_dense= (const float*)d_in[13];
    const float* dec_wih  = (const float*)d_in[14];
    const float* dec_whh  = (const float*)d_in[15];
    const float* dec_bih  = (const float*)d_in[16];
    const float* dec_bhh  = (const float*)d_in[17];
    const float* proj_w   = (const float*)d_in[18];
    const float* proj_b   = (const float*)d_in[19];
    const float* gate_w   = (const float*)d_in[20];
    const float* gate_b   = (const float*)d_in[21];
    float* out = (float*)d_out;

    // ---- ws layout ----
    float* x        = (float*)d_ws;
    float* pm       = x + X_SZ;
    float* g1       = pm + PM_SZ;
    float* g2       = g1 + G1_SZ;
    float* xcat_att = g2 + G2_SZ;          // zero-block start
    float* xcat_dec = xcat_att + XATT_SZ;
    float* ac       = xcat_dec + XDEC_SZ;
    float* dc       = ac + AC_SZ;
    float* aw       = dc + DC_SZ;
    float* awc      = aw + AW_SZ;
    float* tailh_f  = awc + AWC_SZ;
    float* taill_f  = tailh_f + TAILH_SZ;
    float* xdech_f  = taill_f + TAILL_SZ;
    float* xdecl_f  = xdech_f + XDH_SZ;    // zero-block end
    float* pq       = xdecl_f + XDL_SZ;
    float* energ    = pq + PQ_SZ;
    unsigned char* m1 = (unsigned char*)(energ + EN_SZ);
    unsigned char* m2 = m1 + MASK_N;
    u16* pk1 = (u16*)(m2 + MASK_N);
    u16* pk2 = pk1 + PK1_N;

    u16* tailh = (u16*)tailh_f;  u16* taill = (u16*)taill_f;
    u16* xdech = (u16*)xdech_f;  u16* xdecl = (u16*)xdecl_f;

    size_t need_base = (size_t)(m2 + MASK_N - (unsigned char*)d_ws);
    size_t need_full = (size_t)((unsigned char*)(pk2 + PK2_N) - (unsigned char*)d_ws);
    if (ws_size < need_base) return;
    const bool use_mfma = (ws_size >= need_full);
    const int nsplit = use_mfma ? 2 : 4;

    // zero recurrent state (xcat_att .. xdecl contiguous)
    size_t state_floats = (size_t)XATT_SZ + XDEC_SZ + AC_SZ + DC_SZ + AW_SZ + AWC_SZ
                        + TAILH_SZ + TAILL_SZ + XDH_SZ + XDL_SZ;
    hipMemsetAsync(xcat_att, 0, state_floats * sizeof(float), stream);

    // one-time: dropout masks, prenet, processed memory, weight pack
    mask_kernel<<<(MASK_N + 255) / 256, 256, 0, stream>>>(m1, m2);
    prenet1_kernel<<<TOUT * NB, 256, 0, stream>>>(dec_in, pw1, m1, x);
    prenet2_kernel<<<TOUT * NB, 256, 0, stream>>>(pw2, m2, x);
    pm_kernel<<<dim3(NB, TIN), 128, 0, stream>>>(memory, wm, pm);
    if (use_mfma) {
        wpack_kernel<<<(4096 * K1TOT + 255) / 256, 256, 0, stream>>>(att_wih, 768, att_whh, 1024, pk1);
        wpack_kernel<<<(4096 * K2TOT + 255) / 256, 256, 0, stream>>>(dec_wih, 1536, dec_whh, 1024, pk2);
    }

    float* out_align = out + ALGN_OFF;

    // prologue: gemm1 for t=0
    if (use_mfma)
        mfma_pair_gemm<<<1024, 256, 0, stream>>>(xdech, xdecl, pk2, g2, x, tailh, taill, pk1, g1, -1);
    else
        pair_gemm<<<512, 256, 0, stream>>>(xcat_dec, dec_wih, dec_whh, g2,
                                           x, xcat_att, att_wih, att_whh, g1, -1);

    for (int t = 0; t < TOUT; ++t) {
        pair_pw<<<128, 256, 0, stream>>>(g1, att_bih, att_bhh, ac, xcat_att, xcat_dec, wq, pq,
                                         g2, dec_bih, dec_bhh, dc, proj_w, proj_b,
                                         gate_w, gate_b, out, tailh, taill, xdech, xdecl,
                                         nsplit, t);
        energies_kernel<<<dim3(NB, 4), 256, 0, stream>>>(aw, awc, loc_conv, loc_dense, v, pq, pm, energ);
        softmax_ctx_kernel<<<256, 256, 0, stream>>>(energ, mlen, memory, aw, awc, out_align, t,
                                                    xcat_att, xcat_dec, tailh, taill, xdech, xdecl);
        if (use_mfma)
            mfma_pair_gemm<<<1024, 256, 0, stream>>>(xdech, xdecl, pk2, g2, x, tailh, taill, pk1, g1, t);
        else
            pair_gemm<<<512, 256, 0, stream>>>(xcat_dec, dec_wih, dec_whh, g2,
                                               x, xcat_att, att_wih, att_whh, g1, t);
    }
    // epilogue: dec_pointwise+proj for t=499
    pair_pw<<<128, 256, 0, stream>>>(g1, att_bih, att_bhh, ac, xcat_att, xcat_dec, wq, pq,
                                     g2, dec_bih, dec_bhh, dc, proj_w, proj_b,
                                     gate_w, gate_b, out, tailh, taill, xdech, xdecl,
                                     nsplit, TOUT);
}

// Round 9
// 61154.510 us; speedup vs baseline: 4.0304x; 1.0671x over previous
//
#include <hip/hip_runtime.h>
#include <cstdint>
#include <cstddef>

// ---------------- constants ----------------
#define NB    64      // batch
#define TIN   512
#define TOUT  500
#define NMEL  80
#define ENC   512
#define ATTD  128
#define ARNN  1024
#define DRNN  1024
#define PREN  256
#define NFILT 32
#define KSZ   31
#define CPAD  15

#define MEL_OFF  0
#define GATE_OFF 2560000
#define ALGN_OFF 2592000

// ws float-layout sizes
#define X_SZ      8192000
#define PM_SZ     4194304
#define G1_SZ     1048576
#define G2_SZ     1048576
#define XATT_SZ   98304
#define XDEC_SZ   163840
#define AC_SZ     65536
#define DC_SZ     65536
#define AW_SZ     32768
#define AWC_SZ    32768
#define TAILH_SZ  49152
#define TAILL_SZ  49152
#define XDH_SZ    81920
#define XDL_SZ    81920
#define PQ_SZ     8192
#define EN_SZ     32768
#define MASK_N    8208384

// packed bf16 weights: [256 ntile][K/32 kchunk][2 hl][512]
#define K1TOT   1792
#define K2TOT   2560
#define NCH1    56
#define NCH2    80
#define PK1_N   14680064
#define PK2_N   20971520

typedef unsigned short u16;
typedef __attribute__((ext_vector_type(8))) short bf16x8;
typedef __attribute__((ext_vector_type(4))) float f32x4;

__device__ __forceinline__ uint32_t rotl32(uint32_t v, int r) { return (v << r) | (v >> (32 - r)); }

// fast saturating transcendentals (v_exp-based; safe at |x| large: inf handled)
__device__ __forceinline__ float sigf(float x) { return 1.f / (1.f + __expf(-x)); }
__device__ __forceinline__ float tanhf_fast(float x) {
    float ax = fabsf(x);
    float t = 1.f - 2.f / (__expf(2.f * ax) + 1.f);   // exp(inf)=inf -> t=1
    return copysignf(t, x);
}

// Dekker-style split: hi = truncate-to-bf16(v), lo = rn-bf16(v - hi).
__device__ __forceinline__ void split1(float v, u16& h, u16& l) {
    uint32_t u = __float_as_uint(v);
    h = (u16)(u >> 16);
    float r = v - __uint_as_float(u & 0xFFFF0000u);
    uint32_t ru = __float_as_uint(r);
    ru += 0x7FFFu + ((ru >> 16) & 1u);
    l = (u16)(ru >> 16);
}

__device__ __forceinline__ void split8(float4 f0, float4 f1, bf16x8& h, bf16x8& l) {
    float v[8] = { f0.x, f0.y, f0.z, f0.w, f1.x, f1.y, f1.z, f1.w };
#pragma unroll
    for (int i = 0; i < 8; ++i) {
        uint32_t u = __float_as_uint(v[i]);
        h[i] = (short)(u >> 16);
        float r = v[i] - __uint_as_float(u & 0xFFFF0000u);
        uint32_t ru = __float_as_uint(r);
        ru += 0x7FFFu + ((ru >> 16) & 1u);
        l[i] = (short)(ru >> 16);
    }
}

#define MFMA16(a, b, c) __builtin_amdgcn_mfma_f32_16x16x32_bf16(a, b, c, 0, 0, 0)

// JAX threefry2x32
__device__ void tf_block(uint32_t k1, uint32_t k2, uint32_t& x0, uint32_t& x1) {
    uint32_t ks0 = k1, ks1 = k2, ks2 = k1 ^ k2 ^ 0x1BD11BDAu;
    x0 += ks0; x1 += ks1;
#define TFR(r) { x0 += x1; x1 = rotl32(x1, r); x1 ^= x0; }
    TFR(13) TFR(15) TFR(26) TFR(6)   x0 += ks1; x1 += ks2 + 1u;
    TFR(17) TFR(29) TFR(16) TFR(24)  x0 += ks2; x1 += ks0 + 2u;
    TFR(13) TFR(15) TFR(26) TFR(6)   x0 += ks0; x1 += ks1 + 3u;
    TFR(17) TFR(29) TFR(16) TFR(24)  x0 += ks1; x1 += ks2 + 4u;
    TFR(13) TFR(15) TFR(26) TFR(6)   x0 += ks2; x1 += ks0 + 5u;
#undef TFR
}

__global__ __launch_bounds__(256) void mask_kernel(unsigned char* m1, unsigned char* m2) {
    int i = blockIdx.x * 256 + threadIdx.x;
    if (i >= MASK_N) return;
    uint32_t a0 = 0u, a1 = 0u; tf_block(0u, 42u, a0, a1);
    uint32_t b0 = 0u, b1 = 1u; tf_block(0u, 42u, b0, b1);
    uint32_t x0, x1;
    x0 = 0u; x1 = (uint32_t)i; tf_block(a0, a1, x0, x1);
    m1[i] = ((x0 ^ x1) >> 31) == 0u;
    x0 = 0u; x1 = (uint32_t)i; tf_block(b0, b1, x0, x1);
    m2[i] = ((x0 ^ x1) >> 31) == 0u;
}

__global__ __launch_bounds__(256) void prenet1_kernel(
    const float* __restrict__ dec_in, const float* __restrict__ w1,
    const unsigned char* __restrict__ m1, float* __restrict__ x)
{
    int r = blockIdx.x;
    int t = r >> 6, b = r & 63;
    int tid = threadIdx.x;
    __shared__ float ds[NMEL];
    if (tid < NMEL) ds[tid] = (t == 0) ? 0.f : dec_in[(size_t)b * 40000 + tid * 500 + (t - 1)];
    __syncthreads();
    float acc = 0.f;
    const float* w = w1 + tid * NMEL;
#pragma unroll
    for (int k = 0; k < NMEL; ++k) acc += ds[k] * w[k];
    acc = fmaxf(acc, 0.f);
    int flat = r * 256 + tid;
    x[flat] = m1[flat] ? acc * 2.f : 0.f;
}

__global__ __launch_bounds__(256) void prenet2_kernel(
    const float* __restrict__ w2, const unsigned char* __restrict__ m2, float* x)
{
    int r = blockIdx.x;
    int tid = threadIdx.x;
    __shared__ float xs[PREN];
    xs[tid] = x[r * 256 + tid];
    __syncthreads();
    float acc = 0.f;
    const float* w = w2 + tid * PREN;
#pragma unroll 8
    for (int k = 0; k < PREN; ++k) acc += xs[k] * w[k];
    acc = fmaxf(acc, 0.f);
    int flat = r * 256 + tid;
    x[flat] = m2[flat] ? acc * 2.f : 0.f;
}

__global__ __launch_bounds__(128) void pm_kernel(
    const float* __restrict__ memory, const float* __restrict__ wm, float* __restrict__ pm)
{
    int b = blockIdx.x, t = blockIdx.y;
    int tid = threadIdx.x;
    __shared__ float ms[ENC];
    for (int i = tid; i < ENC; i += 128) ms[i] = memory[(size_t)b * (TIN * ENC) + (size_t)t * ENC + i];
    __syncthreads();
    float acc = 0.f;
    const float* w = wm + tid * ENC;
#pragma unroll 8
    for (int k = 0; k < ENC; ++k) acc += ms[k] * w[k];
    pm[(size_t)b * (TIN * ATTD) + t * ATTD + tid] = acc;
}

// one-time weight split+pack (fragment-contiguous B lines)
__global__ __launch_bounds__(256) void wpack_kernel(
    const float* __restrict__ w1, int K1, const float* __restrict__ w2, int K2,
    u16* __restrict__ dst)
{
    const int K = K1 + K2;
    int idx = blockIdx.x * 256 + threadIdx.x;
    if (idx >= 4096 * K) return;
    int n = idx / K, k = idx % K;
    float v = (k < K1) ? w1[n * K1 + k] : w2[n * K2 + (k - K1)];
    u16 h, l;
    split1(v, h, l);
    int tile = n >> 4, kc = k >> 5;
    int lane = (n & 15) + (((k & 31) >> 3) << 4);
    size_t off = ((size_t)(tile * (K >> 5) + kc) * 2) * 512 + lane * 8 + (k & 7);
    dst[off] = h;
    dst[off + 512] = l;
}

// ---------------- fp32 fallback K-split GEMM ----------------
struct SmemGemm { float Xs[32][68]; float Ws[32][68]; };

__device__ void gemm_phase(
    const float* __restrict__ X1, int ldx1, int kx1,
    const float* __restrict__ X2, int ldx2,
    const float* __restrict__ W1, int ldw1, int kw1,
    const float* __restrict__ W2, int ldw2,
    float* __restrict__ outp, int Kq, int blk, SmemGemm& s)
{
    const int tid = threadIdx.x;
    const int n0 = (blk & 63) * 64;
    const int ks = blk >> 6;
    const int kbeg = ks * Kq;
    const int tn = tid & 15, tm = tid >> 4;
    float acc[4][4];
#pragma unroll
    for (int i = 0; i < 4; ++i)
#pragma unroll
        for (int j = 0; j < 4; ++j) acc[i][j] = 0.f;

#pragma unroll 1
    for (int k0 = kbeg; k0 < kbeg + Kq; k0 += 32) {
#pragma unroll
        for (int i = 0; i < 8; ++i) {
            int flat = i * 256 + tid;
            int m = flat >> 5, c = flat & 31;
            int k = k0 + c;
            s.Xs[c][m] = (k < kx1) ? X1[m * ldx1 + k] : X2[m * ldx2 + (k - kx1)];
        }
#pragma unroll
        for (int i = 0; i < 8; ++i) {
            int flat = i * 256 + tid;
            int r = flat >> 5, c = flat & 31;
            int k = k0 + c;
            int n = n0 + r;
            s.Ws[c][r] = (k < kw1) ? W1[n * ldw1 + k] : W2[n * ldw2 + (k - kw1)];
        }
        __syncthreads();
#pragma unroll
        for (int kk = 0; kk < 32; ++kk) {
            float4 xv = *(const float4*)&s.Xs[kk][tm * 4];
            float4 wv = *(const float4*)&s.Ws[kk][tn * 4];
            float xr[4] = { xv.x, xv.y, xv.z, xv.w };
            float wr[4] = { wv.x, wv.y, wv.z, wv.w };
#pragma unroll
            for (int i = 0; i < 4; ++i)
#pragma unroll
                for (int j = 0; j < 4; ++j) acc[i][j] += xr[i] * wr[j];
        }
        __syncthreads();
    }
    float* o = outp + (size_t)ks * 64 * 4096;
#pragma unroll
    for (int i = 0; i < 4; ++i)
#pragma unroll
        for (int j = 0; j < 4; ++j)
            o[(tm * 4 + i) * 4096 + (n0 + tn * 4 + j)] = acc[i][j];
}

__global__ __launch_bounds__(256, 2) void pair_gemm(
    const float* __restrict__ xcat_dec,
    const float* __restrict__ dec_wih, const float* __restrict__ dec_whh,
    float* __restrict__ g2,
    const float* __restrict__ x, const float* __restrict__ xcat_att,
    const float* __restrict__ att_wih, const float* __restrict__ att_whh,
    float* __restrict__ g1, int t)
{
    __shared__ __align__(16) SmemGemm sm;
    const int blk = blockIdx.x;
    if (blk < 256) {
        if (t < 0) return;
        gemm_phase(xcat_dec, 2560, 2560, xcat_dec, 2560,
                   dec_wih, 1536, 1536, dec_whh, 1024, g2, 640, blk, sm);
    } else {
        const int tn = t + 1;
        if (tn >= TOUT) return;
        gemm_phase(x + (size_t)tn * (NB * PREN), PREN, PREN, xcat_att, 1536,
                   att_wih, 768, 768, att_whh, 1024, g1, 448, blk - 256, sm);
    }
}

// ---------------- MFMA pair gemm (round-8 body, unchanged) ----------------
__global__ __launch_bounds__(256) void mfma_pair_gemm(
    const u16* __restrict__ xdech, const u16* __restrict__ xdecl,
    const u16* __restrict__ pk2, float* __restrict__ g2,
    const float* __restrict__ x,
    const u16* __restrict__ tailh, const u16* __restrict__ taill,
    const u16* __restrict__ pk1, float* __restrict__ g1, int t)
{
    const int blk = blockIdx.x;
    const int tid = threadIdx.x;
    const int wave = tid >> 6, lane = tid & 63;
    const int lr = lane & 15, kg = lane >> 4;
    const int mrow = wave * 16 + lr;
    f32x4 acc = {0.f, 0.f, 0.f, 0.f};

    if (blk < 512) {
        if (t < 0) return;
        const int tile = blk >> 1, ks = blk & 1;
        const int c_beg = ks * (NCH2 / 2), c_end = c_beg + NCH2 / 2;
        const u16* Ah = xdech + mrow * 2560;
        const u16* Al = xdecl + mrow * 2560;
        const u16* bp = pk2 + (size_t)tile * NCH2 * 1024 + lane * 8;
#pragma unroll 4
        for (int kc = c_beg; kc < c_end; ++kc) {
            const int k = kc * 32 + kg * 8;
            bf16x8 ah = *(const bf16x8*)(Ah + k);
            bf16x8 al = *(const bf16x8*)(Al + k);
            const u16* c0 = bp + (size_t)kc * 1024;
            bf16x8 bh = *(const bf16x8*)c0;
            bf16x8 bl = *(const bf16x8*)(c0 + 512);
            acc = MFMA16(ah, bh, acc); acc = MFMA16(ah, bl, acc); acc = MFMA16(al, bh, acc);
        }
        const int n0 = tile * 16;
        const int mbase = wave * 16 + kg * 4;
        float* o = g2 + (size_t)ks * 262144;
#pragma unroll
        for (int r = 0; r < 4; ++r)
            o[(mbase + r) * 4096 + n0 + lr] = acc[r];
    } else {
        const int tn = t + 1;
        if (tn >= TOUT) return;
        const int bb = blk - 512;
        const int tile = bb >> 1, ks = bb & 1;
        const int c_beg = ks * (NCH1 / 2), c_end = c_beg + NCH1 / 2;
        const u16* Ah = tailh + mrow * 1536;
        const u16* Al = taill + mrow * 1536;
        const float* xr = x + ((size_t)tn * 64 + mrow) * 256;
        const u16* bp = pk1 + (size_t)tile * NCH1 * 1024 + lane * 8;
#pragma unroll 4
        for (int kc = c_beg; kc < c_end; ++kc) {
            const int k = kc * 32 + kg * 8;
            bf16x8 ah, al;
            if (k < 256) {
                float4 f0 = *(const float4*)(xr + k);
                float4 f1 = *(const float4*)(xr + k + 4);
                split8(f0, f1, ah, al);
            } else {
                ah = *(const bf16x8*)(Ah + (k - 256));
                al = *(const bf16x8*)(Al + (k - 256));
            }
            const u16* c0 = bp + (size_t)kc * 1024;
            bf16x8 bh = *(const bf16x8*)c0;
            bf16x8 bl = *(const bf16x8*)(c0 + 512);
            acc = MFMA16(ah, bh, acc); acc = MFMA16(ah, bl, acc); acc = MFMA16(al, bh, acc);
        }
        const int n0 = tile * 16;
        const int mbase = wave * 16 + kg * 4;
        float* o = g1 + (size_t)ks * 262144;
#pragma unroll
        for (int r = 0; r < 4; ++r)
            o[(mbase + r) * 4096 + n0 + lr] = acc[r];
    }
}

// ---------------- L1: att_pointwise(t) || dec_pointwise+proj(t-1) ----------------
__global__ __launch_bounds__(256) void pair_pw(
    const float* __restrict__ g1, const float* __restrict__ att_bih, const float* __restrict__ att_bhh,
    float* __restrict__ ac, float* __restrict__ xcat_att, float* __restrict__ xcat_dec,
    const float* __restrict__ wq, float* __restrict__ pq,
    const float* __restrict__ g2, const float* __restrict__ dec_bih, const float* __restrict__ dec_bhh,
    float* __restrict__ dc, const float* __restrict__ proj_w, const float* __restrict__ proj_b,
    const float* __restrict__ gate_w, const float* __restrict__ gate_b,
    float* __restrict__ out,
    u16* __restrict__ tailh, u16* __restrict__ taill,
    u16* __restrict__ xdech, u16* __restrict__ xdecl,
    int nsplit, int t)
{
    const int tid = threadIdx.x;
    __shared__ float sbuf[1536];
    __shared__ float red[256];

    if (blockIdx.x < 64) {
        if (t >= TOUT) return;
        const int b = blockIdx.x;
#pragma unroll
        for (int q = 0; q < 4; ++q) {
            int j = q * 256 + tid;
            float gi = att_bih[j] + att_bhh[j];
            float gf = att_bih[1024 + j] + att_bhh[1024 + j];
            float gg = att_bih[2048 + j] + att_bhh[2048 + j];
            float go = att_bih[3072 + j] + att_bhh[3072 + j];
            for (int s = 0; s < nsplit; ++s) {
                const float* g = g1 + (size_t)s * 262144 + b * 4096;
                gi += g[j]; gf += g[1024 + j]; gg += g[2048 + j]; go += g[3072 + j];
            }
            float c = sigf(gf) * ac[b * 1024 + j] + sigf(gi) * tanhf_fast(gg);
            float h = sigf(go) * tanhf_fast(c);
            ac[b * 1024 + j] = c;
            xcat_att[b * 1536 + 512 + j] = h;
            xcat_dec[b * 2560 + j] = h;
            u16 hh, hl; split1(h, hh, hl);
            tailh[b * 1536 + 512 + j] = hh;  taill[b * 1536 + 512 + j] = hl;
            xdech[b * 2560 + j] = hh;        xdecl[b * 2560 + j] = hl;
            sbuf[j] = h;
        }
        __syncthreads();
        const int a = tid & 127, half = tid >> 7;
        const float* wr = wq + a * 1024 + half * 512;
        const float* hh = sbuf + half * 512;
        float s0 = 0.f, s1 = 0.f, s2 = 0.f, s3 = 0.f;
#pragma unroll 4
        for (int k = 0; k < 512; k += 16) {
            float4 w0 = *(const float4*)&wr[k],      h0 = *(const float4*)&hh[k];
            float4 w1 = *(const float4*)&wr[k + 4],  h1 = *(const float4*)&hh[k + 4];
            float4 w2 = *(const float4*)&wr[k + 8],  h2 = *(const float4*)&hh[k + 8];
            float4 w3 = *(const float4*)&wr[k + 12], h3 = *(const float4*)&hh[k + 12];
            s0 += h0.x * w0.x + h0.y * w0.y + h0.z * w0.z + h0.w * w0.w;
            s1 += h1.x * w1.x + h1.y * w1.y + h1.z * w1.z + h1.w * w1.w;
            s2 += h2.x * w2.x + h2.y * w2.y + h2.z * w2.z + h2.w * w2.w;
            s3 += h3.x * w3.x + h3.y * w3.y + h3.z * w3.z + h3.w * w3.w;
        }
        red[tid] = (s0 + s1) + (s2 + s3);
        __syncthreads();
        if (half == 0) pq[b * 128 + a] = red[a] + red[a + 128];
    } else {
        if (t < 1) return;
        const int b = blockIdx.x - 64;
        const int ts = t - 1;
#pragma unroll
        for (int q = 0; q < 4; ++q) {
            int j = q * 256 + tid;
            float gi = dec_bih[j] + dec_bhh[j];
            float gf = dec_bih[1024 + j] + dec_bhh[1024 + j];
            float gg = dec_bih[2048 + j] + dec_bhh[2048 + j];
            float go = dec_bih[3072 + j] + dec_bhh[3072 + j];
            for (int s = 0; s < nsplit; ++s) {
                const float* g = g2 + (size_t)s * 262144 + b * 4096;
                gi += g[j]; gf += g[1024 + j]; gg += g[2048 + j]; go += g[3072 + j];
            }
            float c = sigf(gf) * dc[b * 1024 + j] + sigf(gi) * tanhf_fast(gg);
            float h = sigf(go) * tanhf_fast(c);
            dc[b * 1024 + j] = c;
            xcat_dec[b * 2560 + 1536 + j] = h;
            u16 hh, hl; split1(h, hh, hl);
            xdech[b * 2560 + 1536 + j] = hh;  xdecl[b * 2560 + 1536 + j] = hl;
            sbuf[j] = h;
        }
        for (int i = tid; i < 512; i += 256) sbuf[1024 + i] = xcat_dec[b * 2560 + 1024 + i];
        __syncthreads();
        const int o = tid >> 1, half = tid & 1;
        float accv = 0.f;
        if (o <= 80) {
            const float* w = (o < 80) ? (proj_w + o * 1536) : gate_w;
            const float* sv = sbuf + half * 768;
            const float* wv = w + half * 768;
            float s0 = 0.f, s1 = 0.f, s2 = 0.f, s3 = 0.f;
#pragma unroll 4
            for (int k = 0; k < 768; k += 16) {
                float4 a0 = *(const float4*)&sv[k],      b0 = *(const float4*)&wv[k];
                float4 a1 = *(const float4*)&sv[k + 4],  b1 = *(const float4*)&wv[k + 4];
                float4 a2 = *(const float4*)&sv[k + 8],  b2 = *(const float4*)&wv[k + 8];
                float4 a3 = *(const float4*)&sv[k + 12], b3 = *(const float4*)&wv[k + 12];
                s0 += a0.x * b0.x + a0.y * b0.y + a0.z * b0.z + a0.w * b0.w;
                s1 += a1.x * b1.x + a1.y * b1.y + a1.z * b1.z + a1.w * b1.w;
                s2 += a2.x * b2.x + a2.y * b2.y + a2.z * b2.z + a2.w * b2.w;
                s3 += a3.x * b3.x + a3.y * b3.y + a3.z * b3.z + a3.w * b3.w;
            }
            accv = (s0 + s1) + (s2 + s3);
        }
        red[tid] = accv;
        __syncthreads();
        if (half == 0 && o <= 80) {
            float r = red[tid] + red[tid + 1];
            if (o < 80)
                out[MEL_OFF + (size_t)b * (TOUT * NMEL) + (size_t)ts * NMEL + o] = r + proj_b[o];
            else
                out[GATE_OFF + (size_t)b * TOUT + ts] = r + gate_b[0];
        }
    }
}

// ---------------- L2: conv + loc_dense + energies (grid 64 x 8, 4 threads/t) ----------------
__global__ __launch_bounds__(256) void energies_kernel(
    const float* __restrict__ aw, const float* __restrict__ awc,
    const float* __restrict__ lc, const float* __restrict__ ld,
    const float* __restrict__ vvec, const float* __restrict__ pq,
    const float* __restrict__ pm, float* __restrict__ energ)
{
    const int b = blockIdx.x, tc = blockIdx.y;
    const int t0 = tc * 64;
    const int tid = threadIdx.x;
    __shared__ float awin[96], awcin[96];
    __shared__ float lcs[NFILT * 62];
    __shared__ float locs[64 * 33];
    __shared__ float pqs[ATTD], vs[ATTD];
    __shared__ float ldm[ATTD * 33];           // padded stride 33: bank-conflict-free

    for (int i = tid; i < 94; i += 256) {
        int t = t0 + i - CPAD;
        bool ok = (t >= 0 && t < TIN);
        awin[i]  = ok ? aw[b * TIN + t]  : 0.f;
        awcin[i] = ok ? awc[b * TIN + t] : 0.f;
    }
    for (int i = tid; i < NFILT * 62; i += 256) lcs[i] = lc[i];
    for (int i = tid; i < ATTD * NFILT; i += 256) ldm[(i >> 5) * 33 + (i & 31)] = ld[i];
    if (tid < ATTD) { pqs[tid] = pq[b * ATTD + tid]; vs[tid] = vvec[tid]; }
    __syncthreads();

    // conv: 64 t x 32 f, 8 outputs/thread
    for (int idx = tid; idx < 64 * 32; idx += 256) {
        int tl = idx >> 5, f = idx & 31;
        const float* w0 = lcs + f * 62;
        float s = 0.f;
#pragma unroll
        for (int k = 0; k < KSZ; ++k)
            s += awin[tl + k] * w0[k] + awcin[tl + k] * w0[31 + k];
        locs[tl * 33 + f] = s;
    }
    __syncthreads();

    // energies: 4 threads per t, 32 a each
    const int tl = tid >> 2, q = tid & 3;
    const int a0 = q * 32;
    const float* pmrow = pm + (size_t)b * (TIN * ATTD) + (size_t)(t0 + tl) * ATTD + a0;
    const float* lt = locs + tl * 33;
    float4 pv[8];
#pragma unroll
    for (int u = 0; u < 8; ++u) pv[u] = *(const float4*)&pmrow[u * 4];
    float e = 0.f;
#pragma unroll
    for (int aa = 0; aa < 32; ++aa) {
        int a = a0 + aa;
        float sv = pqs[a] + ((const float*)pv)[aa];
        const float* lrow = ldm + a * 33;
#pragma unroll
        for (int f = 0; f < NFILT; ++f) sv += lt[f] * lrow[f];
        e += vs[a] * tanhf_fast(sv);
    }
    e += __shfl_xor(e, 1);
    e += __shfl_xor(e, 2);
    if (q == 0) energ[b * TIN + t0 + tl] = e;
}

// ---------------- L3: distributed softmax + ctx (grid 512 = 64b x 8dq, 4 threads/d) ----------------
__global__ __launch_bounds__(256) void softmax_ctx_kernel(
    const float* __restrict__ energ, const int* __restrict__ mlen,
    const float* __restrict__ memory,
    float* __restrict__ aw, float* __restrict__ awc,
    float* __restrict__ out_align, int t_step,
    float* __restrict__ xcat_att, float* __restrict__ xcat_dec,
    u16* __restrict__ tailh, u16* __restrict__ taill,
    u16* __restrict__ xdech, u16* __restrict__ xdecl)
{
    const int b = blockIdx.x >> 3, dq = blockIdx.x & 7;
    const int tid = threadIdx.x;
    const int len = mlen[b];
    __shared__ float es[TIN];
    __shared__ float red[256];

    // redundant 512-wide softmax (per-block; avoids cross-block dep)
    float e1 = (tid < len) ? energ[b * TIN + tid] : -INFINITY;
    float e2 = (tid + 256 < len) ? energ[b * TIN + tid + 256] : -INFINITY;
    red[tid] = fmaxf(e1, e2);
    __syncthreads();
    for (int s = 128; s > 0; s >>= 1) {
        if (tid < s) red[tid] = fmaxf(red[tid], red[tid + s]);
        __syncthreads();
    }
    const float mx = red[0];
    __syncthreads();
    float p1 = __expf(e1 - mx);
    float p2 = __expf(e2 - mx);
    red[tid] = p1 + p2;
    __syncthreads();
    for (int s = 128; s > 0; s >>= 1) {
        if (tid < s) red[tid] += red[tid + s];
        __syncthreads();
    }
    const float inv = 1.f / red[0];
    p1 *= inv; p2 *= inv;
    es[tid] = p1; es[tid + 256] = p2;
    __syncthreads();

    // disjoint 64-slice of aw/awc/alignments
    if (tid < 64) {
        int tt = dq * 64 + tid;
        float p = es[tt];
        aw[b * TIN + tt] = p;
        awc[b * TIN + tt] += p;
        out_align[(size_t)b * (TOUT * TIN) + (size_t)t_step * TIN + tt] = p;
    }

    // ctx 64-d slice: 4 threads per d, 128 t each
    const int d = dq * 64 + (tid & 63), th = tid >> 6;
    const float* mb = memory + (size_t)b * (TIN * ENC);
    float accv = 0.f;
#pragma unroll 4
    for (int tt = th * 128; tt < th * 128 + 128; ++tt)
        accv += es[tt] * mb[(size_t)tt * ENC + d];
    red[tid] = accv;
    __syncthreads();
    if (tid < 64) {
        float cv = (red[tid] + red[tid + 64]) + (red[tid + 128] + red[tid + 192]);
        int dd = dq * 64 + tid;
        xcat_att[b * 1536 + dd] = cv;
        xcat_dec[b * 2560 + 1024 + dd] = cv;
        u16 h, l; split1(cv, h, l);
        tailh[b * 1536 + dd] = h;        taill[b * 1536 + dd] = l;
        xdech[b * 2560 + 1024 + dd] = h; xdecl[b * 2560 + 1024 + dd] = l;
    }
}

extern "C" void kernel_launch(void* const* d_in, const int* in_sizes, int n_in,
                              void* d_out, int out_size, void* d_ws, size_t ws_size,
                              hipStream_t stream) {
    const float* memory   = (const float*)d_in[0];
    const float* dec_in   = (const float*)d_in[1];
    const int*   mlen     = (const int*)d_in[2];
    const float* pw1      = (const float*)d_in[3];
    const float* pw2      = (const float*)d_in[4];
    const float* att_wih  = (const float*)d_in[5];
    const float* att_whh  = (const float*)d_in[6];
    const float* att_bih  = (const float*)d_in[7];
    const float* att_bhh  = (const float*)d_in[8];
    const float* wq       = (const float*)d_in[9];
    const float* wm       = (const float*)d_in[10];
    const float* v        = (const float*)d_in[11];
    const float* loc_conv = (const float*)d_in[12];
    const float* loc_dense= (const float*)d_in[13];
    const float* dec_wih  = (const float*)d_in[14];
    const float* dec_whh  = (const float*)d_in[15];
    const float* dec_bih  = (const float*)d_in[16];
    const float* dec_bhh  = (const float*)d_in[17];
    const float* proj_w   = (const float*)d_in[18];
    const float* proj_b   = (const float*)d_in[19];
    const float* gate_w   = (const float*)d_in[20];
    const float* gate_b   = (const float*)d_in[21];
    float* out = (float*)d_out;

    // ---- ws layout ----
    float* x        = (float*)d_ws;
    float* pm       = x + X_SZ;
    float* g1       = pm + PM_SZ;
    float* g2       = g1 + G1_SZ;
    float* xcat_att = g2 + G2_SZ;          // zero-block start
    float* xcat_dec = xcat_att + XATT_SZ;
    float* ac       = xcat_dec + XDEC_SZ;
    float* dc       = ac + AC_SZ;
    float* aw       = dc + DC_SZ;
    float* awc      = aw + AW_SZ;
    float* tailh_f  = awc + AWC_SZ;
    float* taill_f  = tailh_f + TAILH_SZ;
    float* xdech_f  = taill_f + TAILL_SZ;
    float* xdecl_f  = xdech_f + XDH_SZ;    // zero-block end
    float* pq       = xdecl_f + XDL_SZ;
    float* energ    = pq + PQ_SZ;
    unsigned char* m1 = (unsigned char*)(energ + EN_SZ);
    unsigned char* m2 = m1 + MASK_N;
    u16* pk1 = (u16*)(m2 + MASK_N);
    u16* pk2 = pk1 + PK1_N;

    u16* tailh = (u16*)tailh_f;  u16* taill = (u16*)taill_f;
    u16* xdech = (u16*)xdech_f;  u16* xdecl = (u16*)xdecl_f;

    size_t need_base = (size_t)(m2 + MASK_N - (unsigned char*)d_ws);
    size_t need_full = (size_t)((unsigned char*)(pk2 + PK2_N) - (unsigned char*)d_ws);
    if (ws_size < need_base) return;
    const bool use_mfma = (ws_size >= need_full);
    const int nsplit = use_mfma ? 2 : 4;

    // zero recurrent state (xcat_att .. xdecl contiguous)
    size_t state_floats = (size_t)XATT_SZ + XDEC_SZ + AC_SZ + DC_SZ + AW_SZ + AWC_SZ
                        + TAILH_SZ + TAILL_SZ + XDH_SZ + XDL_SZ;
    hipMemsetAsync(xcat_att, 0, state_floats * sizeof(float), stream);

    // one-time: dropout masks, prenet, processed memory, weight pack
    mask_kernel<<<(MASK_N + 255) / 256, 256, 0, stream>>>(m1, m2);
    prenet1_kernel<<<TOUT * NB, 256, 0, stream>>>(dec_in, pw1, m1, x);
    prenet2_kernel<<<TOUT * NB, 256, 0, stream>>>(pw2, m2, x);
    pm_kernel<<<dim3(NB, TIN), 128, 0, stream>>>(memory, wm, pm);
    if (use_mfma) {
        wpack_kernel<<<(4096 * K1TOT + 255) / 256, 256, 0, stream>>>(att_wih, 768, att_whh, 1024, pk1);
        wpack_kernel<<<(4096 * K2TOT + 255) / 256, 256, 0, stream>>>(dec_wih, 1536, dec_whh, 1024, pk2);
    }

    float* out_align = out + ALGN_OFF;

    // prologue: gemm1 for t=0
    if (use_mfma)
        mfma_pair_gemm<<<1024, 256, 0, stream>>>(xdech, xdecl, pk2, g2, x, tailh, taill, pk1, g1, -1);
    else
        pair_gemm<<<512, 256, 0, stream>>>(xcat_dec, dec_wih, dec_whh, g2,
                                           x, xcat_att, att_wih, att_whh, g1, -1);

    for (int t = 0; t < TOUT; ++t) {
        pair_pw<<<128, 256, 0, stream>>>(g1, att_bih, att_bhh, ac, xcat_att, xcat_dec, wq, pq,
                                         g2, dec_bih, dec_bhh, dc, proj_w, proj_b,
                                         gate_w, gate_b, out, tailh, taill, xdech, xdecl,
                                         nsplit, t);
        energies_kernel<<<dim3(NB, 8), 256, 0, stream>>>(aw, awc, loc_conv, loc_dense, v, pq, pm, energ);
        softmax_ctx_kernel<<<512, 256, 0, stream>>>(energ, mlen, memory, aw, awc, out_align, t,
                                                    xcat_att, xcat_dec, tailh, taill, xdech, xdecl);
        if (use_mfma)
            mfma_pair_gemm<<<1024, 256, 0, stream>>>(xdech, xdecl, pk2, g2, x, tailh, taill, pk1, g1, t);
        else
            pair_gemm<<<512, 256, 0, stream>>>(xcat_dec, dec_wih, dec_whh, g2,
                                               x, xcat_att, att_wih, att_whh, g1, t);
    }
    // epilogue: dec_pointwise+proj for t=499
    pair_pw<<<128, 256, 0, stream>>>(g1, att_bih, att_bhh, ac, xcat_att, xcat_dec, wq, pq,
                                     g2, dec_bih, dec_bhh, dc, proj_w, proj_b,
                                     gate_w, gate_b, out, tailh, taill, xdech, xdecl,
                                     nsplit, TOUT);
}